// Round 1
// baseline (1179.306 us; speedup 1.0000x reference)
//
#include <hip/hip_runtime.h>
#include <hip/hip_bf16.h>
#include <math.h>
#include <stdint.h>

#define IN_C 128
#define HID  256
#define OUT_C 2

// ---------------------------------------------------------------------------
// CSR build: degree count -> block sums -> scan -> per-block scan -> fill
// ---------------------------------------------------------------------------

__global__ void k_deg(const int* __restrict__ dst, int* __restrict__ deg, int E) {
  int e = blockIdx.x * 256 + threadIdx.x;
  if (e < E) atomicAdd(&deg[dst[e]], 1);
}

__global__ void k_block_sum(const int* __restrict__ deg, int* __restrict__ bsum, int n) {
  __shared__ int sd[256];
  int t = threadIdx.x, idx = blockIdx.x * 256 + t;
  sd[t] = (idx < n) ? deg[idx] : 0;
  __syncthreads();
  for (int off = 128; off > 0; off >>= 1) {
    if (t < off) sd[t] += sd[t + off];
    __syncthreads();
  }
  if (t == 0) bsum[blockIdx.x] = sd[0];
}

__global__ void k_scan_bsums(int* bsum, int nb) {
  // nb <= 512 (N=100000 -> 391 blocks)
  __shared__ int sd[512];
  int t = threadIdx.x;
  sd[t] = (t < nb) ? bsum[t] : 0;
  __syncthreads();
  for (int off = 1; off < 512; off <<= 1) {
    int v = (t >= off) ? sd[t - off] : 0;
    __syncthreads();
    sd[t] += v;
    __syncthreads();
  }
  if (t < nb) bsum[t] = sd[t];   // inclusive scan of block sums
}

__global__ void k_scan_final(const int* __restrict__ deg, const int* __restrict__ bsum,
                             int* __restrict__ row_start, int* __restrict__ cursor, int n) {
  __shared__ int sd[256];
  int t = threadIdx.x, b = blockIdx.x, idx = b * 256 + t;
  int own = (idx < n) ? deg[idx] : 0;
  sd[t] = own;
  __syncthreads();
  for (int off = 1; off < 256; off <<= 1) {
    int v = (t >= off) ? sd[t - off] : 0;
    __syncthreads();
    sd[t] += v;
    __syncthreads();
  }
  int excl = sd[t] - own;
  int base = (b > 0) ? bsum[b - 1] : 0;
  if (idx < n) { row_start[idx] = base + excl; cursor[idx] = base + excl; }
}

__global__ void k_fill(const int* __restrict__ src, const int* __restrict__ dst,
                       int* __restrict__ cursor, int* __restrict__ csr, int E) {
  int e = blockIdx.x * 256 + threadIdx.x;
  if (e < E) {
    int d = dst[e];
    int pos = atomicAdd(&cursor[d], 1);
    csr[pos] = src[e];
  }
}

// ---------------------------------------------------------------------------
// Mean aggregation: one wave per node; lane holds float2 of the 128-dim row
// ---------------------------------------------------------------------------

__global__ void k_aggr(const float* __restrict__ x, const int* __restrict__ csr,
                       const int* __restrict__ row_start, const int* __restrict__ deg,
                       float* __restrict__ aggr, int n) {
  int wid = threadIdx.x >> 6;
  int lane = threadIdx.x & 63;
  int node = blockIdx.x * 4 + wid;
  if (node >= n) return;
  int base = row_start[node];
  int d = deg[node];
  float sx = 0.f, sy = 0.f;
  int i = 0;
  for (; i + 1 < d; i += 2) {
    int n0 = csr[base + i];
    int n1 = csr[base + i + 1];
    float2 v0 = ((const float2*)(x + (size_t)n0 * IN_C))[lane];
    float2 v1 = ((const float2*)(x + (size_t)n1 * IN_C))[lane];
    sx += v0.x + v1.x;
    sy += v0.y + v1.y;
  }
  if (i < d) {
    int n0 = csr[base + i];
    float2 v0 = ((const float2*)(x + (size_t)n0 * IN_C))[lane];
    sx += v0.x; sy += v0.y;
  }
  float inv = 1.0f / (float)(d > 1 ? d : 1);
  float2 r; r.x = sx * inv; r.y = sy * inv;
  ((float2*)(aggr + (size_t)node * IN_C))[lane] = r;
}

// ---------------------------------------------------------------------------
// Fused SAGE GEMM + relu + per-graph max-pool
// h = relu(aggr@Wl^T + x@Wr^T + bl); hp[g] = max over nodes of graph g
// Tile: 64 nodes x 64 cols, K chunked by 32. Never materializes h.
// ---------------------------------------------------------------------------

#define BN 64
#define BC 64
#define KC 32

__global__ __launch_bounds__(256) void k_gemm_pool(
    const float* __restrict__ x, const float* __restrict__ aggr,
    const float* __restrict__ Wl, const float* __restrict__ Wr,
    const float* __restrict__ bl, const int* __restrict__ batch,
    float* __restrict__ hp, int n) {
  __shared__ union {
    struct { float A[2][KC][BN + 4]; float W[2][KC][BC + 4]; } s;
    float H[BN][BC + 4];
  } sm;
  __shared__ int sBatch[BN];

  int t = threadIdx.x;
  int n0 = blockIdx.x * BN;
  int c0 = blockIdx.y * BC;
  if (t < BN) sBatch[t] = (n0 + t < n) ? batch[n0 + t] : -1;

  int tn = t & 15;   // node group: nodes tn*4 .. tn*4+3
  int tc = t >> 4;   // col group:  cols  tc*4 .. tc*4+3
  float acc[4][4] = {};

  for (int k0 = 0; k0 < IN_C; k0 += KC) {
    __syncthreads();
    // stage A (aggr, x) and W (Wl, Wr) tiles, transposed to k-major
#pragma unroll
    for (int it = 0; it < 2; ++it) {
      int j = it * 256 + t;          // 0..511
      int r = j >> 3;                // 0..63 (node or col within tile)
      int kq = (j & 7) * 4;          // 0,4,...,28
      int gn = n0 + r; gn = gn < n ? gn : n - 1;
      float4 va = *(const float4*)(aggr + (size_t)gn * IN_C + k0 + kq);
      float4 vx = *(const float4*)(x + (size_t)gn * IN_C + k0 + kq);
      float4 vl = *(const float4*)(Wl + (size_t)(c0 + r) * IN_C + k0 + kq);
      float4 vr = *(const float4*)(Wr + (size_t)(c0 + r) * IN_C + k0 + kq);
      sm.s.A[0][kq + 0][r] = va.x; sm.s.A[0][kq + 1][r] = va.y;
      sm.s.A[0][kq + 2][r] = va.z; sm.s.A[0][kq + 3][r] = va.w;
      sm.s.A[1][kq + 0][r] = vx.x; sm.s.A[1][kq + 1][r] = vx.y;
      sm.s.A[1][kq + 2][r] = vx.z; sm.s.A[1][kq + 3][r] = vx.w;
      sm.s.W[0][kq + 0][r] = vl.x; sm.s.W[0][kq + 1][r] = vl.y;
      sm.s.W[0][kq + 2][r] = vl.z; sm.s.W[0][kq + 3][r] = vl.w;
      sm.s.W[1][kq + 0][r] = vr.x; sm.s.W[1][kq + 1][r] = vr.y;
      sm.s.W[1][kq + 2][r] = vr.z; sm.s.W[1][kq + 3][r] = vr.w;
    }
    __syncthreads();
#pragma unroll
    for (int k = 0; k < KC; ++k) {
      float4 a0 = *(const float4*)&sm.s.A[0][k][tn * 4];
      float4 a1 = *(const float4*)&sm.s.A[1][k][tn * 4];
      float4 w0 = *(const float4*)&sm.s.W[0][k][tc * 4];
      float4 w1 = *(const float4*)&sm.s.W[1][k][tc * 4];
      float a0v[4] = {a0.x, a0.y, a0.z, a0.w};
      float a1v[4] = {a1.x, a1.y, a1.z, a1.w};
      float w0v[4] = {w0.x, w0.y, w0.z, w0.w};
      float w1v[4] = {w1.x, w1.y, w1.z, w1.w};
#pragma unroll
      for (int i = 0; i < 4; ++i)
#pragma unroll
        for (int j = 0; j < 4; ++j)
          acc[i][j] += a0v[i] * w0v[j] + a1v[i] * w1v[j];
    }
  }

  // bias + relu -> LDS H tile (aliases staging area)
  float blv[4];
#pragma unroll
  for (int j = 0; j < 4; ++j) blv[j] = bl[c0 + tc * 4 + j];
  __syncthreads();
#pragma unroll
  for (int i = 0; i < 4; ++i) {
    float4 hv;
    hv.x = fmaxf(acc[i][0] + blv[0], 0.f);
    hv.y = fmaxf(acc[i][1] + blv[1], 0.f);
    hv.z = fmaxf(acc[i][2] + blv[2], 0.f);
    hv.w = fmaxf(acc[i][3] + blv[3], 0.f);
    *(float4*)&sm.H[tn * 4 + i][tc * 4] = hv;
  }
  __syncthreads();

  // per-graph max over this 64-node window (batch sorted => <=2 graphs/window)
  if (t < BC) {
    int col = c0 + t;
    int curg = sBatch[0];          // n0 < n always
    float cur = 0.f;               // relu values are >= 0
    for (int node = 0; node < BN; ++node) {
      int g = sBatch[node];
      if (g < 0) break;
      if (g != curg) {
        atomicMax((int*)(hp + (size_t)curg * HID + col), __float_as_int(cur));
        curg = g;
        cur = 0.f;
      }
      float v = sm.H[node][t];
      cur = fmaxf(cur, v);
    }
    atomicMax((int*)(hp + (size_t)curg * HID + col), __float_as_int(cur));
  }
}

// ---------------------------------------------------------------------------
// Root finding (first node of each graph; batch is sorted)
// ---------------------------------------------------------------------------

__global__ void k_root(const int* __restrict__ batch, int* __restrict__ root, int n) {
  int i = blockIdx.x * 256 + threadIdx.x;
  if (i < n) {
    int g = batch[i];
    if (i == 0 || batch[i - 1] != g) root[g] = i;
  }
}

// ---------------------------------------------------------------------------
// Tail MLP, one block per graph:
// news = relu(x[root]@W0^T + b0); h2 = relu([news,hp]@W1^T + b1);
// out = log_softmax(h2@W2^T + b2)
// ---------------------------------------------------------------------------

__global__ __launch_bounds__(256) void k_mlp2(
    const float* __restrict__ x, const float* __restrict__ hp,
    const int* __restrict__ root,
    const float* __restrict__ W0, const float* __restrict__ b0,
    const float* __restrict__ W1, const float* __restrict__ b1,
    const float* __restrict__ W2, const float* __restrict__ b2,
    float* __restrict__ out) {
  __shared__ float xr[IN_C];
  __shared__ float cat[2 * HID];
  __shared__ float h2r[HID];
  __shared__ float red[8];

  int g = blockIdx.x;
  int t = threadIdx.x;
  int rg = root[g];
  if (t < IN_C) xr[t] = x[(size_t)rg * IN_C + t];
  __syncthreads();

  // news_t
  float a0 = b0[t];
  const float* w0 = W0 + (size_t)t * IN_C;
#pragma unroll 4
  for (int k = 0; k < IN_C; ++k) a0 += xr[k] * w0[k];
  cat[t] = fmaxf(a0, 0.f);
  cat[HID + t] = hp[(size_t)g * HID + t];
  __syncthreads();

  // h2_t
  float a1 = b1[t];
  const float* w1 = W1 + (size_t)t * (2 * HID);
#pragma unroll 4
  for (int j = 0; j < 2 * HID; ++j) a1 += cat[j] * w1[j];
  h2r[t] = fmaxf(a1, 0.f);
  __syncthreads();

  // logits + log_softmax
  float p0 = h2r[t] * W2[t];
  float p1 = h2r[t] * W2[HID + t];
  for (int off = 32; off > 0; off >>= 1) {
    p0 += __shfl_down(p0, off);
    p1 += __shfl_down(p1, off);
  }
  int lane = t & 63, wid = t >> 6;
  if (lane == 0) { red[wid * 2] = p0; red[wid * 2 + 1] = p1; }
  __syncthreads();
  if (t == 0) {
    float l0 = b2[0] + red[0] + red[2] + red[4] + red[6];
    float l1 = b2[1] + red[1] + red[3] + red[5] + red[7];
    float m = fmaxf(l0, l1);
    float ls = logf(expf(l0 - m) + expf(l1 - m));
    out[(size_t)g * 2 + 0] = l0 - m - ls;
    out[(size_t)g * 2 + 1] = l1 - m - ls;
  }
}

// ---------------------------------------------------------------------------

extern "C" void kernel_launch(void* const* d_in, const int* in_sizes, int n_in,
                              void* d_out, int out_size, void* d_ws, size_t ws_size,
                              hipStream_t stream) {
  const float* x  = (const float*)d_in[0];
  const int* ei   = (const int*)d_in[1];
  const int* batch= (const int*)d_in[2];
  const float* Wl = (const float*)d_in[3];
  const float* bl = (const float*)d_in[4];
  const float* Wr = (const float*)d_in[5];
  const float* W0 = (const float*)d_in[6];
  const float* b0 = (const float*)d_in[7];
  const float* W1 = (const float*)d_in[8];
  const float* b1 = (const float*)d_in[9];
  const float* W2 = (const float*)d_in[10];
  const float* b2 = (const float*)d_in[11];
  float* out = (float*)d_out;

  const int N = in_sizes[0] / IN_C;
  const int E = in_sizes[1] / 2;
  const int G = out_size / OUT_C;
  const int* src = ei;
  const int* dst = ei + E;

  char* w = (char*)d_ws;
  int* deg       = (int*)w; w += (size_t)N * 4;
  int* row_start = (int*)w; w += (size_t)N * 4;
  int* cursor    = (int*)w; w += (size_t)N * 4;
  int* bsum      = (int*)w; w += 4096;                 // up to 1024 block sums
  int* root      = (int*)w; w += (size_t)G * 4;
  w = (char*)(((uintptr_t)w + 15) & ~(uintptr_t)15);
  int* csr       = (int*)w; w += (size_t)E * 4;
  float* aggr    = (float*)w; w += (size_t)N * IN_C * 4;
  float* hp      = (float*)w; w += (size_t)G * HID * 4;

  hipMemsetAsync(deg, 0, (size_t)N * 4, stream);
  hipMemsetAsync(hp, 0, (size_t)G * HID * 4, stream);

  int nb = (N + 255) / 256;
  k_deg<<<(E + 255) / 256, 256, 0, stream>>>(dst, deg, E);
  k_block_sum<<<nb, 256, 0, stream>>>(deg, bsum, N);
  k_scan_bsums<<<1, 512, 0, stream>>>(bsum, nb);
  k_scan_final<<<nb, 256, 0, stream>>>(deg, bsum, row_start, cursor, N);
  k_fill<<<(E + 255) / 256, 256, 0, stream>>>(src, dst, cursor, csr, E);
  k_aggr<<<(N + 3) / 4, 256, 0, stream>>>(x, csr, row_start, deg, aggr, N);
  k_root<<<(N + 255) / 256, 256, 0, stream>>>(batch, root, N);
  k_gemm_pool<<<dim3((N + BN - 1) / BN, HID / BC), 256, 0, stream>>>(
      x, aggr, Wl, Wr, bl, batch, hp, N);
  k_mlp2<<<G, 256, 0, stream>>>(x, hp, root, W0, b0, W1, b1, W2, b2, out);
}

// Round 2
// 470.366 us; speedup vs baseline: 2.5072x; 2.5072x over previous
//
#include <hip/hip_runtime.h>
#include <hip/hip_bf16.h>
#include <math.h>
#include <stdint.h>

#define IN_C 128
#define HID  256
#define OUT_C 2

typedef __attribute__((ext_vector_type(8))) short short8;
typedef __attribute__((ext_vector_type(4))) float f32x4;

__device__ __forceinline__ ushort f2bf(float f) {
  uint32_t u = __float_as_uint(f);
  uint32_t r = u + 0x7FFF + ((u >> 16) & 1);   // RNE
  return (ushort)(r >> 16);
}
__device__ __forceinline__ float bf2f(ushort b) {
  return __uint_as_float(((uint32_t)b) << 16);
}

// ---------------------------------------------------------------------------
// CSR build: degree count -> block sums -> scan -> per-block scan -> fill
// ---------------------------------------------------------------------------

__global__ void k_deg(const int* __restrict__ dst, int* __restrict__ deg, int E) {
  int e = blockIdx.x * 256 + threadIdx.x;
  if (e < E) atomicAdd(&deg[dst[e]], 1);
}

__global__ void k_block_sum(const int* __restrict__ deg, int* __restrict__ bsum, int n) {
  __shared__ int sd[256];
  int t = threadIdx.x, idx = blockIdx.x * 256 + t;
  sd[t] = (idx < n) ? deg[idx] : 0;
  __syncthreads();
  for (int off = 128; off > 0; off >>= 1) {
    if (t < off) sd[t] += sd[t + off];
    __syncthreads();
  }
  if (t == 0) bsum[blockIdx.x] = sd[0];
}

__global__ void k_scan_bsums(int* bsum, int nb) {
  __shared__ int sd[512];
  int t = threadIdx.x;
  sd[t] = (t < nb) ? bsum[t] : 0;
  __syncthreads();
  for (int off = 1; off < 512; off <<= 1) {
    int v = (t >= off) ? sd[t - off] : 0;
    __syncthreads();
    sd[t] += v;
    __syncthreads();
  }
  if (t < nb) bsum[t] = sd[t];
}

__global__ void k_scan_final(const int* __restrict__ deg, const int* __restrict__ bsum,
                             int* __restrict__ row_start, int* __restrict__ cursor, int n) {
  __shared__ int sd[256];
  int t = threadIdx.x, b = blockIdx.x, idx = b * 256 + t;
  int own = (idx < n) ? deg[idx] : 0;
  sd[t] = own;
  __syncthreads();
  for (int off = 1; off < 256; off <<= 1) {
    int v = (t >= off) ? sd[t - off] : 0;
    __syncthreads();
    sd[t] += v;
    __syncthreads();
  }
  int excl = sd[t] - own;
  int base = (b > 0) ? bsum[b - 1] : 0;
  if (idx < n) { row_start[idx] = base + excl; cursor[idx] = base + excl; }
}

__global__ void k_fill(const int* __restrict__ src, const int* __restrict__ dst,
                       int* __restrict__ cursor, int* __restrict__ csr, int E) {
  int e = blockIdx.x * 256 + threadIdx.x;
  if (e < E) {
    int d = dst[e];
    int pos = atomicAdd(&cursor[d], 1);
    csr[pos] = src[e];
  }
}

// ---------------------------------------------------------------------------
// fp32 -> bf16 casts
// ---------------------------------------------------------------------------

__global__ void k_cast(const float* __restrict__ in, ushort* __restrict__ out, int n4) {
  int i = blockIdx.x * 256 + threadIdx.x;
  if (i < n4) {
    float4 v = ((const float4*)in)[i];
    ushort4 o;
    o.x = f2bf(v.x); o.y = f2bf(v.y); o.z = f2bf(v.z); o.w = f2bf(v.w);
    ((ushort4*)out)[i] = o;
  }
}

// W_cat[c][k] = k<128 ? Wl[c][k] : Wr[c][k-128], bf16, [256][256]
__global__ void k_wcat(const float* __restrict__ Wl, const float* __restrict__ Wr,
                       ushort* __restrict__ Wcat) {
  int c = blockIdx.x, k = threadIdx.x;
  float v = (k < IN_C) ? Wl[(size_t)c * IN_C + k] : Wr[(size_t)c * IN_C + (k - IN_C)];
  Wcat[(size_t)c * (2 * IN_C) + k] = f2bf(v);
}

// ---------------------------------------------------------------------------
// Mean aggregation on bf16 rows: one wave per node, 2 rows in flight
// (half-wave per row, uint2 = 4 bf16 per lane), fp32 accumulate, bf16 out.
// ---------------------------------------------------------------------------

__global__ void k_aggr(const ushort* __restrict__ xb, const int* __restrict__ csr,
                       const int* __restrict__ row_start, const int* __restrict__ deg,
                       ushort* __restrict__ aggr, int n) {
  int wid = threadIdx.x >> 6;
  int lane = threadIdx.x & 63;
  int node = blockIdx.x * 4 + wid;
  if (node >= n) return;
  int base = row_start[node];
  int d = deg[node];
  int half = lane >> 5, li = lane & 31;
  float s0 = 0.f, s1 = 0.f, s2 = 0.f, s3 = 0.f;
  int i = half;
  for (; i + 2 < d; i += 4) {   // this half-wave handles i and i+2
    int na = csr[base + i];
    int nb = csr[base + i + 2];
    uint2 va = ((const uint2*)(xb + (size_t)na * IN_C))[li];
    uint2 vb = ((const uint2*)(xb + (size_t)nb * IN_C))[li];
    s0 += bf2f((ushort)(va.x & 0xffff)) + bf2f((ushort)(vb.x & 0xffff));
    s1 += bf2f((ushort)(va.x >> 16))    + bf2f((ushort)(vb.x >> 16));
    s2 += bf2f((ushort)(va.y & 0xffff)) + bf2f((ushort)(vb.y & 0xffff));
    s3 += bf2f((ushort)(va.y >> 16))    + bf2f((ushort)(vb.y >> 16));
  }
  for (; i < d; i += 2) {
    int na = csr[base + i];
    uint2 va = ((const uint2*)(xb + (size_t)na * IN_C))[li];
    s0 += bf2f((ushort)(va.x & 0xffff));
    s1 += bf2f((ushort)(va.x >> 16));
    s2 += bf2f((ushort)(va.y & 0xffff));
    s3 += bf2f((ushort)(va.y >> 16));
  }
  // merge the two halves (lane ^ 32 holds the other parity, same columns)
  s0 += __shfl_xor(s0, 32);
  s1 += __shfl_xor(s1, 32);
  s2 += __shfl_xor(s2, 32);
  s3 += __shfl_xor(s3, 32);
  if (half == 0) {
    float inv = 1.0f / (float)(d > 1 ? d : 1);
    ushort4 o;
    o.x = f2bf(s0 * inv); o.y = f2bf(s1 * inv);
    o.z = f2bf(s2 * inv); o.w = f2bf(s3 * inv);
    ((ushort4*)(aggr + (size_t)node * IN_C))[li] = o;
  }
}

// ---------------------------------------------------------------------------
// Fused SAGE GEMM (bf16 MFMA, fp32 accum) + relu + per-graph max-pool.
// Block = 64 nodes x 256 cols; 4 waves, each 64x64 via 16x16x32 MFMA.
// A = [aggr | x] (K=256), B = Wcat[col][k]. h never materialized:
// register-level pool -> shfl reduce -> <=2 atomicMax per col per wave
// (batch sorted => <=2 graphs per 64-node window; 195+ nodes/graph).
// ---------------------------------------------------------------------------

__global__ __launch_bounds__(256) void k_gemm_pool(
    const ushort* __restrict__ aggrb, const ushort* __restrict__ xb,
    const ushort* __restrict__ Wcat, const float* __restrict__ bl,
    const int* __restrict__ batch, float* __restrict__ hp, int n) {
  __shared__ ushort sA[64][40];     // 80 B rows: 16B-aligned b128, banks spread
  __shared__ ushort sB[256][40];
  __shared__ float sbl[256];
  __shared__ int sBatch[64];

  int t = threadIdx.x;
  int n0 = blockIdx.x * 64;
  sbl[t] = bl[t];
  if (t < 64) sBatch[t] = (n0 + t < n) ? batch[n0 + t] : -1;

  int lane = t & 63, w = t >> 6;
  int q = lane >> 4, m = lane & 15;

  f32x4 acc[4][4] = {};

  int rA = t >> 2, kA = (t & 3) * 8;

  for (int k0 = 0; k0 < 2 * IN_C; k0 += 32) {
    __syncthreads();
    // stage A: 64 rows x 32 k (one uint4 per thread)
    int gn = n0 + rA; gn = gn < n ? gn : n - 1;
    const ushort* srcA = (k0 < IN_C) ? (aggrb + (size_t)gn * IN_C + k0 + kA)
                                     : (xb + (size_t)gn * IN_C + (k0 - IN_C) + kA);
    *(uint4*)&sA[rA][kA] = *(const uint4*)srcA;
    // stage B: 256 cols x 32 k (4 uint4 per thread)
#pragma unroll
    for (int it = 0; it < 4; ++it) {
      int j = it * 256 + t;
      int c = j >> 2, kB = (j & 3) * 8;
      *(uint4*)&sB[c][kB] = *(const uint4*)(Wcat + (size_t)c * (2 * IN_C) + k0 + kB);
    }
    __syncthreads();

    short8 af[4], bf[4];
#pragma unroll
    for (int rt = 0; rt < 4; ++rt) af[rt] = *(const short8*)&sA[rt * 16 + m][q * 8];
#pragma unroll
    for (int ct = 0; ct < 4; ++ct) bf[ct] = *(const short8*)&sB[w * 64 + ct * 16 + m][q * 8];
#pragma unroll
    for (int rt = 0; rt < 4; ++rt)
#pragma unroll
      for (int ct = 0; ct < 4; ++ct)
        acc[rt][ct] = __builtin_amdgcn_mfma_f32_16x16x32_bf16(af[rt], bf[ct], acc[rt][ct], 0, 0, 0);
  }

  // epilogue: bias + relu + per-graph max, all in registers
  int last = n - 1 - n0; last = last < 63 ? last : 63;
  int gA = sBatch[0];
  int gB = sBatch[last];
#pragma unroll
  for (int ct = 0; ct < 4; ++ct) {
    int col = w * 64 + ct * 16 + m;
    float bias = sbl[col];
    float mA = 0.f, mB = 0.f;   // relu values >= 0, so 0 is the identity
#pragma unroll
    for (int rt = 0; rt < 4; ++rt) {
#pragma unroll
      for (int i = 0; i < 4; ++i) {
        int lr = rt * 16 + q * 4 + i;
        if (n0 + lr < n) {
          float v = fmaxf(acc[rt][ct][i] + bias, 0.f);
          if (sBatch[lr] == gA) mA = fmaxf(mA, v);
          else mB = fmaxf(mB, v);
        }
      }
    }
    mA = fmaxf(mA, __shfl_xor(mA, 16)); mA = fmaxf(mA, __shfl_xor(mA, 32));
    mB = fmaxf(mB, __shfl_xor(mB, 16)); mB = fmaxf(mB, __shfl_xor(mB, 32));
    if (q == 0) {
      atomicMax((int*)&hp[(size_t)gA * HID + col], __float_as_int(mA));
      if (gB != gA) atomicMax((int*)&hp[(size_t)gB * HID + col], __float_as_int(mB));
    }
  }
}

// ---------------------------------------------------------------------------
// Root finding (first node of each graph; batch is sorted)
// ---------------------------------------------------------------------------

__global__ void k_root(const int* __restrict__ batch, int* __restrict__ root, int n) {
  int i = blockIdx.x * 256 + threadIdx.x;
  if (i < n) {
    int g = batch[i];
    if (i == 0 || batch[i - 1] != g) root[g] = i;
  }
}

// ---------------------------------------------------------------------------
// Tail MLP (fp32), one block per graph
// ---------------------------------------------------------------------------

__global__ __launch_bounds__(256) void k_mlp2(
    const float* __restrict__ x, const float* __restrict__ hp,
    const int* __restrict__ root,
    const float* __restrict__ W0, const float* __restrict__ b0,
    const float* __restrict__ W1, const float* __restrict__ b1,
    const float* __restrict__ W2, const float* __restrict__ b2,
    float* __restrict__ out) {
  __shared__ float xr[IN_C];
  __shared__ float cat[2 * HID];
  __shared__ float h2r[HID];
  __shared__ float red[8];

  int g = blockIdx.x;
  int t = threadIdx.x;
  int rg = root[g];
  if (t < IN_C) xr[t] = x[(size_t)rg * IN_C + t];
  __syncthreads();

  float a0 = b0[t];
  const float* w0 = W0 + (size_t)t * IN_C;
#pragma unroll 4
  for (int k = 0; k < IN_C; ++k) a0 += xr[k] * w0[k];
  cat[t] = fmaxf(a0, 0.f);
  cat[HID + t] = hp[(size_t)g * HID + t];
  __syncthreads();

  float a1 = b1[t];
  const float* w1 = W1 + (size_t)t * (2 * HID);
#pragma unroll 4
  for (int j = 0; j < 2 * HID; ++j) a1 += cat[j] * w1[j];
  h2r[t] = fmaxf(a1, 0.f);
  __syncthreads();

  float p0 = h2r[t] * W2[t];
  float p1 = h2r[t] * W2[HID + t];
  for (int off = 32; off > 0; off >>= 1) {
    p0 += __shfl_down(p0, off);
    p1 += __shfl_down(p1, off);
  }
  int lane = t & 63, wid = t >> 6;
  if (lane == 0) { red[wid * 2] = p0; red[wid * 2 + 1] = p1; }
  __syncthreads();
  if (t == 0) {
    float l0 = b2[0] + red[0] + red[2] + red[4] + red[6];
    float l1 = b2[1] + red[1] + red[3] + red[5] + red[7];
    float mx = fmaxf(l0, l1);
    float ls = logf(expf(l0 - mx) + expf(l1 - mx));
    out[(size_t)g * 2 + 0] = l0 - mx - ls;
    out[(size_t)g * 2 + 1] = l1 - mx - ls;
  }
}

// ---------------------------------------------------------------------------

extern "C" void kernel_launch(void* const* d_in, const int* in_sizes, int n_in,
                              void* d_out, int out_size, void* d_ws, size_t ws_size,
                              hipStream_t stream) {
  const float* x  = (const float*)d_in[0];
  const int* ei   = (const int*)d_in[1];
  const int* batch= (const int*)d_in[2];
  const float* Wl = (const float*)d_in[3];
  const float* bl = (const float*)d_in[4];
  const float* Wr = (const float*)d_in[5];
  const float* W0 = (const float*)d_in[6];
  const float* b0 = (const float*)d_in[7];
  const float* W1 = (const float*)d_in[8];
  const float* b1 = (const float*)d_in[9];
  const float* W2 = (const float*)d_in[10];
  const float* b2 = (const float*)d_in[11];
  float* out = (float*)d_out;

  const int N = in_sizes[0] / IN_C;
  const int E = in_sizes[1] / 2;
  const int G = out_size / OUT_C;
  const int* src = ei;
  const int* dst = ei + E;

  char* w = (char*)d_ws;
  int* deg       = (int*)w; w += (size_t)N * 4;
  int* row_start = (int*)w; w += (size_t)N * 4;
  int* cursor    = (int*)w; w += (size_t)N * 4;
  int* bsum      = (int*)w; w += 4096;
  int* root      = (int*)w; w += (size_t)G * 4;
  w = (char*)(((uintptr_t)w + 255) & ~(uintptr_t)255);
  int* csr       = (int*)w; w += (size_t)E * 4;
  w = (char*)(((uintptr_t)w + 255) & ~(uintptr_t)255);
  ushort* xb     = (ushort*)w; w += (size_t)N * IN_C * 2;
  ushort* aggrb  = (ushort*)w; w += (size_t)N * IN_C * 2;
  ushort* Wcat   = (ushort*)w; w += (size_t)HID * (2 * IN_C) * 2;
  float* hp      = (float*)w; w += (size_t)G * HID * 4;

  hipMemsetAsync(deg, 0, (size_t)N * 4, stream);
  hipMemsetAsync(hp, 0, (size_t)G * HID * 4, stream);

  int nb = (N + 255) / 256;
  k_deg<<<(E + 255) / 256, 256, 0, stream>>>(dst, deg, E);
  k_cast<<<((N * IN_C / 4) + 255) / 256, 256, 0, stream>>>(x, xb, N * IN_C / 4);
  k_wcat<<<HID, 2 * IN_C, 0, stream>>>(Wl, Wr, Wcat);
  k_block_sum<<<nb, 256, 0, stream>>>(deg, bsum, N);
  k_scan_bsums<<<1, 512, 0, stream>>>(bsum, nb);
  k_scan_final<<<nb, 256, 0, stream>>>(deg, bsum, row_start, cursor, N);
  k_fill<<<(E + 255) / 256, 256, 0, stream>>>(src, dst, cursor, csr, E);
  k_aggr<<<(N + 3) / 4, 256, 0, stream>>>(xb, csr, row_start, deg, aggrb, N);
  k_root<<<(N + 255) / 256, 256, 0, stream>>>(batch, root, N);
  k_gemm_pool<<<(N + 63) / 64, 256, 0, stream>>>(aggrb, xb, Wcat, bl, batch, hp, N);
  k_mlp2<<<G, 256, 0, stream>>>(x, hp, root, W0, b0, W1, b1, W2, b2, out);
}

// Round 3
// 349.179 us; speedup vs baseline: 3.3774x; 1.3471x over previous
//
#include <hip/hip_runtime.h>
#include <hip/hip_bf16.h>
#include <math.h>
#include <stdint.h>

#define IN_C 128
#define HID  256
#define OUT_C 2

// bucketing for CSR build: 512 nodes per bucket
#define BSHIFT 9
#define BNODES 512
#define EPB 4096   // edges per k_scatter block

typedef __attribute__((ext_vector_type(8))) short short8;
typedef __attribute__((ext_vector_type(4))) float f32x4;

__device__ __forceinline__ ushort f2bf(float f) {
  uint32_t u = __float_as_uint(f);
  uint32_t r = u + 0x7FFF + ((u >> 16) & 1);   // RNE
  return (ushort)(r >> 16);
}
__device__ __forceinline__ float bf2f(ushort b) {
  return __uint_as_float(((uint32_t)b) << 16);
}

// ---------------------------------------------------------------------------
// CSR build, pass 1: bucket histogram (LDS-aggregated)
// ---------------------------------------------------------------------------

__global__ void k_hist(const int* __restrict__ dst, int* __restrict__ bcount, int E) {
  __shared__ int h[256];
  int t = threadIdx.x;
  h[t] = 0;
  __syncthreads();
  for (int e = blockIdx.x * 256 + t; e < E; e += gridDim.x * 256)
    atomicAdd(&h[dst[e] >> BSHIFT], 1);
  __syncthreads();
  if (h[t]) atomicAdd(&bcount[t], h[t]);
}

// pass 2: scan bucket counts -> base & cursor (1 block, NB<=256)
__global__ void k_bucket_scan(const int* __restrict__ bcount,
                              int* __restrict__ bbase, int* __restrict__ bcursor) {
  __shared__ int sd[256];
  int t = threadIdx.x;
  int cnt = bcount[t];
  sd[t] = cnt;
  __syncthreads();
  for (int off = 1; off < 256; off <<= 1) {
    int v = (t >= off) ? sd[t - off] : 0;
    __syncthreads();
    sd[t] += v;
    __syncthreads();
  }
  int base = sd[t] - cnt;
  bbase[t] = base;
  bcursor[t] = base;
}

// pass 3: partition (src,dst) records into bucket regions
__global__ __launch_bounds__(256) void k_scatter(
    const int* __restrict__ src, const int* __restrict__ dst,
    int* __restrict__ bcursor, uint2* __restrict__ rec, int E) {
  __shared__ int h[256];
  __shared__ int bbase[256];
  __shared__ int lcur[256];
  int t = threadIdx.x;
  int e0 = blockIdx.x * EPB;
  int e1 = e0 + EPB < E ? e0 + EPB : E;
  h[t] = 0; lcur[t] = 0;
  __syncthreads();
  for (int e = e0 + t; e < e1; e += 256)
    atomicAdd(&h[dst[e] >> BSHIFT], 1);
  __syncthreads();
  if (h[t]) bbase[t] = atomicAdd(&bcursor[t], h[t]);
  __syncthreads();
  for (int e = e0 + t; e < e1; e += 256) {
    int d = dst[e];
    int b = d >> BSHIFT;
    int r = atomicAdd(&lcur[b], 1);
    rec[bbase[b] + r] = make_uint2((unsigned)src[e], (unsigned)d);
  }
}

// pass 4: per-bucket local CSR (one block per bucket)
__global__ __launch_bounds__(256) void k_csr(
    const uint2* __restrict__ rec, const int* __restrict__ bbase,
    const int* __restrict__ bcount,
    int* __restrict__ row_start, int* __restrict__ deg,
    int* __restrict__ csr, int n) {
  __shared__ int ldeg[BNODES];
  __shared__ int lexcl[BNODES];
  __shared__ int ssum[256];
  int t = threadIdx.x;
  int b = blockIdx.x;
  int node0 = b << BSHIFT;
  int ebase = bbase[b];
  int ecnt = bcount[b];

  ldeg[t] = 0; ldeg[t + 256] = 0;
  __syncthreads();
  for (int i = t; i < ecnt; i += 256)
    atomicAdd(&ldeg[(int)rec[ebase + i].y - node0], 1);
  __syncthreads();

  int v0 = ldeg[2 * t], v1 = ldeg[2 * t + 1];
  ssum[t] = v0 + v1;
  __syncthreads();
  for (int off = 1; off < 256; off <<= 1) {
    int v = (t >= off) ? ssum[t - off] : 0;
    __syncthreads();
    ssum[t] += v;
    __syncthreads();
  }
  int excl = ssum[t] - (v0 + v1);
  lexcl[2 * t] = excl;
  lexcl[2 * t + 1] = excl + v0;
  int node = node0 + 2 * t;
  if (node < n) { row_start[node] = ebase + excl; deg[node] = v0; }
  if (node + 1 < n) { row_start[node + 1] = ebase + excl + v0; deg[node + 1] = v1; }
  // reset ldeg as local cursor
  ldeg[2 * t] = 0; ldeg[2 * t + 1] = 0;
  __syncthreads();
  for (int i = t; i < ecnt; i += 256) {
    uint2 r = rec[ebase + i];
    int li = (int)r.y - node0;
    int k = atomicAdd(&ldeg[li], 1);
    csr[ebase + lexcl[li] + k] = (int)r.x;
  }
}

// ---------------------------------------------------------------------------
// fp32 -> bf16 casts
// ---------------------------------------------------------------------------

__global__ void k_cast(const float* __restrict__ in, ushort* __restrict__ out, int n4) {
  int i = blockIdx.x * 256 + threadIdx.x;
  if (i < n4) {
    float4 v = ((const float4*)in)[i];
    ushort4 o;
    o.x = f2bf(v.x); o.y = f2bf(v.y); o.z = f2bf(v.z); o.w = f2bf(v.w);
    ((ushort4*)out)[i] = o;
  }
}

__global__ void k_wcat(const float* __restrict__ Wl, const float* __restrict__ Wr,
                       ushort* __restrict__ Wcat) {
  int c = blockIdx.x, k = threadIdx.x;
  float v = (k < IN_C) ? Wl[(size_t)c * IN_C + k] : Wr[(size_t)c * IN_C + (k - IN_C)];
  Wcat[(size_t)c * (2 * IN_C) + k] = f2bf(v);
}

// ---------------------------------------------------------------------------
// Mean aggregation on bf16 rows: one wave per node, half-wave per row
// ---------------------------------------------------------------------------

__global__ void k_aggr(const ushort* __restrict__ xb, const int* __restrict__ csr,
                       const int* __restrict__ row_start, const int* __restrict__ deg,
                       ushort* __restrict__ aggr, int n) {
  int wid = threadIdx.x >> 6;
  int lane = threadIdx.x & 63;
  int node = blockIdx.x * 4 + wid;
  if (node >= n) return;
  int base = row_start[node];
  int d = deg[node];
  int half = lane >> 5, li = lane & 31;
  float s0 = 0.f, s1 = 0.f, s2 = 0.f, s3 = 0.f;
  int i = half;
  for (; i + 2 < d; i += 4) {
    int na = csr[base + i];
    int nb = csr[base + i + 2];
    uint2 va = ((const uint2*)(xb + (size_t)na * IN_C))[li];
    uint2 vb = ((const uint2*)(xb + (size_t)nb * IN_C))[li];
    s0 += bf2f((ushort)(va.x & 0xffff)) + bf2f((ushort)(vb.x & 0xffff));
    s1 += bf2f((ushort)(va.x >> 16))    + bf2f((ushort)(vb.x >> 16));
    s2 += bf2f((ushort)(va.y & 0xffff)) + bf2f((ushort)(vb.y & 0xffff));
    s3 += bf2f((ushort)(va.y >> 16))    + bf2f((ushort)(vb.y >> 16));
  }
  for (; i < d; i += 2) {
    int na = csr[base + i];
    uint2 va = ((const uint2*)(xb + (size_t)na * IN_C))[li];
    s0 += bf2f((ushort)(va.x & 0xffff));
    s1 += bf2f((ushort)(va.x >> 16));
    s2 += bf2f((ushort)(va.y & 0xffff));
    s3 += bf2f((ushort)(va.y >> 16));
  }
  s0 += __shfl_xor(s0, 32);
  s1 += __shfl_xor(s1, 32);
  s2 += __shfl_xor(s2, 32);
  s3 += __shfl_xor(s3, 32);
  if (half == 0) {
    float inv = 1.0f / (float)(d > 1 ? d : 1);
    ushort4 o;
    o.x = f2bf(s0 * inv); o.y = f2bf(s1 * inv);
    o.z = f2bf(s2 * inv); o.w = f2bf(s3 * inv);
    ((ushort4*)(aggr + (size_t)node * IN_C))[li] = o;
  }
}

// ---------------------------------------------------------------------------
// Fused SAGE GEMM (bf16 MFMA) + relu + per-graph max-pool (registers only)
// ---------------------------------------------------------------------------

__global__ __launch_bounds__(256) void k_gemm_pool(
    const ushort* __restrict__ aggrb, const ushort* __restrict__ xb,
    const ushort* __restrict__ Wcat, const float* __restrict__ bl,
    const int* __restrict__ batch, float* __restrict__ hp, int n) {
  __shared__ ushort sA[64][40];
  __shared__ ushort sB[256][40];
  __shared__ float sbl[256];
  __shared__ int sBatch[64];

  int t = threadIdx.x;
  int n0 = blockIdx.x * 64;
  sbl[t] = bl[t];
  if (t < 64) sBatch[t] = (n0 + t < n) ? batch[n0 + t] : -1;

  int lane = t & 63, w = t >> 6;
  int q = lane >> 4, m = lane & 15;

  f32x4 acc[4][4] = {};
  int rA = t >> 2, kA = (t & 3) * 8;

  for (int k0 = 0; k0 < 2 * IN_C; k0 += 32) {
    __syncthreads();
    int gn = n0 + rA; gn = gn < n ? gn : n - 1;
    const ushort* srcA = (k0 < IN_C) ? (aggrb + (size_t)gn * IN_C + k0 + kA)
                                     : (xb + (size_t)gn * IN_C + (k0 - IN_C) + kA);
    *(uint4*)&sA[rA][kA] = *(const uint4*)srcA;
#pragma unroll
    for (int it = 0; it < 4; ++it) {
      int j = it * 256 + t;
      int c = j >> 2, kB = (j & 3) * 8;
      *(uint4*)&sB[c][kB] = *(const uint4*)(Wcat + (size_t)c * (2 * IN_C) + k0 + kB);
    }
    __syncthreads();

    short8 af[4], bf[4];
#pragma unroll
    for (int rt = 0; rt < 4; ++rt) af[rt] = *(const short8*)&sA[rt * 16 + m][q * 8];
#pragma unroll
    for (int ct = 0; ct < 4; ++ct) bf[ct] = *(const short8*)&sB[w * 64 + ct * 16 + m][q * 8];
#pragma unroll
    for (int rt = 0; rt < 4; ++rt)
#pragma unroll
      for (int ct = 0; ct < 4; ++ct)
        acc[rt][ct] = __builtin_amdgcn_mfma_f32_16x16x32_bf16(af[rt], bf[ct], acc[rt][ct], 0, 0, 0);
  }

  int last = n - 1 - n0; last = last < 63 ? last : 63;
  int gA = sBatch[0];
  int gB = sBatch[last];
#pragma unroll
  for (int ct = 0; ct < 4; ++ct) {
    int col = w * 64 + ct * 16 + m;
    float bias = sbl[col];
    float mA = 0.f, mB = 0.f;
#pragma unroll
    for (int rt = 0; rt < 4; ++rt) {
#pragma unroll
      for (int i = 0; i < 4; ++i) {
        int lr = rt * 16 + q * 4 + i;
        if (n0 + lr < n) {
          float v = fmaxf(acc[rt][ct][i] + bias, 0.f);
          if (sBatch[lr] == gA) mA = fmaxf(mA, v);
          else mB = fmaxf(mB, v);
        }
      }
    }
    mA = fmaxf(mA, __shfl_xor(mA, 16)); mA = fmaxf(mA, __shfl_xor(mA, 32));
    mB = fmaxf(mB, __shfl_xor(mB, 16)); mB = fmaxf(mB, __shfl_xor(mB, 32));
    if (q == 0) {
      atomicMax((int*)&hp[(size_t)gA * HID + col], __float_as_int(mA));
      if (gB != gA) atomicMax((int*)&hp[(size_t)gB * HID + col], __float_as_int(mB));
    }
  }
}

// ---------------------------------------------------------------------------

__global__ void k_root(const int* __restrict__ batch, int* __restrict__ root, int n) {
  int i = blockIdx.x * 256 + threadIdx.x;
  if (i < n) {
    int g = batch[i];
    if (i == 0 || batch[i - 1] != g) root[g] = i;
  }
}

// ---------------------------------------------------------------------------
// Tail MLP (fp32), one block per graph
// ---------------------------------------------------------------------------

__global__ __launch_bounds__(256) void k_mlp2(
    const float* __restrict__ x, const float* __restrict__ hp,
    const int* __restrict__ root,
    const float* __restrict__ W0, const float* __restrict__ b0,
    const float* __restrict__ W1, const float* __restrict__ b1,
    const float* __restrict__ W2, const float* __restrict__ b2,
    float* __restrict__ out) {
  __shared__ float xr[IN_C];
  __shared__ float cat[2 * HID];
  __shared__ float h2r[HID];
  __shared__ float red[8];

  int g = blockIdx.x;
  int t = threadIdx.x;
  int rg = root[g];
  if (t < IN_C) xr[t] = x[(size_t)rg * IN_C + t];
  __syncthreads();

  float a0 = b0[t];
  const float* w0 = W0 + (size_t)t * IN_C;
#pragma unroll 4
  for (int k = 0; k < IN_C; ++k) a0 += xr[k] * w0[k];
  cat[t] = fmaxf(a0, 0.f);
  cat[HID + t] = hp[(size_t)g * HID + t];
  __syncthreads();

  float a1 = b1[t];
  const float* w1 = W1 + (size_t)t * (2 * HID);
#pragma unroll 4
  for (int j = 0; j < 2 * HID; ++j) a1 += cat[j] * w1[j];
  h2r[t] = fmaxf(a1, 0.f);
  __syncthreads();

  float p0 = h2r[t] * W2[t];
  float p1 = h2r[t] * W2[HID + t];
  for (int off = 32; off > 0; off >>= 1) {
    p0 += __shfl_down(p0, off);
    p1 += __shfl_down(p1, off);
  }
  int lane = t & 63, wid = t >> 6;
  if (lane == 0) { red[wid * 2] = p0; red[wid * 2 + 1] = p1; }
  __syncthreads();
  if (t == 0) {
    float l0 = b2[0] + red[0] + red[2] + red[4] + red[6];
    float l1 = b2[1] + red[1] + red[3] + red[5] + red[7];
    float mx = fmaxf(l0, l1);
    float ls = logf(expf(l0 - mx) + expf(l1 - mx));
    out[(size_t)g * 2 + 0] = l0 - mx - ls;
    out[(size_t)g * 2 + 1] = l1 - mx - ls;
  }
}

// ---------------------------------------------------------------------------

extern "C" void kernel_launch(void* const* d_in, const int* in_sizes, int n_in,
                              void* d_out, int out_size, void* d_ws, size_t ws_size,
                              hipStream_t stream) {
  const float* x  = (const float*)d_in[0];
  const int* ei   = (const int*)d_in[1];
  const int* batch= (const int*)d_in[2];
  const float* Wl = (const float*)d_in[3];
  const float* bl = (const float*)d_in[4];
  const float* Wr = (const float*)d_in[5];
  const float* W0 = (const float*)d_in[6];
  const float* b0 = (const float*)d_in[7];
  const float* W1 = (const float*)d_in[8];
  const float* b1 = (const float*)d_in[9];
  const float* W2 = (const float*)d_in[10];
  const float* b2 = (const float*)d_in[11];
  float* out = (float*)d_out;

  const int N = in_sizes[0] / IN_C;
  const int E = in_sizes[1] / 2;
  const int G = out_size / OUT_C;
  const int* src = ei;
  const int* dst = ei + E;
  const int NB = (N + BNODES - 1) >> BSHIFT;   // 196 for N=100000

  char* w = (char*)d_ws;
  int* deg       = (int*)w; w += (size_t)N * 4;
  int* row_start = (int*)w; w += (size_t)N * 4;
  int* bcount    = (int*)w; w += 1024;
  int* bbase     = (int*)w; w += 1024;
  int* bcursor   = (int*)w; w += 1024;
  int* root      = (int*)w; w += (size_t)G * 4;
  w = (char*)(((uintptr_t)w + 255) & ~(uintptr_t)255);
  int* csr       = (int*)w; w += (size_t)E * 4;
  w = (char*)(((uintptr_t)w + 255) & ~(uintptr_t)255);
  ushort* xb     = (ushort*)w; w += (size_t)N * IN_C * 2;
  ushort* aggrb  = (ushort*)w; w += (size_t)N * IN_C * 2;
  ushort* Wcat   = (ushort*)w; w += (size_t)HID * (2 * IN_C) * 2;
  float* hp      = (float*)w; w += (size_t)G * HID * 4;
  // rec aliases aggrb: rec dead before k_aggr writes aggrb (E*8 <= N*IN_C*2)
  uint2* rec     = (uint2*)aggrb;

  hipMemsetAsync(bcount, 0, 1024, stream);
  hipMemsetAsync(hp, 0, (size_t)G * HID * 4, stream);

  k_cast<<<((N * IN_C / 4) + 255) / 256, 256, 0, stream>>>(x, xb, N * IN_C / 4);
  k_wcat<<<HID, 2 * IN_C, 0, stream>>>(Wl, Wr, Wcat);
  k_hist<<<1024, 256, 0, stream>>>(dst, bcount, E);
  k_bucket_scan<<<1, 256, 0, stream>>>(bcount, bbase, bcursor);
  k_scatter<<<(E + EPB - 1) / EPB, 256, 0, stream>>>(src, dst, bcursor, rec, E);
  k_csr<<<NB, 256, 0, stream>>>(rec, bbase, bcount, row_start, deg, csr, N);
  k_root<<<(N + 255) / 256, 256, 0, stream>>>(batch, root, N);
  k_aggr<<<(N + 3) / 4, 256, 0, stream>>>(xb, csr, row_start, deg, aggrb, N);
  k_gemm_pool<<<(N + 63) / 64, 256, 0, stream>>>(aggrb, xb, Wcat, bl, batch, hp, N);
  k_mlp2<<<G, 256, 0, stream>>>(x, hp, root, W0, b0, W1, b1, W2, b2, out);
}

// Round 4
// 346.338 us; speedup vs baseline: 3.4051x; 1.0082x over previous
//
#include <hip/hip_runtime.h>
#include <hip/hip_bf16.h>
#include <math.h>
#include <stdint.h>

#define IN_C 128
#define HID  256
#define OUT_C 2

// bucketing for CSR build: 512 nodes per bucket
#define BSHIFT 9
#define BNODES 512
#define EPB 4096   // edges per k_scatter block

typedef __attribute__((ext_vector_type(8))) short short8;
typedef __attribute__((ext_vector_type(4))) float f32x4;

__device__ __forceinline__ ushort f2bf(float f) {
  uint32_t u = __float_as_uint(f);
  uint32_t r = u + 0x7FFF + ((u >> 16) & 1);   // RNE
  return (ushort)(r >> 16);
}
__device__ __forceinline__ float bf2f(ushort b) {
  return __uint_as_float(((uint32_t)b) << 16);
}

// ---------------------------------------------------------------------------
// CSR build, pass 1: bucket histogram (LDS-aggregated)
// ---------------------------------------------------------------------------

__global__ void k_hist(const int* __restrict__ dst, int* __restrict__ bcount, int E) {
  __shared__ int h[256];
  int t = threadIdx.x;
  h[t] = 0;
  __syncthreads();
  for (int e = blockIdx.x * 256 + t; e < E; e += gridDim.x * 256)
    atomicAdd(&h[dst[e] >> BSHIFT], 1);
  __syncthreads();
  if (h[t]) atomicAdd(&bcount[t], h[t]);
}

// pass 2: scan bucket counts -> base & cursor (1 block, NB<=256)
__global__ void k_bucket_scan(const int* __restrict__ bcount,
                              int* __restrict__ bbase, int* __restrict__ bcursor) {
  __shared__ int sd[256];
  int t = threadIdx.x;
  int cnt = bcount[t];
  sd[t] = cnt;
  __syncthreads();
  for (int off = 1; off < 256; off <<= 1) {
    int v = (t >= off) ? sd[t - off] : 0;
    __syncthreads();
    sd[t] += v;
    __syncthreads();
  }
  int base = sd[t] - cnt;
  bbase[t] = base;
  bcursor[t] = base;
}

// pass 3: partition (src,dst) records into bucket regions
__global__ __launch_bounds__(256) void k_scatter(
    const int* __restrict__ src, const int* __restrict__ dst,
    int* __restrict__ bcursor, uint2* __restrict__ rec, int E) {
  __shared__ int h[256];
  __shared__ int bbase[256];
  __shared__ int lcur[256];
  int t = threadIdx.x;
  int e0 = blockIdx.x * EPB;
  int e1 = e0 + EPB < E ? e0 + EPB : E;
  h[t] = 0; lcur[t] = 0;
  __syncthreads();
  for (int e = e0 + t; e < e1; e += 256)
    atomicAdd(&h[dst[e] >> BSHIFT], 1);
  __syncthreads();
  if (h[t]) bbase[t] = atomicAdd(&bcursor[t], h[t]);
  __syncthreads();
  for (int e = e0 + t; e < e1; e += 256) {
    int d = dst[e];
    int b = d >> BSHIFT;
    int r = atomicAdd(&lcur[b], 1);
    rec[bbase[b] + r] = make_uint2((unsigned)src[e], (unsigned)d);
  }
}

// pass 4: per-bucket local CSR (one block per bucket)
__global__ __launch_bounds__(256) void k_csr(
    const uint2* __restrict__ rec, const int* __restrict__ bbase,
    const int* __restrict__ bcount,
    int* __restrict__ row_start, int* __restrict__ deg,
    int* __restrict__ csr, int n) {
  __shared__ int ldeg[BNODES];
  __shared__ int lexcl[BNODES];
  __shared__ int ssum[256];
  int t = threadIdx.x;
  int b = blockIdx.x;
  int node0 = b << BSHIFT;
  int ebase = bbase[b];
  int ecnt = bcount[b];

  ldeg[t] = 0; ldeg[t + 256] = 0;
  __syncthreads();
  for (int i = t; i < ecnt; i += 256)
    atomicAdd(&ldeg[(int)rec[ebase + i].y - node0], 1);
  __syncthreads();

  int v0 = ldeg[2 * t], v1 = ldeg[2 * t + 1];
  ssum[t] = v0 + v1;
  __syncthreads();
  for (int off = 1; off < 256; off <<= 1) {
    int v = (t >= off) ? ssum[t - off] : 0;
    __syncthreads();
    ssum[t] += v;
    __syncthreads();
  }
  int excl = ssum[t] - (v0 + v1);
  lexcl[2 * t] = excl;
  lexcl[2 * t + 1] = excl + v0;
  int node = node0 + 2 * t;
  if (node < n) { row_start[node] = ebase + excl; deg[node] = v0; }
  if (node + 1 < n) { row_start[node + 1] = ebase + excl + v0; deg[node + 1] = v1; }
  ldeg[2 * t] = 0; ldeg[2 * t + 1] = 0;
  __syncthreads();
  for (int i = t; i < ecnt; i += 256) {
    uint2 r = rec[ebase + i];
    int li = (int)r.y - node0;
    int k = atomicAdd(&ldeg[li], 1);
    csr[ebase + lexcl[li] + k] = (int)r.x;
  }
}

// ---------------------------------------------------------------------------
// fp32 -> bf16 casts
// ---------------------------------------------------------------------------

__global__ void k_cast(const float* __restrict__ in, ushort* __restrict__ out, int n4) {
  int i = blockIdx.x * 256 + threadIdx.x;
  if (i < n4) {
    float4 v = ((const float4*)in)[i];
    ushort4 o;
    o.x = f2bf(v.x); o.y = f2bf(v.y); o.z = f2bf(v.z); o.w = f2bf(v.w);
    ((ushort4*)out)[i] = o;
  }
}

__global__ void k_wcat(const float* __restrict__ Wl, const float* __restrict__ Wr,
                       ushort* __restrict__ Wcat) {
  int c = blockIdx.x, k = threadIdx.x;
  float v = (k < IN_C) ? Wl[(size_t)c * IN_C + k] : Wr[(size_t)c * IN_C + (k - IN_C)];
  Wcat[(size_t)c * (2 * IN_C) + k] = f2bf(v);
}

// ---------------------------------------------------------------------------
// Mean aggregation: one wave per node, quarter-wave (16 lanes) per neighbor
// row, uint4 (8 bf16) per lane, 4 rows in flight -> high MLP. fp32 accum.
// ---------------------------------------------------------------------------

__device__ __forceinline__ void acc8(float* s, uint4 v) {
  s[0] += __uint_as_float(v.x << 16);
  s[1] += __uint_as_float(v.x & 0xffff0000u);
  s[2] += __uint_as_float(v.y << 16);
  s[3] += __uint_as_float(v.y & 0xffff0000u);
  s[4] += __uint_as_float(v.z << 16);
  s[5] += __uint_as_float(v.z & 0xffff0000u);
  s[6] += __uint_as_float(v.w << 16);
  s[7] += __uint_as_float(v.w & 0xffff0000u);
}

__global__ void k_aggr(const ushort* __restrict__ xb, const int* __restrict__ csr,
                       const int* __restrict__ row_start, const int* __restrict__ deg,
                       ushort* __restrict__ aggr, int n) {
  int wid = threadIdx.x >> 6;
  int lane = threadIdx.x & 63;
  int node = blockIdx.x * 4 + wid;
  if (node >= n) return;
  int base = row_start[node];
  int d = deg[node];
  int q = lane >> 4, li = lane & 15;
  float s[8] = {};
  int i = q;
  for (; i + 12 < d; i += 16) {   // 4 neighbors in flight per lane
    int n0 = csr[base + i];
    int n1 = csr[base + i + 4];
    int n2 = csr[base + i + 8];
    int n3 = csr[base + i + 12];
    uint4 a = ((const uint4*)(xb + (size_t)n0 * IN_C))[li];
    uint4 b = ((const uint4*)(xb + (size_t)n1 * IN_C))[li];
    uint4 c = ((const uint4*)(xb + (size_t)n2 * IN_C))[li];
    uint4 e = ((const uint4*)(xb + (size_t)n3 * IN_C))[li];
    acc8(s, a); acc8(s, b); acc8(s, c); acc8(s, e);
  }
  for (; i < d; i += 4) {
    int n0 = csr[base + i];
    uint4 a = ((const uint4*)(xb + (size_t)n0 * IN_C))[li];
    acc8(s, a);
  }
  // combine the 4 quarters (same columns, different neighbor subsets)
#pragma unroll
  for (int j = 0; j < 8; ++j) {
    s[j] += __shfl_xor(s[j], 16);
    s[j] += __shfl_xor(s[j], 32);
  }
  if (q == 0) {
    float inv = 1.0f / (float)(d > 1 ? d : 1);
    uint4 o;
    o.x = (uint32_t)f2bf(s[0] * inv) | ((uint32_t)f2bf(s[1] * inv) << 16);
    o.y = (uint32_t)f2bf(s[2] * inv) | ((uint32_t)f2bf(s[3] * inv) << 16);
    o.z = (uint32_t)f2bf(s[4] * inv) | ((uint32_t)f2bf(s[5] * inv) << 16);
    o.w = (uint32_t)f2bf(s[6] * inv) | ((uint32_t)f2bf(s[7] * inv) << 16);
    ((uint4*)(aggr + (size_t)node * IN_C))[li] = o;
  }
}

// ---------------------------------------------------------------------------
// Fused SAGE GEMM (bf16 MFMA) + relu + per-graph max-pool.
// Block = 128 nodes x 256 cols; 4 waves, each 128x64 via 16x16x32 MFMA
// (8 row-tiles x 4 col-tiles). Pool in registers; <=2 graphs per 128-window.
// ---------------------------------------------------------------------------

__global__ __launch_bounds__(256, 2) void k_gemm_pool(
    const ushort* __restrict__ aggrb, const ushort* __restrict__ xb,
    const ushort* __restrict__ Wcat, const float* __restrict__ bl,
    const int* __restrict__ batch, float* __restrict__ hp, int n) {
  __shared__ ushort sA[128][40];
  __shared__ ushort sB[256][40];
  __shared__ float sbl[256];
  __shared__ int sBatch[128];

  int t = threadIdx.x;
  int n0 = blockIdx.x * 128;
  sbl[t] = bl[t];
  if (t < 128) sBatch[t] = (n0 + t < n) ? batch[n0 + t] : -1;

  int lane = t & 63, w = t >> 6;
  int q = lane >> 4, m = lane & 15;

  f32x4 acc[8][4] = {};

  for (int k0 = 0; k0 < 2 * IN_C; k0 += 32) {
    __syncthreads();
    // stage A: 128 rows x 32 k (2 uint4 per thread)
#pragma unroll
    for (int it = 0; it < 2; ++it) {
      int j = it * 256 + t;
      int r = j >> 2, kA = (j & 3) * 8;
      int gn = n0 + r; gn = gn < n ? gn : n - 1;
      const ushort* srcA = (k0 < IN_C) ? (aggrb + (size_t)gn * IN_C + k0 + kA)
                                       : (xb + (size_t)gn * IN_C + (k0 - IN_C) + kA);
      *(uint4*)&sA[r][kA] = *(const uint4*)srcA;
    }
    // stage B: 256 cols x 32 k (4 uint4 per thread)
#pragma unroll
    for (int it = 0; it < 4; ++it) {
      int j = it * 256 + t;
      int c = j >> 2, kB = (j & 3) * 8;
      *(uint4*)&sB[c][kB] = *(const uint4*)(Wcat + (size_t)c * (2 * IN_C) + k0 + kB);
    }
    __syncthreads();

    short8 af[8], bf[4];
#pragma unroll
    for (int rt = 0; rt < 8; ++rt) af[rt] = *(const short8*)&sA[rt * 16 + m][q * 8];
#pragma unroll
    for (int ct = 0; ct < 4; ++ct) bf[ct] = *(const short8*)&sB[w * 64 + ct * 16 + m][q * 8];
#pragma unroll
    for (int rt = 0; rt < 8; ++rt)
#pragma unroll
      for (int ct = 0; ct < 4; ++ct)
        acc[rt][ct] = __builtin_amdgcn_mfma_f32_16x16x32_bf16(af[rt], bf[ct], acc[rt][ct], 0, 0, 0);
  }

  int last = n - 1 - n0; last = last < 127 ? last : 127;
  int gA = sBatch[0];
  int gB = sBatch[last];
#pragma unroll
  for (int ct = 0; ct < 4; ++ct) {
    int col = w * 64 + ct * 16 + m;
    float bias = sbl[col];
    float mA = 0.f, mB = 0.f;
#pragma unroll
    for (int rt = 0; rt < 8; ++rt) {
#pragma unroll
      for (int i = 0; i < 4; ++i) {
        int lr = rt * 16 + q * 4 + i;
        if (n0 + lr < n) {
          float v = fmaxf(acc[rt][ct][i] + bias, 0.f);
          if (sBatch[lr] == gA) mA = fmaxf(mA, v);
          else mB = fmaxf(mB, v);
        }
      }
    }
    mA = fmaxf(mA, __shfl_xor(mA, 16)); mA = fmaxf(mA, __shfl_xor(mA, 32));
    mB = fmaxf(mB, __shfl_xor(mB, 16)); mB = fmaxf(mB, __shfl_xor(mB, 32));
    if (q == 0) {
      atomicMax((int*)&hp[(size_t)gA * HID + col], __float_as_int(mA));
      if (gB != gA) atomicMax((int*)&hp[(size_t)gB * HID + col], __float_as_int(mB));
    }
  }
}

// ---------------------------------------------------------------------------

__global__ void k_root(const int* __restrict__ batch, int* __restrict__ root, int n) {
  int i = blockIdx.x * 256 + threadIdx.x;
  if (i < n) {
    int g = batch[i];
    if (i == 0 || batch[i - 1] != g) root[g] = i;
  }
}

// ---------------------------------------------------------------------------
// Tail MLP (fp32), one block per graph
// ---------------------------------------------------------------------------

__global__ __launch_bounds__(256) void k_mlp2(
    const float* __restrict__ x, const float* __restrict__ hp,
    const int* __restrict__ root,
    const float* __restrict__ W0, const float* __restrict__ b0,
    const float* __restrict__ W1, const float* __restrict__ b1,
    const float* __restrict__ W2, const float* __restrict__ b2,
    float* __restrict__ out) {
  __shared__ float xr[IN_C];
  __shared__ float cat[2 * HID];
  __shared__ float h2r[HID];
  __shared__ float red[8];

  int g = blockIdx.x;
  int t = threadIdx.x;
  int rg = root[g];
  if (t < IN_C) xr[t] = x[(size_t)rg * IN_C + t];
  __syncthreads();

  float a0 = b0[t];
  const float* w0 = W0 + (size_t)t * IN_C;
#pragma unroll 4
  for (int k = 0; k < IN_C; ++k) a0 += xr[k] * w0[k];
  cat[t] = fmaxf(a0, 0.f);
  cat[HID + t] = hp[(size_t)g * HID + t];
  __syncthreads();

  float a1 = b1[t];
  const float* w1 = W1 + (size_t)t * (2 * HID);
#pragma unroll 4
  for (int j = 0; j < 2 * HID; ++j) a1 += cat[j] * w1[j];
  h2r[t] = fmaxf(a1, 0.f);
  __syncthreads();

  float p0 = h2r[t] * W2[t];
  float p1 = h2r[t] * W2[HID + t];
  for (int off = 32; off > 0; off >>= 1) {
    p0 += __shfl_down(p0, off);
    p1 += __shfl_down(p1, off);
  }
  int lane = t & 63, wid = t >> 6;
  if (lane == 0) { red[wid * 2] = p0; red[wid * 2 + 1] = p1; }
  __syncthreads();
  if (t == 0) {
    float l0 = b2[0] + red[0] + red[2] + red[4] + red[6];
    float l1 = b2[1] + red[1] + red[3] + red[5] + red[7];
    float mx = fmaxf(l0, l1);
    float ls = logf(expf(l0 - mx) + expf(l1 - mx));
    out[(size_t)g * 2 + 0] = l0 - mx - ls;
    out[(size_t)g * 2 + 1] = l1 - mx - ls;
  }
}

// ---------------------------------------------------------------------------

extern "C" void kernel_launch(void* const* d_in, const int* in_sizes, int n_in,
                              void* d_out, int out_size, void* d_ws, size_t ws_size,
                              hipStream_t stream) {
  const float* x  = (const float*)d_in[0];
  const int* ei   = (const int*)d_in[1];
  const int* batch= (const int*)d_in[2];
  const float* Wl = (const float*)d_in[3];
  const float* bl = (const float*)d_in[4];
  const float* Wr = (const float*)d_in[5];
  const float* W0 = (const float*)d_in[6];
  const float* b0 = (const float*)d_in[7];
  const float* W1 = (const float*)d_in[8];
  const float* b1 = (const float*)d_in[9];
  const float* W2 = (const float*)d_in[10];
  const float* b2 = (const float*)d_in[11];
  float* out = (float*)d_out;

  const int N = in_sizes[0] / IN_C;
  const int E = in_sizes[1] / 2;
  const int G = out_size / OUT_C;
  const int* src = ei;
  const int* dst = ei + E;
  const int NB = (N + BNODES - 1) >> BSHIFT;

  char* w = (char*)d_ws;
  int* deg       = (int*)w; w += (size_t)N * 4;
  int* row_start = (int*)w; w += (size_t)N * 4;
  int* bcount    = (int*)w; w += 1024;
  int* bbase     = (int*)w; w += 1024;
  int* bcursor   = (int*)w; w += 1024;
  int* root      = (int*)w; w += (size_t)G * 4;
  w = (char*)(((uintptr_t)w + 255) & ~(uintptr_t)255);
  int* csr       = (int*)w; w += (size_t)E * 4;
  w = (char*)(((uintptr_t)w + 255) & ~(uintptr_t)255);
  ushort* xb     = (ushort*)w; w += (size_t)N * IN_C * 2;
  ushort* aggrb  = (ushort*)w; w += (size_t)N * IN_C * 2;
  ushort* Wcat   = (ushort*)w; w += (size_t)HID * (2 * IN_C) * 2;
  float* hp      = (float*)w; w += (size_t)G * HID * 4;
  uint2* rec     = (uint2*)aggrb;   // dead before k_aggr writes aggrb

  hipMemsetAsync(bcount, 0, 1024, stream);
  hipMemsetAsync(hp, 0, (size_t)G * HID * 4, stream);

  k_cast<<<((N * IN_C / 4) + 255) / 256, 256, 0, stream>>>(x, xb, N * IN_C / 4);
  k_wcat<<<HID, 2 * IN_C, 0, stream>>>(Wl, Wr, Wcat);
  k_hist<<<1024, 256, 0, stream>>>(dst, bcount, E);
  k_bucket_scan<<<1, 256, 0, stream>>>(bcount, bbase, bcursor);
  k_scatter<<<(E + EPB - 1) / EPB, 256, 0, stream>>>(src, dst, bcursor, rec, E);
  k_csr<<<NB, 256, 0, stream>>>(rec, bbase, bcount, row_start, deg, csr, N);
  k_root<<<(N + 255) / 256, 256, 0, stream>>>(batch, root, N);
  k_aggr<<<(N + 3) / 4, 256, 0, stream>>>(xb, csr, row_start, deg, aggrb, N);
  k_gemm_pool<<<(N + 127) / 128, 256, 0, stream>>>(aggrb, xb, Wcat, bl, batch, hp, N);
  k_mlp2<<<G, 256, 0, stream>>>(x, hp, root, W0, b0, W1, b1, W2, b2, out);
}

// Round 5
// 331.531 us; speedup vs baseline: 3.5572x; 1.0447x over previous
//
#include <hip/hip_runtime.h>
#include <hip/hip_bf16.h>
#include <math.h>
#include <stdint.h>

#define IN_C 128
#define HID  256
#define OUT_C 2

// bucketing for CSR build: 512 nodes per bucket
#define BSHIFT 9
#define BNODES 512
#define EPB 4096   // edges per k_scatter block

typedef __attribute__((ext_vector_type(8))) short short8;
typedef __attribute__((ext_vector_type(4))) float f32x4;
typedef __attribute__((ext_vector_type(2))) float f32x2;

#if defined(__has_builtin)
#if __has_builtin(__builtin_amdgcn_cvt_pk_f32_fp8) && __has_builtin(__builtin_amdgcn_cvt_pk_fp8_f32)
#define HAVE_FP8_CVT 1
#endif
#endif

__device__ __forceinline__ ushort f2bf(float f) {
  uint32_t u = __float_as_uint(f);
  uint32_t r = u + 0x7FFF + ((u >> 16) & 1);   // RNE
  return (ushort)(r >> 16);
}
__device__ __forceinline__ float bf2f(ushort b) {
  return __uint_as_float(((uint32_t)b) << 16);
}

#ifndef HAVE_FP8_CVT
// manual OCP e4m3 encode/decode fallbacks
__device__ __forceinline__ uint32_t f2fp8_1(float f) {
  uint32_t u = __float_as_uint(f);
  uint32_t s = (u >> 24) & 0x80;
  float a = fabsf(f);
  if (a >= 448.f) return s | 0x7E;
  if (a < 0.015625f) {                 // subnormal: m = round(a*512)
    uint32_t m = (uint32_t)(a * 512.f + 0.5f);
    return s | m;                       // m==8 rolls into e=1,m=0
  }
  uint32_t r = u & 0x7fffffff;
  r += 0x7FFFF + ((r >> 20) & 1);       // RNE to 3 mantissa bits
  uint32_t e = (r >> 23) - 127;
  if ((int)e > 8) return s | 0x7E;
  return s | ((e + 7) << 3) | ((r >> 20) & 7);
}
__device__ __forceinline__ float fp8_2f(uint32_t b) {
  uint32_t s = (b & 0x80) << 24;
  uint32_t e = (b >> 3) & 0xF, m = b & 7;
  if (e == 0) { float f = (float)m * 0.001953125f; return s ? -f : f; }
  return __uint_as_float(s | ((e + 120) << 23) | (m << 20));
}
#endif

// accumulate 8 fp8 elements (one uint2) into s[0..7]
__device__ __forceinline__ void acc8f8(float* s, uint2 v) {
#ifdef HAVE_FP8_CVT
  f32x2 a = __builtin_amdgcn_cvt_pk_f32_fp8(v.x, false);
  f32x2 b = __builtin_amdgcn_cvt_pk_f32_fp8(v.x, true);
  f32x2 c = __builtin_amdgcn_cvt_pk_f32_fp8(v.y, false);
  f32x2 d = __builtin_amdgcn_cvt_pk_f32_fp8(v.y, true);
  s[0] += a.x; s[1] += a.y; s[2] += b.x; s[3] += b.y;
  s[4] += c.x; s[5] += c.y; s[6] += d.x; s[7] += d.y;
#else
  s[0] += fp8_2f(v.x & 0xff);        s[1] += fp8_2f((v.x >> 8) & 0xff);
  s[2] += fp8_2f((v.x >> 16) & 0xff); s[3] += fp8_2f(v.x >> 24);
  s[4] += fp8_2f(v.y & 0xff);        s[5] += fp8_2f((v.y >> 8) & 0xff);
  s[6] += fp8_2f((v.y >> 16) & 0xff); s[7] += fp8_2f(v.y >> 24);
#endif
}

// ---------------------------------------------------------------------------
// CSR build, pass 1: bucket histogram (LDS-aggregated)
// ---------------------------------------------------------------------------

__global__ void k_hist(const int* __restrict__ dst, int* __restrict__ bcount, int E) {
  __shared__ int h[256];
  int t = threadIdx.x;
  h[t] = 0;
  __syncthreads();
  for (int e = blockIdx.x * 256 + t; e < E; e += gridDim.x * 256)
    atomicAdd(&h[dst[e] >> BSHIFT], 1);
  __syncthreads();
  if (h[t]) atomicAdd(&bcount[t], h[t]);
}

// pass 2: scan bucket counts -> base & cursor (1 block, NB<=256)
__global__ void k_bucket_scan(const int* __restrict__ bcount,
                              int* __restrict__ bbase, int* __restrict__ bcursor) {
  __shared__ int sd[256];
  int t = threadIdx.x;
  int cnt = bcount[t];
  sd[t] = cnt;
  __syncthreads();
  for (int off = 1; off < 256; off <<= 1) {
    int v = (t >= off) ? sd[t - off] : 0;
    __syncthreads();
    sd[t] += v;
    __syncthreads();
  }
  int base = sd[t] - cnt;
  bbase[t] = base;
  bcursor[t] = base;
}

// pass 3: partition packed (src<<9 | dst&511) records into bucket regions
__global__ __launch_bounds__(256) void k_scatter(
    const int* __restrict__ src, const int* __restrict__ dst,
    int* __restrict__ bcursor, uint32_t* __restrict__ rec, int E) {
  __shared__ int h[256];
  __shared__ int bbase[256];
  __shared__ int lcur[256];
  int t = threadIdx.x;
  int e0 = blockIdx.x * EPB;
  int e1 = e0 + EPB < E ? e0 + EPB : E;
  h[t] = 0; lcur[t] = 0;
  __syncthreads();
  for (int e = e0 + t; e < e1; e += 256)
    atomicAdd(&h[dst[e] >> BSHIFT], 1);
  __syncthreads();
  if (h[t]) bbase[t] = atomicAdd(&bcursor[t], h[t]);
  __syncthreads();
  for (int e = e0 + t; e < e1; e += 256) {
    int d = dst[e];
    int b = d >> BSHIFT;
    int r = atomicAdd(&lcur[b], 1);
    rec[bbase[b] + r] = ((uint32_t)src[e] << BSHIFT) | ((uint32_t)d & (BNODES - 1));
  }
}

// pass 4: per-bucket local CSR (one block per bucket)
__global__ __launch_bounds__(256) void k_csr(
    const uint32_t* __restrict__ rec, const int* __restrict__ bbase,
    const int* __restrict__ bcount,
    int* __restrict__ row_start, int* __restrict__ deg,
    int* __restrict__ csr, int n) {
  __shared__ int ldeg[BNODES];
  __shared__ int lexcl[BNODES];
  __shared__ int ssum[256];
  int t = threadIdx.x;
  int b = blockIdx.x;
  int node0 = b << BSHIFT;
  int ebase = bbase[b];
  int ecnt = bcount[b];

  ldeg[t] = 0; ldeg[t + 256] = 0;
  __syncthreads();
  for (int i = t; i < ecnt; i += 256)
    atomicAdd(&ldeg[rec[ebase + i] & (BNODES - 1)], 1);
  __syncthreads();

  int v0 = ldeg[2 * t], v1 = ldeg[2 * t + 1];
  ssum[t] = v0 + v1;
  __syncthreads();
  for (int off = 1; off < 256; off <<= 1) {
    int v = (t >= off) ? ssum[t - off] : 0;
    __syncthreads();
    ssum[t] += v;
    __syncthreads();
  }
  int excl = ssum[t] - (v0 + v1);
  lexcl[2 * t] = excl;
  lexcl[2 * t + 1] = excl + v0;
  int node = node0 + 2 * t;
  if (node < n) { row_start[node] = ebase + excl; deg[node] = v0; }
  if (node + 1 < n) { row_start[node + 1] = ebase + excl + v0; deg[node + 1] = v1; }
  ldeg[2 * t] = 0; ldeg[2 * t + 1] = 0;
  __syncthreads();
  for (int i = t; i < ecnt; i += 256) {
    uint32_t r = rec[ebase + i];
    int li = r & (BNODES - 1);
    int k = atomicAdd(&ldeg[li], 1);
    csr[ebase + lexcl[li] + k] = (int)(r >> BSHIFT);
  }
}

// ---------------------------------------------------------------------------
// fp32 -> bf16 + fp8 cast in one pass (reads x once)
// ---------------------------------------------------------------------------

__global__ void k_cast(const float* __restrict__ in, ushort* __restrict__ outb,
                       uint32_t* __restrict__ outf8, int n4) {
  int i = blockIdx.x * 256 + threadIdx.x;
  if (i < n4) {
    float4 v = ((const float4*)in)[i];
    ushort4 o;
    o.x = f2bf(v.x); o.y = f2bf(v.y); o.z = f2bf(v.z); o.w = f2bf(v.w);
    ((ushort4*)outb)[i] = o;
#ifdef HAVE_FP8_CVT
    int p = __builtin_amdgcn_cvt_pk_fp8_f32(v.x, v.y, 0, false);
    p = __builtin_amdgcn_cvt_pk_fp8_f32(v.z, v.w, p, true);
    outf8[i] = (uint32_t)p;
#else
    outf8[i] = f2fp8_1(v.x) | (f2fp8_1(v.y) << 8) | (f2fp8_1(v.z) << 16) |
               (f2fp8_1(v.w) << 24);
#endif
  }
}

__global__ void k_wcat(const float* __restrict__ Wl, const float* __restrict__ Wr,
                       ushort* __restrict__ Wcat) {
  int c = blockIdx.x, k = threadIdx.x;
  float v = (k < IN_C) ? Wl[(size_t)c * IN_C + k] : Wr[(size_t)c * IN_C + (k - IN_C)];
  Wcat[(size_t)c * (2 * IN_C) + k] = f2bf(v);
}

// ---------------------------------------------------------------------------
// Mean aggregation on fp8 rows (128 B each): one wave per node, quarter-wave
// (16 lanes) per neighbor row, uint2 (8 fp8) per lane, 4 rows per load inst,
// 16 rows in flight. fp32 accumulate, bf16 out.
// ---------------------------------------------------------------------------

__global__ void k_aggr(const uint32_t* __restrict__ xf8, const int* __restrict__ csr,
                       const int* __restrict__ row_start, const int* __restrict__ deg,
                       ushort* __restrict__ aggr, int n) {
  int wid = threadIdx.x >> 6;
  int lane = threadIdx.x & 63;
  int node = blockIdx.x * 4 + wid;
  if (node >= n) return;
  int base = row_start[node];
  int d = deg[node];
  int q = lane >> 4, li = lane & 15;
  float s[8] = {};
  int i = q;
  for (; i + 12 < d; i += 16) {   // 4 neighbor rows in flight per quarter-lane
    int n0 = csr[base + i];
    int n1 = csr[base + i + 4];
    int n2 = csr[base + i + 8];
    int n3 = csr[base + i + 12];
    uint2 a = ((const uint2*)(xf8 + (size_t)n0 * (IN_C / 4)))[li];
    uint2 b = ((const uint2*)(xf8 + (size_t)n1 * (IN_C / 4)))[li];
    uint2 c = ((const uint2*)(xf8 + (size_t)n2 * (IN_C / 4)))[li];
    uint2 e = ((const uint2*)(xf8 + (size_t)n3 * (IN_C / 4)))[li];
    acc8f8(s, a); acc8f8(s, b); acc8f8(s, c); acc8f8(s, e);
  }
  for (; i < d; i += 4) {
    int n0 = csr[base + i];
    uint2 a = ((const uint2*)(xf8 + (size_t)n0 * (IN_C / 4)))[li];
    acc8f8(s, a);
  }
  // combine the 4 quarters (same columns, different neighbor subsets)
#pragma unroll
  for (int j = 0; j < 8; ++j) {
    s[j] += __shfl_xor(s[j], 16);
    s[j] += __shfl_xor(s[j], 32);
  }
  if (q == 0) {
    float inv = 1.0f / (float)(d > 1 ? d : 1);
    uint4 o;
    o.x = (uint32_t)f2bf(s[0] * inv) | ((uint32_t)f2bf(s[1] * inv) << 16);
    o.y = (uint32_t)f2bf(s[2] * inv) | ((uint32_t)f2bf(s[3] * inv) << 16);
    o.z = (uint32_t)f2bf(s[4] * inv) | ((uint32_t)f2bf(s[5] * inv) << 16);
    o.w = (uint32_t)f2bf(s[6] * inv) | ((uint32_t)f2bf(s[7] * inv) << 16);
    ((uint4*)(aggr + (size_t)node * IN_C))[li] = o;
  }
}

// ---------------------------------------------------------------------------
// Fused SAGE GEMM (bf16 MFMA) + relu + per-graph max-pool.
// Block = 128 nodes x 256 cols; 4 waves, each 128x64 via 16x16x32 MFMA.
// ---------------------------------------------------------------------------

__global__ __launch_bounds__(256, 2) void k_gemm_pool(
    const ushort* __restrict__ aggrb, const ushort* __restrict__ xb,
    const ushort* __restrict__ Wcat, const float* __restrict__ bl,
    const int* __restrict__ batch, float* __restrict__ hp, int n) {
  __shared__ ushort sA[128][40];
  __shared__ ushort sB[256][40];
  __shared__ float sbl[256];
  __shared__ int sBatch[128];

  int t = threadIdx.x;
  int n0 = blockIdx.x * 128;
  sbl[t] = bl[t];
  if (t < 128) sBatch[t] = (n0 + t < n) ? batch[n0 + t] : -1;

  int lane = t & 63, w = t >> 6;
  int q = lane >> 4, m = lane & 15;

  f32x4 acc[8][4] = {};

  for (int k0 = 0; k0 < 2 * IN_C; k0 += 32) {
    __syncthreads();
#pragma unroll
    for (int it = 0; it < 2; ++it) {
      int j = it * 256 + t;
      int r = j >> 2, kA = (j & 3) * 8;
      int gn = n0 + r; gn = gn < n ? gn : n - 1;
      const ushort* srcA = (k0 < IN_C) ? (aggrb + (size_t)gn * IN_C + k0 + kA)
                                       : (xb + (size_t)gn * IN_C + (k0 - IN_C) + kA);
      *(uint4*)&sA[r][kA] = *(const uint4*)srcA;
    }
#pragma unroll
    for (int it = 0; it < 4; ++it) {
      int j = it * 256 + t;
      int c = j >> 2, kB = (j & 3) * 8;
      *(uint4*)&sB[c][kB] = *(const uint4*)(Wcat + (size_t)c * (2 * IN_C) + k0 + kB);
    }
    __syncthreads();

    short8 af[8], bf[4];
#pragma unroll
    for (int rt = 0; rt < 8; ++rt) af[rt] = *(const short8*)&sA[rt * 16 + m][q * 8];
#pragma unroll
    for (int ct = 0; ct < 4; ++ct) bf[ct] = *(const short8*)&sB[w * 64 + ct * 16 + m][q * 8];
#pragma unroll
    for (int rt = 0; rt < 8; ++rt)
#pragma unroll
      for (int ct = 0; ct < 4; ++ct)
        acc[rt][ct] = __builtin_amdgcn_mfma_f32_16x16x32_bf16(af[rt], bf[ct], acc[rt][ct], 0, 0, 0);
  }

  int last = n - 1 - n0; last = last < 127 ? last : 127;
  int gA = sBatch[0];
  int gB = sBatch[last];
#pragma unroll
  for (int ct = 0; ct < 4; ++ct) {
    int col = w * 64 + ct * 16 + m;
    float bias = sbl[col];
    float mA = 0.f, mB = 0.f;
#pragma unroll
    for (int rt = 0; rt < 8; ++rt) {
#pragma unroll
      for (int i = 0; i < 4; ++i) {
        int lr = rt * 16 + q * 4 + i;
        if (n0 + lr < n) {
          float v = fmaxf(acc[rt][ct][i] + bias, 0.f);
          if (sBatch[lr] == gA) mA = fmaxf(mA, v);
          else mB = fmaxf(mB, v);
        }
      }
    }
    mA = fmaxf(mA, __shfl_xor(mA, 16)); mA = fmaxf(mA, __shfl_xor(mA, 32));
    mB = fmaxf(mB, __shfl_xor(mB, 16)); mB = fmaxf(mB, __shfl_xor(mB, 32));
    if (q == 0) {
      atomicMax((int*)&hp[(size_t)gA * HID + col], __float_as_int(mA));
      if (gB != gA) atomicMax((int*)&hp[(size_t)gB * HID + col], __float_as_int(mB));
    }
  }
}

// ---------------------------------------------------------------------------

__global__ void k_root(const int* __restrict__ batch, int* __restrict__ root, int n) {
  int i = blockIdx.x * 256 + threadIdx.x;
  if (i < n) {
    int g = batch[i];
    if (i == 0 || batch[i - 1] != g) root[g] = i;
  }
}

// ---------------------------------------------------------------------------
// Tail MLP (fp32), one block per graph
// ---------------------------------------------------------------------------

__global__ __launch_bounds__(256) void k_mlp2(
    const float* __restrict__ x, const float* __restrict__ hp,
    const int* __restrict__ root,
    const float* __restrict__ W0, const float* __restrict__ b0,
    const float* __restrict__ W1, const float* __restrict__ b1,
    const float* __restrict__ W2, const float* __restrict__ b2,
    float* __restrict__ out) {
  __shared__ float xr[IN_C];
  __shared__ float cat[2 * HID];
  __shared__ float h2r[HID];
  __shared__ float red[8];

  int g = blockIdx.x;
  int t = threadIdx.x;
  int rg = root[g];
  if (t < IN_C) xr[t] = x[(size_t)rg * IN_C + t];
  __syncthreads();

  float a0 = b0[t];
  const float* w0 = W0 + (size_t)t * IN_C;
#pragma unroll 4
  for (int k = 0; k < IN_C; ++k) a0 += xr[k] * w0[k];
  cat[t] = fmaxf(a0, 0.f);
  cat[HID + t] = hp[(size_t)g * HID + t];
  __syncthreads();

  float a1 = b1[t];
  const float* w1 = W1 + (size_t)t * (2 * HID);
#pragma unroll 4
  for (int j = 0; j < 2 * HID; ++j) a1 += cat[j] * w1[j];
  h2r[t] = fmaxf(a1, 0.f);
  __syncthreads();

  float p0 = h2r[t] * W2[t];
  float p1 = h2r[t] * W2[HID + t];
  for (int off = 32; off > 0; off >>= 1) {
    p0 += __shfl_down(p0, off);
    p1 += __shfl_down(p1, off);
  }
  int lane = t & 63, wid = t >> 6;
  if (lane == 0) { red[wid * 2] = p0; red[wid * 2 + 1] = p1; }
  __syncthreads();
  if (t == 0) {
    float l0 = b2[0] + red[0] + red[2] + red[4] + red[6];
    float l1 = b2[1] + red[1] + red[3] + red[5] + red[7];
    float mx = fmaxf(l0, l1);
    float ls = logf(expf(l0 - mx) + expf(l1 - mx));
    out[(size_t)g * 2 + 0] = l0 - mx - ls;
    out[(size_t)g * 2 + 1] = l1 - mx - ls;
  }
}

// ---------------------------------------------------------------------------

extern "C" void kernel_launch(void* const* d_in, const int* in_sizes, int n_in,
                              void* d_out, int out_size, void* d_ws, size_t ws_size,
                              hipStream_t stream) {
  const float* x  = (const float*)d_in[0];
  const int* ei   = (const int*)d_in[1];
  const int* batch= (const int*)d_in[2];
  const float* Wl = (const float*)d_in[3];
  const float* bl = (const float*)d_in[4];
  const float* Wr = (const float*)d_in[5];
  const float* W0 = (const float*)d_in[6];
  const float* b0 = (const float*)d_in[7];
  const float* W1 = (const float*)d_in[8];
  const float* b1 = (const float*)d_in[9];
  const float* W2 = (const float*)d_in[10];
  const float* b2 = (const float*)d_in[11];
  float* out = (float*)d_out;

  const int N = in_sizes[0] / IN_C;
  const int E = in_sizes[1] / 2;
  const int G = out_size / OUT_C;
  const int* src = ei;
  const int* dst = ei + E;
  const int NB = (N + BNODES - 1) >> BSHIFT;

  char* w = (char*)d_ws;
  int* deg       = (int*)w; w += (size_t)N * 4;
  int* row_start = (int*)w; w += (size_t)N * 4;
  int* bcount    = (int*)w; w += 1024;
  int* bbase     = (int*)w; w += 1024;
  int* bcursor   = (int*)w; w += 1024;
  int* root      = (int*)w; w += (size_t)G * 4;
  w = (char*)(((uintptr_t)w + 255) & ~(uintptr_t)255);
  int* csr       = (int*)w; w += (size_t)E * 4;
  w = (char*)(((uintptr_t)w + 255) & ~(uintptr_t)255);
  ushort* xb     = (ushort*)w; w += (size_t)N * IN_C * 2;
  uint32_t* xf8  = (uint32_t*)w; w += (size_t)N * IN_C;
  ushort* aggrb  = (ushort*)w; w += (size_t)N * IN_C * 2;
  ushort* Wcat   = (ushort*)w; w += (size_t)HID * (2 * IN_C) * 2;
  float* hp      = (float*)w; w += (size_t)G * HID * 4;
  uint32_t* rec  = (uint32_t*)aggrb;   // dead before k_aggr writes aggrb

  hipMemsetAsync(bcount, 0, 1024, stream);
  hipMemsetAsync(hp, 0, (size_t)G * HID * 4, stream);

  k_cast<<<((N * IN_C / 4) + 255) / 256, 256, 0, stream>>>(x, xb, xf8, N * IN_C / 4);
  k_wcat<<<HID, 2 * IN_C, 0, stream>>>(Wl, Wr, Wcat);
  k_hist<<<1024, 256, 0, stream>>>(dst, bcount, E);
  k_bucket_scan<<<1, 256, 0, stream>>>(bcount, bbase, bcursor);
  k_scatter<<<(E + EPB - 1) / EPB, 256, 0, stream>>>(src, dst, bcursor, rec, E);
  k_csr<<<NB, 256, 0, stream>>>(rec, bbase, bcount, row_start, deg, csr, N);
  k_root<<<(N + 255) / 256, 256, 0, stream>>>(batch, root, N);
  k_aggr<<<(N + 3) / 4, 256, 0, stream>>>(xf8, csr, row_start, deg, aggrb, N);
  k_gemm_pool<<<(N + 127) / 128, 256, 0, stream>>>(aggrb, xb, Wcat, bl, batch, hp, N);
  k_mlp2<<<G, 256, 0, stream>>>(x, hp, root, W0, b0, W1, b1, W2, b2, out);
}

// Round 6
// 331.275 us; speedup vs baseline: 3.5599x; 1.0008x over previous
//
#include <hip/hip_runtime.h>
#include <hip/hip_bf16.h>
#include <math.h>
#include <stdint.h>

#define IN_C 128
#define HID  256
#define OUT_C 2

// bucketing for CSR build: 512 nodes per bucket
#define BSHIFT 9
#define BNODES 512
#define EPB 4096   // edges per k_scatter block

typedef __attribute__((ext_vector_type(8))) short short8;
typedef __attribute__((ext_vector_type(4))) float f32x4;
typedef __attribute__((ext_vector_type(2))) float f32x2;

#if defined(__has_builtin)
#if __has_builtin(__builtin_amdgcn_cvt_pk_f32_fp8) && __has_builtin(__builtin_amdgcn_cvt_pk_fp8_f32)
#define HAVE_FP8_CVT 1
#endif
#if __has_builtin(__builtin_amdgcn_global_load_lds)
#define HAVE_GLL 1
#endif
#endif

__device__ __forceinline__ ushort f2bf(float f) {
  uint32_t u = __float_as_uint(f);
  uint32_t r = u + 0x7FFF + ((u >> 16) & 1);   // RNE
  return (ushort)(r >> 16);
}
__device__ __forceinline__ float bf2f(ushort b) {
  return __uint_as_float(((uint32_t)b) << 16);
}

#ifndef HAVE_FP8_CVT
// manual OCP e4m3 encode/decode fallbacks
__device__ __forceinline__ uint32_t f2fp8_1(float f) {
  uint32_t u = __float_as_uint(f);
  uint32_t s = (u >> 24) & 0x80;
  float a = fabsf(f);
  if (a >= 448.f) return s | 0x7E;
  if (a < 0.015625f) {
    uint32_t m = (uint32_t)(a * 512.f + 0.5f);
    return s | m;
  }
  uint32_t r = u & 0x7fffffff;
  r += 0x7FFFF + ((r >> 20) & 1);
  uint32_t e = (r >> 23) - 127;
  if ((int)e > 8) return s | 0x7E;
  return s | ((e + 7) << 3) | ((r >> 20) & 7);
}
__device__ __forceinline__ float fp8_2f(uint32_t b) {
  uint32_t s = (b & 0x80) << 24;
  uint32_t e = (b >> 3) & 0xF, m = b & 7;
  if (e == 0) { float f = (float)m * 0.001953125f; return s ? -f : f; }
  return __uint_as_float(s | ((e + 120) << 23) | (m << 20));
}
#endif

__device__ __forceinline__ void acc8f8(float* s, uint2 v) {
#ifdef HAVE_FP8_CVT
  f32x2 a = __builtin_amdgcn_cvt_pk_f32_fp8(v.x, false);
  f32x2 b = __builtin_amdgcn_cvt_pk_f32_fp8(v.x, true);
  f32x2 c = __builtin_amdgcn_cvt_pk_f32_fp8(v.y, false);
  f32x2 d = __builtin_amdgcn_cvt_pk_f32_fp8(v.y, true);
  s[0] += a.x; s[1] += a.y; s[2] += b.x; s[3] += b.y;
  s[4] += c.x; s[5] += c.y; s[6] += d.x; s[7] += d.y;
#else
  s[0] += fp8_2f(v.x & 0xff);        s[1] += fp8_2f((v.x >> 8) & 0xff);
  s[2] += fp8_2f((v.x >> 16) & 0xff); s[3] += fp8_2f(v.x >> 24);
  s[4] += fp8_2f(v.y & 0xff);        s[5] += fp8_2f((v.y >> 8) & 0xff);
  s[6] += fp8_2f((v.y >> 16) & 0xff); s[7] += fp8_2f(v.y >> 24);
#endif
}

// ---------------------------------------------------------------------------
// CSR build
// ---------------------------------------------------------------------------

__global__ void k_hist(const int* __restrict__ dst, int* __restrict__ bcount, int E) {
  __shared__ int h[256];
  int t = threadIdx.x;
  h[t] = 0;
  __syncthreads();
  for (int e = blockIdx.x * 256 + t; e < E; e += gridDim.x * 256)
    atomicAdd(&h[dst[e] >> BSHIFT], 1);
  __syncthreads();
  if (h[t]) atomicAdd(&bcount[t], h[t]);
}

__global__ void k_bucket_scan(const int* __restrict__ bcount,
                              int* __restrict__ bbase, int* __restrict__ bcursor) {
  __shared__ int sd[256];
  int t = threadIdx.x;
  int cnt = bcount[t];
  sd[t] = cnt;
  __syncthreads();
  for (int off = 1; off < 256; off <<= 1) {
    int v = (t >= off) ? sd[t - off] : 0;
    __syncthreads();
    sd[t] += v;
    __syncthreads();
  }
  int base = sd[t] - cnt;
  bbase[t] = base;
  bcursor[t] = base;
}

__global__ __launch_bounds__(256) void k_scatter(
    const int* __restrict__ src, const int* __restrict__ dst,
    int* __restrict__ bcursor, uint32_t* __restrict__ rec, int E) {
  __shared__ int h[256];
  __shared__ int bbase[256];
  __shared__ int lcur[256];
  int t = threadIdx.x;
  int e0 = blockIdx.x * EPB;
  int e1 = e0 + EPB < E ? e0 + EPB : E;
  h[t] = 0; lcur[t] = 0;
  __syncthreads();
  for (int e = e0 + t; e < e1; e += 256)
    atomicAdd(&h[dst[e] >> BSHIFT], 1);
  __syncthreads();
  if (h[t]) bbase[t] = atomicAdd(&bcursor[t], h[t]);
  __syncthreads();
  for (int e = e0 + t; e < e1; e += 256) {
    int d = dst[e];
    int b = d >> BSHIFT;
    int r = atomicAdd(&lcur[b], 1);
    rec[bbase[b] + r] = ((uint32_t)src[e] << BSHIFT) | ((uint32_t)d & (BNODES - 1));
  }
}

__global__ __launch_bounds__(256) void k_csr(
    const uint32_t* __restrict__ rec, const int* __restrict__ bbase,
    const int* __restrict__ bcount,
    int* __restrict__ row_start, int* __restrict__ deg,
    int* __restrict__ csr, int n) {
  __shared__ int ldeg[BNODES];
  __shared__ int lexcl[BNODES];
  __shared__ int ssum[256];
  int t = threadIdx.x;
  int b = blockIdx.x;
  int node0 = b << BSHIFT;
  int ebase = bbase[b];
  int ecnt = bcount[b];

  ldeg[t] = 0; ldeg[t + 256] = 0;
  __syncthreads();
  for (int i = t; i < ecnt; i += 256)
    atomicAdd(&ldeg[rec[ebase + i] & (BNODES - 1)], 1);
  __syncthreads();

  int v0 = ldeg[2 * t], v1 = ldeg[2 * t + 1];
  ssum[t] = v0 + v1;
  __syncthreads();
  for (int off = 1; off < 256; off <<= 1) {
    int v = (t >= off) ? ssum[t - off] : 0;
    __syncthreads();
    ssum[t] += v;
    __syncthreads();
  }
  int excl = ssum[t] - (v0 + v1);
  lexcl[2 * t] = excl;
  lexcl[2 * t + 1] = excl + v0;
  int node = node0 + 2 * t;
  if (node < n) { row_start[node] = ebase + excl; deg[node] = v0; }
  if (node + 1 < n) { row_start[node + 1] = ebase + excl + v0; deg[node + 1] = v1; }
  ldeg[2 * t] = 0; ldeg[2 * t + 1] = 0;
  __syncthreads();
  for (int i = t; i < ecnt; i += 256) {
    uint32_t r = rec[ebase + i];
    int li = r & (BNODES - 1);
    int k = atomicAdd(&ldeg[li], 1);
    csr[ebase + lexcl[li] + k] = (int)(r >> BSHIFT);
  }
}

// ---------------------------------------------------------------------------
// fp32 -> bf16 + fp8 cast in one pass
// ---------------------------------------------------------------------------

__global__ void k_cast(const float* __restrict__ in, ushort* __restrict__ outb,
                       uint32_t* __restrict__ outf8, int n4) {
  int i = blockIdx.x * 256 + threadIdx.x;
  if (i < n4) {
    float4 v = ((const float4*)in)[i];
    ushort4 o;
    o.x = f2bf(v.x); o.y = f2bf(v.y); o.z = f2bf(v.z); o.w = f2bf(v.w);
    ((ushort4*)outb)[i] = o;
#ifdef HAVE_FP8_CVT
    int p = __builtin_amdgcn_cvt_pk_fp8_f32(v.x, v.y, 0, false);
    p = __builtin_amdgcn_cvt_pk_fp8_f32(v.z, v.w, p, true);
    outf8[i] = (uint32_t)p;
#else
    outf8[i] = f2fp8_1(v.x) | (f2fp8_1(v.y) << 8) | (f2fp8_1(v.z) << 16) |
               (f2fp8_1(v.w) << 24);
#endif
  }
}

__global__ void k_wcat(const float* __restrict__ Wl, const float* __restrict__ Wr,
                       ushort* __restrict__ Wcat) {
  int c = blockIdx.x, k = threadIdx.x;
  float v = (k < IN_C) ? Wl[(size_t)c * IN_C + k] : Wr[(size_t)c * IN_C + (k - IN_C)];
  Wcat[(size_t)c * (2 * IN_C) + k] = f2bf(v);
}

// ---------------------------------------------------------------------------
// Mean aggregation on fp8 rows
// ---------------------------------------------------------------------------

__global__ void k_aggr(const uint32_t* __restrict__ xf8, const int* __restrict__ csr,
                       const int* __restrict__ row_start, const int* __restrict__ deg,
                       ushort* __restrict__ aggr, int n) {
  int wid = threadIdx.x >> 6;
  int lane = threadIdx.x & 63;
  int node = blockIdx.x * 4 + wid;
  if (node >= n) return;
  int base = row_start[node];
  int d = deg[node];
  int q = lane >> 4, li = lane & 15;
  float s[8] = {};
  int i = q;
  for (; i + 12 < d; i += 16) {
    int n0 = csr[base + i];
    int n1 = csr[base + i + 4];
    int n2 = csr[base + i + 8];
    int n3 = csr[base + i + 12];
    uint2 a = ((const uint2*)(xf8 + (size_t)n0 * (IN_C / 4)))[li];
    uint2 b = ((const uint2*)(xf8 + (size_t)n1 * (IN_C / 4)))[li];
    uint2 c = ((const uint2*)(xf8 + (size_t)n2 * (IN_C / 4)))[li];
    uint2 e = ((const uint2*)(xf8 + (size_t)n3 * (IN_C / 4)))[li];
    acc8f8(s, a); acc8f8(s, b); acc8f8(s, c); acc8f8(s, e);
  }
  for (; i < d; i += 4) {
    int n0 = csr[base + i];
    uint2 a = ((const uint2*)(xf8 + (size_t)n0 * (IN_C / 4)))[li];
    acc8f8(s, a);
  }
#pragma unroll
  for (int j = 0; j < 8; ++j) {
    s[j] += __shfl_xor(s[j], 16);
    s[j] += __shfl_xor(s[j], 32);
  }
  if (q == 0) {
    float inv = 1.0f / (float)(d > 1 ? d : 1);
    uint4 o;
    o.x = (uint32_t)f2bf(s[0] * inv) | ((uint32_t)f2bf(s[1] * inv) << 16);
    o.y = (uint32_t)f2bf(s[2] * inv) | ((uint32_t)f2bf(s[3] * inv) << 16);
    o.z = (uint32_t)f2bf(s[4] * inv) | ((uint32_t)f2bf(s[5] * inv) << 16);
    o.w = (uint32_t)f2bf(s[6] * inv) | ((uint32_t)f2bf(s[7] * inv) << 16);
    ((uint4*)(aggr + (size_t)node * IN_C))[li] = o;
  }
}

// ---------------------------------------------------------------------------
// Fused SAGE GEMM (bf16 MFMA) + relu + per-graph max-pool.
// Block = 64 nodes x 256 cols, 4 waves. Async pipeline: global_load_lds
// (16B DMA) into double-buffered LDS, ONE barrier per K-iter; loads for
// chunk k+1 overlap MFMA of chunk k (barrier vmcnt-drain lands after compute).
// Unpadded LDS + XOR chunk swizzle (phys = q ^ ((row>>1)&3)): staging stays
// lane-linear (DMA constraint) and frag reads alias only 2-way (free).
// ---------------------------------------------------------------------------

#ifdef HAVE_GLL
__device__ __forceinline__ void load16_lds(const ushort* g, ushort* l) {
  __builtin_amdgcn_global_load_lds(
      (const __attribute__((address_space(1))) uint32_t*)g,
      (__attribute__((address_space(3))) uint32_t*)l, 16, 0, 0);
}
#endif

__global__ __launch_bounds__(256) void k_gemm_pool(
    const ushort* __restrict__ aggrb, const ushort* __restrict__ xb,
    const ushort* __restrict__ Wcat, const float* __restrict__ bl,
    const int* __restrict__ batch, float* __restrict__ hp, int n) {
  __shared__ ushort sA[2][64 * 32];
  __shared__ ushort sB[2][256 * 32];
  __shared__ float sbl[256];
  __shared__ int sBatch[64];

  int t = threadIdx.x;
  int n0 = blockIdx.x * 64;
  sbl[t] = bl[t];
  if (t < 64) sBatch[t] = (n0 + t < n) ? batch[n0 + t] : -1;

  int lane = t & 63, w = t >> 6;
  int q = lane >> 4, m = lane & 15;

  // staging geometry: thread t <-> (row t>>2, phys chunk t&3)
  int rA = t >> 2, pA = t & 3;
  int cA = pA ^ ((rA >> 1) & 3);                  // logical 8-elem chunk
  int gnA = n0 + rA; gnA = gnA < n ? gnA : n - 1;
  const ushort* baseAggr = aggrb + (size_t)gnA * IN_C + cA * 8;
  const ushort* baseX    = xb + (size_t)gnA * IN_C + cA * 8;
  int ldsA = rA * 32 + pA * 8;
  int pchunk = q ^ ((m >> 1) & 3);                // read-side phys chunk

  f32x4 acc[4][4] = {};

#ifdef HAVE_GLL
  auto stage = [&](int k0, int buf) {
    const ushort* srcA = (k0 < 4) ? baseAggr + k0 * 32 : baseX + (k0 - 4) * 32;
    load16_lds(srcA, &sA[buf][ldsA]);
#pragma unroll
    for (int it = 0; it < 4; ++it) {
      int rB = it * 64 + (t >> 2);
      int cB = (t & 3) ^ ((rB >> 1) & 3);
      load16_lds(Wcat + (size_t)rB * (2 * IN_C) + k0 * 32 + cB * 8,
                 &sB[buf][rB * 32 + (t & 3) * 8]);
    }
  };
  stage(0, 0);
  __syncthreads();
#pragma unroll
  for (int k0 = 0; k0 < 8; ++k0) {
    int cur = k0 & 1;
    if (k0 < 7) stage(k0 + 1, cur ^ 1);
    short8 af[4], bf[4];
#pragma unroll
    for (int rt = 0; rt < 4; ++rt)
      af[rt] = *(const short8*)&sA[cur][(rt * 16 + m) * 32 + pchunk * 8];
#pragma unroll
    for (int ct = 0; ct < 4; ++ct)
      bf[ct] = *(const short8*)&sB[cur][(w * 64 + ct * 16 + m) * 32 + pchunk * 8];
#pragma unroll
    for (int rt = 0; rt < 4; ++rt)
#pragma unroll
      for (int ct = 0; ct < 4; ++ct)
        acc[rt][ct] = __builtin_amdgcn_mfma_f32_16x16x32_bf16(af[rt], bf[ct], acc[rt][ct], 0, 0, 0);
    __syncthreads();
  }
#else
  // fallback: register-mediated staging, single buffer, 2 barriers/iter
  for (int k0 = 0; k0 < 8; ++k0) {
    const ushort* srcA = (k0 < 4) ? baseAggr + k0 * 32 : baseX + (k0 - 4) * 32;
    uint4 vA = *(const uint4*)srcA;
    uint4 vB[4];
#pragma unroll
    for (int it = 0; it < 4; ++it) {
      int rB = it * 64 + (t >> 2);
      int cB = (t & 3) ^ ((rB >> 1) & 3);
      vB[it] = *(const uint4*)(Wcat + (size_t)rB * (2 * IN_C) + k0 * 32 + cB * 8);
    }
    __syncthreads();
    *(uint4*)&sA[0][ldsA] = vA;
#pragma unroll
    for (int it = 0; it < 4; ++it) {
      int rB = it * 64 + (t >> 2);
      *(uint4*)&sB[0][rB * 32 + (t & 3) * 8] = vB[it];
    }
    __syncthreads();
    short8 af[4], bf[4];
#pragma unroll
    for (int rt = 0; rt < 4; ++rt)
      af[rt] = *(const short8*)&sA[0][(rt * 16 + m) * 32 + pchunk * 8];
#pragma unroll
    for (int ct = 0; ct < 4; ++ct)
      bf[ct] = *(const short8*)&sB[0][(w * 64 + ct * 16 + m) * 32 + pchunk * 8];
#pragma unroll
    for (int rt = 0; rt < 4; ++rt)
#pragma unroll
      for (int ct = 0; ct < 4; ++ct)
        acc[rt][ct] = __builtin_amdgcn_mfma_f32_16x16x32_bf16(af[rt], bf[ct], acc[rt][ct], 0, 0, 0);
  }
#endif

  // epilogue: bias + relu + per-graph max, registers -> <=2 atomics/col/wave
  int last = n - 1 - n0; last = last < 63 ? last : 63;
  int gA = sBatch[0];
  int gB = sBatch[last];
#pragma unroll
  for (int ct = 0; ct < 4; ++ct) {
    int col = w * 64 + ct * 16 + m;
    float bias = sbl[col];
    float mA = 0.f, mB = 0.f;
#pragma unroll
    for (int rt = 0; rt < 4; ++rt) {
#pragma unroll
      for (int i = 0; i < 4; ++i) {
        int lr = rt * 16 + q * 4 + i;
        if (n0 + lr < n) {
          float v = fmaxf(acc[rt][ct][i] + bias, 0.f);
          if (sBatch[lr] == gA) mA = fmaxf(mA, v);
          else mB = fmaxf(mB, v);
        }
      }
    }
    mA = fmaxf(mA, __shfl_xor(mA, 16)); mA = fmaxf(mA, __shfl_xor(mA, 32));
    mB = fmaxf(mB, __shfl_xor(mB, 16)); mB = fmaxf(mB, __shfl_xor(mB, 32));
    if (q == 0) {
      atomicMax((int*)&hp[(size_t)gA * HID + col], __float_as_int(mA));
      if (gB != gA) atomicMax((int*)&hp[(size_t)gB * HID + col], __float_as_int(mB));
    }
  }
}

// ---------------------------------------------------------------------------

__global__ void k_root(const int* __restrict__ batch, int* __restrict__ root, int n) {
  int i = blockIdx.x * 256 + threadIdx.x;
  if (i < n) {
    int g = batch[i];
    if (i == 0 || batch[i - 1] != g) root[g] = i;
  }
}

// ---------------------------------------------------------------------------
// Tail MLP (fp32), one block per graph
// ---------------------------------------------------------------------------

__global__ __launch_bounds__(256) void k_mlp2(
    const float* __restrict__ x, const float* __restrict__ hp,
    const int* __restrict__ root,
    const float* __restrict__ W0, const float* __restrict__ b0,
    const float* __restrict__ W1, const float* __restrict__ b1,
    const float* __restrict__ W2, const float* __restrict__ b2,
    float* __restrict__ out) {
  __shared__ float xr[IN_C];
  __shared__ float cat[2 * HID];
  __shared__ float h2r[HID];
  __shared__ float red[8];

  int g = blockIdx.x;
  int t = threadIdx.x;
  int rg = root[g];
  if (t < IN_C) xr[t] = x[(size_t)rg * IN_C + t];
  __syncthreads();

  float a0 = b0[t];
  const float* w0 = W0 + (size_t)t * IN_C;
#pragma unroll 4
  for (int k = 0; k < IN_C; ++k) a0 += xr[k] * w0[k];
  cat[t] = fmaxf(a0, 0.f);
  cat[HID + t] = hp[(size_t)g * HID + t];
  __syncthreads();

  float a1 = b1[t];
  const float* w1 = W1 + (size_t)t * (2 * HID);
#pragma unroll 4
  for (int j = 0; j < 2 * HID; ++j) a1 += cat[j] * w1[j];
  h2r[t] = fmaxf(a1, 0.f);
  __syncthreads();

  float p0 = h2r[t] * W2[t];
  float p1 = h2r[t] * W2[HID + t];
  for (int off = 32; off > 0; off >>= 1) {
    p0 += __shfl_down(p0, off);
    p1 += __shfl_down(p1, off);
  }
  int lane = t & 63, wid = t >> 6;
  if (lane == 0) { red[wid * 2] = p0; red[wid * 2 + 1] = p1; }
  __syncthreads();
  if (t == 0) {
    float l0 = b2[0] + red[0] + red[2] + red[4] + red[6];
    float l1 = b2[1] + red[1] + red[3] + red[5] + red[7];
    float mx = fmaxf(l0, l1);
    float ls = logf(expf(l0 - mx) + expf(l1 - mx));
    out[(size_t)g * 2 + 0] = l0 - mx - ls;
    out[(size_t)g * 2 + 1] = l1 - mx - ls;
  }
}

// ---------------------------------------------------------------------------

extern "C" void kernel_launch(void* const* d_in, const int* in_sizes, int n_in,
                              void* d_out, int out_size, void* d_ws, size_t ws_size,
                              hipStream_t stream) {
  const float* x  = (const float*)d_in[0];
  const int* ei   = (const int*)d_in[1];
  const int* batch= (const int*)d_in[2];
  const float* Wl = (const float*)d_in[3];
  const float* bl = (const float*)d_in[4];
  const float* Wr = (const float*)d_in[5];
  const float* W0 = (const float*)d_in[6];
  const float* b0 = (const float*)d_in[7];
  const float* W1 = (const float*)d_in[8];
  const float* b1 = (const float*)d_in[9];
  const float* W2 = (const float*)d_in[10];
  const float* b2 = (const float*)d_in[11];
  float* out = (float*)d_out;

  const int N = in_sizes[0] / IN_C;
  const int E = in_sizes[1] / 2;
  const int G = out_size / OUT_C;
  const int* src = ei;
  const int* dst = ei + E;
  const int NB = (N + BNODES - 1) >> BSHIFT;

  char* w = (char*)d_ws;
  int* deg       = (int*)w; w += (size_t)N * 4;
  int* row_start = (int*)w; w += (size_t)N * 4;
  int* bcount    = (int*)w; w += 1024;
  int* bbase     = (int*)w; w += 1024;
  int* bcursor   = (int*)w; w += 1024;
  int* root      = (int*)w; w += (size_t)G * 4;
  w = (char*)(((uintptr_t)w + 255) & ~(uintptr_t)255);
  int* csr       = (int*)w; w += (size_t)E * 4;
  w = (char*)(((uintptr_t)w + 255) & ~(uintptr_t)255);
  ushort* xb     = (ushort*)w; w += (size_t)N * IN_C * 2;
  uint32_t* xf8  = (uint32_t*)w; w += (size_t)N * IN_C;
  ushort* aggrb  = (ushort*)w; w += (size_t)N * IN_C * 2;
  ushort* Wcat   = (ushort*)w; w += (size_t)HID * (2 * IN_C) * 2;
  float* hp      = (float*)w; w += (size_t)G * HID * 4;
  uint32_t* rec  = (uint32_t*)aggrb;   // dead before k_aggr writes aggrb

  hipMemsetAsync(bcount, 0, 1024, stream);
  hipMemsetAsync(hp, 0, (size_t)G * HID * 4, stream);

  k_cast<<<((N * IN_C / 4) + 255) / 256, 256, 0, stream>>>(x, xb, xf8, N * IN_C / 4);
  k_wcat<<<HID, 2 * IN_C, 0, stream>>>(Wl, Wr, Wcat);
  k_hist<<<1024, 256, 0, stream>>>(dst, bcount, E);
  k_bucket_scan<<<1, 256, 0, stream>>>(bcount, bbase, bcursor);
  k_scatter<<<(E + EPB - 1) / EPB, 256, 0, stream>>>(src, dst, bcursor, rec, E);
  k_csr<<<NB, 256, 0, stream>>>(rec, bbase, bcount, row_start, deg, csr, N);
  k_root<<<(N + 255) / 256, 256, 0, stream>>>(batch, root, N);
  k_aggr<<<(N + 3) / 4, 256, 0, stream>>>(xf8, csr, row_start, deg, aggrb, N);
  k_gemm_pool<<<(N + 63) / 64, 256, 0, stream>>>(aggrb, xb, Wcat, bl, batch, hp, N);
  k_mlp2<<<G, 256, 0, stream>>>(x, hp, root, W0, b0, W1, b1, W2, b2, out);
}

// Round 7
// 302.248 us; speedup vs baseline: 3.9018x; 1.0960x over previous
//
#include <hip/hip_runtime.h>
#include <hip/hip_bf16.h>
#include <math.h>
#include <stdint.h>

#define IN_C 128
#define HID  256
#define OUT_C 2

// bucketing for CSR build: 512 nodes per bucket
#define BSHIFT 9
#define BNODES 512
#define EPB 4096   // edges per k_scatter block

typedef __attribute__((ext_vector_type(8))) short short8;
typedef __attribute__((ext_vector_type(4))) float f32x4;
typedef __attribute__((ext_vector_type(2))) float f32x2;

#if defined(__has_builtin)
#if __has_builtin(__builtin_amdgcn_cvt_pk_f32_fp8) && __has_builtin(__builtin_amdgcn_cvt_pk_fp8_f32)
#define HAVE_FP8_CVT 1
#endif
#if __has_builtin(__builtin_amdgcn_global_load_lds)
#define HAVE_GLL 1
#endif
#endif

__device__ __forceinline__ ushort f2bf(float f) {
  uint32_t u = __float_as_uint(f);
  uint32_t r = u + 0x7FFF + ((u >> 16) & 1);   // RNE
  return (ushort)(r >> 16);
}
__device__ __forceinline__ float bf2f(ushort b) {
  return __uint_as_float(((uint32_t)b) << 16);
}

#ifndef HAVE_FP8_CVT
__device__ __forceinline__ uint32_t f2fp8_1(float f) {
  uint32_t u = __float_as_uint(f);
  uint32_t s = (u >> 24) & 0x80;
  float a = fabsf(f);
  if (a >= 448.f) return s | 0x7E;
  if (a < 0.015625f) {
    uint32_t m = (uint32_t)(a * 512.f + 0.5f);
    return s | m;
  }
  uint32_t r = u & 0x7fffffff;
  r += 0x7FFFF + ((r >> 20) & 1);
  uint32_t e = (r >> 23) - 127;
  if ((int)e > 8) return s | 0x7E;
  return s | ((e + 7) << 3) | ((r >> 20) & 7);
}
__device__ __forceinline__ float fp8_2f(uint32_t b) {
  uint32_t s = (b & 0x80) << 24;
  uint32_t e = (b >> 3) & 0xF, m = b & 7;
  if (e == 0) { float f = (float)m * 0.001953125f; return s ? -f : f; }
  return __uint_as_float(s | ((e + 120) << 23) | (m << 20));
}
#endif

__device__ __forceinline__ void acc8f8(float* s, uint2 v) {
#ifdef HAVE_FP8_CVT
  f32x2 a = __builtin_amdgcn_cvt_pk_f32_fp8(v.x, false);
  f32x2 b = __builtin_amdgcn_cvt_pk_f32_fp8(v.x, true);
  f32x2 c = __builtin_amdgcn_cvt_pk_f32_fp8(v.y, false);
  f32x2 d = __builtin_amdgcn_cvt_pk_f32_fp8(v.y, true);
  s[0] += a.x; s[1] += a.y; s[2] += b.x; s[3] += b.y;
  s[4] += c.x; s[5] += c.y; s[6] += d.x; s[7] += d.y;
#else
  s[0] += fp8_2f(v.x & 0xff);        s[1] += fp8_2f((v.x >> 8) & 0xff);
  s[2] += fp8_2f((v.x >> 16) & 0xff); s[3] += fp8_2f(v.x >> 24);
  s[4] += fp8_2f(v.y & 0xff);        s[5] += fp8_2f((v.y >> 8) & 0xff);
  s[6] += fp8_2f((v.y >> 16) & 0xff); s[7] += fp8_2f(v.y >> 24);
#endif
}

// ---------------------------------------------------------------------------
// CSR build
// ---------------------------------------------------------------------------

__global__ void k_hist(const int* __restrict__ dst, int* __restrict__ bcount, int E) {
  __shared__ int h[256];
  int t = threadIdx.x;
  h[t] = 0;
  __syncthreads();
  for (int e = blockIdx.x * 256 + t; e < E; e += gridDim.x * 256)
    atomicAdd(&h[dst[e] >> BSHIFT], 1);
  __syncthreads();
  if (h[t]) atomicAdd(&bcount[t], h[t]);
}

__global__ void k_bucket_scan(const int* __restrict__ bcount,
                              int* __restrict__ bbase, int* __restrict__ bcursor) {
  __shared__ int sd[256];
  int t = threadIdx.x;
  int cnt = bcount[t];
  sd[t] = cnt;
  __syncthreads();
  for (int off = 1; off < 256; off <<= 1) {
    int v = (t >= off) ? sd[t - off] : 0;
    __syncthreads();
    sd[t] += v;
    __syncthreads();
  }
  int base = sd[t] - cnt;
  bbase[t] = base;
  bcursor[t] = base;
}

__global__ __launch_bounds__(256) void k_scatter(
    const int* __restrict__ src, const int* __restrict__ dst,
    int* __restrict__ bcursor, uint32_t* __restrict__ rec, int E) {
  __shared__ int h[256];
  __shared__ int bbase[256];
  __shared__ int lcur[256];
  int t = threadIdx.x;
  int e0 = blockIdx.x * EPB;
  int e1 = e0 + EPB < E ? e0 + EPB : E;
  h[t] = 0; lcur[t] = 0;
  __syncthreads();
  for (int e = e0 + t; e < e1; e += 256)
    atomicAdd(&h[dst[e] >> BSHIFT], 1);
  __syncthreads();
  if (h[t]) bbase[t] = atomicAdd(&bcursor[t], h[t]);
  __syncthreads();
  for (int e = e0 + t; e < e1; e += 256) {
    int d = dst[e];
    int b = d >> BSHIFT;
    int r = atomicAdd(&lcur[b], 1);
    rec[bbase[b] + r] = ((uint32_t)src[e] << BSHIFT) | ((uint32_t)d & (BNODES - 1));
  }
}

__global__ __launch_bounds__(256) void k_csr(
    const uint32_t* __restrict__ rec, const int* __restrict__ bbase,
    const int* __restrict__ bcount,
    int* __restrict__ row_start, int* __restrict__ deg,
    int* __restrict__ csr, int n) {
  __shared__ int ldeg[BNODES];
  __shared__ int lexcl[BNODES];
  __shared__ int ssum[256];
  int t = threadIdx.x;
  int b = blockIdx.x;
  int node0 = b << BSHIFT;
  int ebase = bbase[b];
  int ecnt = bcount[b];

  ldeg[t] = 0; ldeg[t + 256] = 0;
  __syncthreads();
  for (int i = t; i < ecnt; i += 256)
    atomicAdd(&ldeg[rec[ebase + i] & (BNODES - 1)], 1);
  __syncthreads();

  int v0 = ldeg[2 * t], v1 = ldeg[2 * t + 1];
  ssum[t] = v0 + v1;
  __syncthreads();
  for (int off = 1; off < 256; off <<= 1) {
    int v = (t >= off) ? ssum[t - off] : 0;
    __syncthreads();
    ssum[t] += v;
    __syncthreads();
  }
  int excl = ssum[t] - (v0 + v1);
  lexcl[2 * t] = excl;
  lexcl[2 * t + 1] = excl + v0;
  int node = node0 + 2 * t;
  if (node < n) { row_start[node] = ebase + excl; deg[node] = v0; }
  if (node + 1 < n) { row_start[node + 1] = ebase + excl + v0; deg[node + 1] = v1; }
  ldeg[2 * t] = 0; ldeg[2 * t + 1] = 0;
  __syncthreads();
  for (int i = t; i < ecnt; i += 256) {
    uint32_t r = rec[ebase + i];
    int li = r & (BNODES - 1);
    int k = atomicAdd(&ldeg[li], 1);
    csr[ebase + lexcl[li] + k] = (int)(r >> BSHIFT);
  }
}

// ---------------------------------------------------------------------------
// casts
// ---------------------------------------------------------------------------

__global__ void k_cast(const float* __restrict__ in, ushort* __restrict__ outb,
                       uint32_t* __restrict__ outf8, int n4) {
  int i = blockIdx.x * 256 + threadIdx.x;
  if (i < n4) {
    float4 v = ((const float4*)in)[i];
    ushort4 o;
    o.x = f2bf(v.x); o.y = f2bf(v.y); o.z = f2bf(v.z); o.w = f2bf(v.w);
    ((ushort4*)outb)[i] = o;
#ifdef HAVE_FP8_CVT
    int p = __builtin_amdgcn_cvt_pk_fp8_f32(v.x, v.y, 0, false);
    p = __builtin_amdgcn_cvt_pk_fp8_f32(v.z, v.w, p, true);
    outf8[i] = (uint32_t)p;
#else
    outf8[i] = f2fp8_1(v.x) | (f2fp8_1(v.y) << 8) | (f2fp8_1(v.z) << 16) |
               (f2fp8_1(v.w) << 24);
#endif
  }
}

__global__ void k_wcat(const float* __restrict__ Wl, const float* __restrict__ Wr,
                       ushort* __restrict__ Wcat) {
  int c = blockIdx.x, k = threadIdx.x;
  float v = (k < IN_C) ? Wl[(size_t)c * IN_C + k] : Wr[(size_t)c * IN_C + (k - IN_C)];
  Wcat[(size_t)c * (2 * IN_C) + k] = f2bf(v);
}

// W0 (HID*IN_C) and W1 (HID*2*HID) fp32 -> bf16 in one launch
__global__ void k_cast2(const float* __restrict__ W0, const float* __restrict__ W1,
                        ushort* __restrict__ W0b, ushort* __restrict__ W1b) {
  const int N0 = HID * IN_C / 4;          // 8192
  const int N1 = HID * 2 * HID / 4;       // 32768
  int i = blockIdx.x * 256 + threadIdx.x;
  if (i < N0) {
    float4 v = ((const float4*)W0)[i];
    ushort4 o = {f2bf(v.x), f2bf(v.y), f2bf(v.z), f2bf(v.w)};
    ((ushort4*)W0b)[i] = o;
  } else if (i < N0 + N1) {
    int j = i - N0;
    float4 v = ((const float4*)W1)[j];
    ushort4 o = {f2bf(v.x), f2bf(v.y), f2bf(v.z), f2bf(v.w)};
    ((ushort4*)W1b)[j] = o;
  }
}

// ---------------------------------------------------------------------------
// Mean aggregation on fp8 rows
// ---------------------------------------------------------------------------

__global__ void k_aggr(const uint32_t* __restrict__ xf8, const int* __restrict__ csr,
                       const int* __restrict__ row_start, const int* __restrict__ deg,
                       ushort* __restrict__ aggr, int n) {
  int wid = threadIdx.x >> 6;
  int lane = threadIdx.x & 63;
  int node = blockIdx.x * 4 + wid;
  if (node >= n) return;
  int base = row_start[node];
  int d = deg[node];
  int q = lane >> 4, li = lane & 15;
  float s[8] = {};
  int i = q;
  for (; i + 12 < d; i += 16) {
    int n0 = csr[base + i];
    int n1 = csr[base + i + 4];
    int n2 = csr[base + i + 8];
    int n3 = csr[base + i + 12];
    uint2 a = ((const uint2*)(xf8 + (size_t)n0 * (IN_C / 4)))[li];
    uint2 b = ((const uint2*)(xf8 + (size_t)n1 * (IN_C / 4)))[li];
    uint2 c = ((const uint2*)(xf8 + (size_t)n2 * (IN_C / 4)))[li];
    uint2 e = ((const uint2*)(xf8 + (size_t)n3 * (IN_C / 4)))[li];
    acc8f8(s, a); acc8f8(s, b); acc8f8(s, c); acc8f8(s, e);
  }
  for (; i < d; i += 4) {
    int n0 = csr[base + i];
    uint2 a = ((const uint2*)(xf8 + (size_t)n0 * (IN_C / 4)))[li];
    acc8f8(s, a);
  }
#pragma unroll
  for (int j = 0; j < 8; ++j) {
    s[j] += __shfl_xor(s[j], 16);
    s[j] += __shfl_xor(s[j], 32);
  }
  if (q == 0) {
    float inv = 1.0f / (float)(d > 1 ? d : 1);
    uint4 o;
    o.x = (uint32_t)f2bf(s[0] * inv) | ((uint32_t)f2bf(s[1] * inv) << 16);
    o.y = (uint32_t)f2bf(s[2] * inv) | ((uint32_t)f2bf(s[3] * inv) << 16);
    o.z = (uint32_t)f2bf(s[4] * inv) | ((uint32_t)f2bf(s[5] * inv) << 16);
    o.w = (uint32_t)f2bf(s[6] * inv) | ((uint32_t)f2bf(s[7] * inv) << 16);
    ((uint4*)(aggr + (size_t)node * IN_C))[li] = o;
  }
}

// ---------------------------------------------------------------------------
// Fused SAGE GEMM (bf16 MFMA) + relu + per-graph max-pool (async pipeline)
// ---------------------------------------------------------------------------

#ifdef HAVE_GLL
__device__ __forceinline__ void load16_lds(const ushort* g, ushort* l) {
  __builtin_amdgcn_global_load_lds(
      (const __attribute__((address_space(1))) uint32_t*)g,
      (__attribute__((address_space(3))) uint32_t*)l, 16, 0, 0);
}
#endif

__global__ __launch_bounds__(256) void k_gemm_pool(
    const ushort* __restrict__ aggrb, const ushort* __restrict__ xb,
    const ushort* __restrict__ Wcat, const float* __restrict__ bl,
    const int* __restrict__ batch, float* __restrict__ hp, int n) {
  __shared__ ushort sA[2][64 * 32];
  __shared__ ushort sB[2][256 * 32];
  __shared__ float sbl[256];
  __shared__ int sBatch[64];

  int t = threadIdx.x;
  int n0 = blockIdx.x * 64;
  sbl[t] = bl[t];
  if (t < 64) sBatch[t] = (n0 + t < n) ? batch[n0 + t] : -1;

  int lane = t & 63, w = t >> 6;
  int q = lane >> 4, m = lane & 15;

  int rA = t >> 2, pA = t & 3;
  int cA = pA ^ ((rA >> 1) & 3);
  int gnA = n0 + rA; gnA = gnA < n ? gnA : n - 1;
  const ushort* baseAggr = aggrb + (size_t)gnA * IN_C + cA * 8;
  const ushort* baseX    = xb + (size_t)gnA * IN_C + cA * 8;
  int ldsA = rA * 32 + pA * 8;
  int pchunk = q ^ ((m >> 1) & 3);

  f32x4 acc[4][4] = {};

#ifdef HAVE_GLL
  auto stage = [&](int k0, int buf) {
    const ushort* srcA = (k0 < 4) ? baseAggr + k0 * 32 : baseX + (k0 - 4) * 32;
    load16_lds(srcA, &sA[buf][ldsA]);
#pragma unroll
    for (int it = 0; it < 4; ++it) {
      int rB = it * 64 + (t >> 2);
      int cB = (t & 3) ^ ((rB >> 1) & 3);
      load16_lds(Wcat + (size_t)rB * (2 * IN_C) + k0 * 32 + cB * 8,
                 &sB[buf][rB * 32 + (t & 3) * 8]);
    }
  };
  stage(0, 0);
  __syncthreads();
#pragma unroll
  for (int k0 = 0; k0 < 8; ++k0) {
    int cur = k0 & 1;
    if (k0 < 7) stage(k0 + 1, cur ^ 1);
    short8 af[4], bf[4];
#pragma unroll
    for (int rt = 0; rt < 4; ++rt)
      af[rt] = *(const short8*)&sA[cur][(rt * 16 + m) * 32 + pchunk * 8];
#pragma unroll
    for (int ct = 0; ct < 4; ++ct)
      bf[ct] = *(const short8*)&sB[cur][(w * 64 + ct * 16 + m) * 32 + pchunk * 8];
#pragma unroll
    for (int rt = 0; rt < 4; ++rt)
#pragma unroll
      for (int ct = 0; ct < 4; ++ct)
        acc[rt][ct] = __builtin_amdgcn_mfma_f32_16x16x32_bf16(af[rt], bf[ct], acc[rt][ct], 0, 0, 0);
    __syncthreads();
  }
#else
  for (int k0 = 0; k0 < 8; ++k0) {
    const ushort* srcA = (k0 < 4) ? baseAggr + k0 * 32 : baseX + (k0 - 4) * 32;
    uint4 vA = *(const uint4*)srcA;
    uint4 vB[4];
#pragma unroll
    for (int it = 0; it < 4; ++it) {
      int rB = it * 64 + (t >> 2);
      int cB = (t & 3) ^ ((rB >> 1) & 3);
      vB[it] = *(const uint4*)(Wcat + (size_t)rB * (2 * IN_C) + k0 * 32 + cB * 8);
    }
    __syncthreads();
    *(uint4*)&sA[0][ldsA] = vA;
#pragma unroll
    for (int it = 0; it < 4; ++it) {
      int rB = it * 64 + (t >> 2);
      *(uint4*)&sB[0][rB * 32 + (t & 3) * 8] = vB[it];
    }
    __syncthreads();
    short8 af[4], bf[4];
#pragma unroll
    for (int rt = 0; rt < 4; ++rt)
      af[rt] = *(const short8*)&sA[0][(rt * 16 + m) * 32 + pchunk * 8];
#pragma unroll
    for (int ct = 0; ct < 4; ++ct)
      bf[ct] = *(const short8*)&sB[0][(w * 64 + ct * 16 + m) * 32 + pchunk * 8];
#pragma unroll
    for (int rt = 0; rt < 4; ++rt)
#pragma unroll
      for (int ct = 0; ct < 4; ++ct)
        acc[rt][ct] = __builtin_amdgcn_mfma_f32_16x16x32_bf16(af[rt], bf[ct], acc[rt][ct], 0, 0, 0);
  }
#endif

  int last = n - 1 - n0; last = last < 63 ? last : 63;
  int gA = sBatch[0];
  int gB = sBatch[last];
#pragma unroll
  for (int ct = 0; ct < 4; ++ct) {
    int col = w * 64 + ct * 16 + m;
    float bias = sbl[col];
    float mA = 0.f, mB = 0.f;
#pragma unroll
    for (int rt = 0; rt < 4; ++rt) {
#pragma unroll
      for (int i = 0; i < 4; ++i) {
        int lr = rt * 16 + q * 4 + i;
        if (n0 + lr < n) {
          float v = fmaxf(acc[rt][ct][i] + bias, 0.f);
          if (sBatch[lr] == gA) mA = fmaxf(mA, v);
          else mB = fmaxf(mB, v);
        }
      }
    }
    mA = fmaxf(mA, __shfl_xor(mA, 16)); mA = fmaxf(mA, __shfl_xor(mA, 32));
    mB = fmaxf(mB, __shfl_xor(mB, 16)); mB = fmaxf(mB, __shfl_xor(mB, 32));
    if (q == 0) {
      atomicMax((int*)&hp[(size_t)gA * HID + col], __float_as_int(mA));
      if (gB != gA) atomicMax((int*)&hp[(size_t)gB * HID + col], __float_as_int(mB));
    }
  }
}

// ---------------------------------------------------------------------------

__global__ void k_root(const int* __restrict__ batch, int* __restrict__ root, int n) {
  int i = blockIdx.x * 256 + threadIdx.x;
  if (i < n) {
    int g = batch[i];
    if (i == 0 || batch[i - 1] != g) root[g] = i;
  }
}

// ---------------------------------------------------------------------------
// Fused tail: news = relu(x[root]@W0^T+b0); h2 = relu([news,hp]@W1^T+b1);
// out = log_softmax(h2@W2^T+b2). One block per 64 graphs; bf16 MFMA with
// direct-global B fragments (weights L2-resident at 8 blocks); cat staged
// in LDS half-at-a-time (news half -> hp half, acc carries across).
// ---------------------------------------------------------------------------

__global__ __launch_bounds__(256) void k_tail(
    const ushort* __restrict__ xb, const float* __restrict__ hp,
    const int* __restrict__ root,
    const ushort* __restrict__ W0b, const float* __restrict__ b0,
    const ushort* __restrict__ W1b, const float* __restrict__ b1,
    const float* __restrict__ W2, const float* __restrict__ b2,
    float* __restrict__ out, int G) {
  __shared__ ushort sCat[64][264];   // half of cat (256 cols) + pad
  __shared__ int sRoot[64];
  __shared__ float pp[256][2];

  int t = threadIdx.x;
  int g0 = blockIdx.x * 64;
  if (t < 64) sRoot[t] = (g0 + t < G) ? root[g0 + t] : 0;
  __syncthreads();

  int lane = t & 63, w = t >> 6;
  int q = lane >> 4, m = lane & 15;

  // ---- phase A: news = relu(x[root] @ W0b^T + b0) ----
  const ushort* xrow[4];
#pragma unroll
  for (int rt = 0; rt < 4; ++rt)
    xrow[rt] = xb + (size_t)sRoot[rt * 16 + m] * IN_C;

  {
    f32x4 acc[4][4] = {};
#pragma unroll
    for (int kc = 0; kc < 4; ++kc) {
      short8 af[4], bf[4];
#pragma unroll
      for (int rt = 0; rt < 4; ++rt)
        af[rt] = *(const short8*)(xrow[rt] + kc * 32 + q * 8);
#pragma unroll
      for (int ct = 0; ct < 4; ++ct) {
        int col = w * 64 + ct * 16 + m;
        bf[ct] = *(const short8*)(W0b + (size_t)col * IN_C + kc * 32 + q * 8);
      }
#pragma unroll
      for (int rt = 0; rt < 4; ++rt)
#pragma unroll
        for (int ct = 0; ct < 4; ++ct)
          acc[rt][ct] = __builtin_amdgcn_mfma_f32_16x16x32_bf16(af[rt], bf[ct], acc[rt][ct], 0, 0, 0);
    }
    // news -> sCat (bf16)
#pragma unroll
    for (int ct = 0; ct < 4; ++ct) {
      int col = w * 64 + ct * 16 + m;
      float bias = b0[col];
#pragma unroll
      for (int rt = 0; rt < 4; ++rt)
#pragma unroll
        for (int i = 0; i < 4; ++i) {
          int row = rt * 16 + q * 4 + i;
          sCat[row][col] = f2bf(fmaxf(acc[rt][ct][i] + bias, 0.f));
        }
    }
  }
  __syncthreads();

  // ---- phase C: h2 = relu(cat @ W1b^T + b1), K=512 in two halves ----
  f32x4 acc2[4][4] = {};
#pragma unroll
  for (int kc = 0; kc < 8; ++kc) {        // K 0..255: news half
    short8 af[4], bf[4];
#pragma unroll
    for (int rt = 0; rt < 4; ++rt)
      af[rt] = *(const short8*)&sCat[rt * 16 + m][kc * 32 + q * 8];
#pragma unroll
    for (int ct = 0; ct < 4; ++ct) {
      int col = w * 64 + ct * 16 + m;
      bf[ct] = *(const short8*)(W1b + (size_t)col * (2 * HID) + kc * 32 + q * 8);
    }
#pragma unroll
    for (int rt = 0; rt < 4; ++rt)
#pragma unroll
      for (int ct = 0; ct < 4; ++ct)
        acc2[rt][ct] = __builtin_amdgcn_mfma_f32_16x16x32_bf16(af[rt], bf[ct], acc2[rt][ct], 0, 0, 0);
  }
  __syncthreads();
  // overwrite sCat with hp (bf16)
#pragma unroll
  for (int it = 0; it < 16; ++it) {
    int idx = it * 256 + t;               // 4096 float4s = 64 rows x 64/row
    int r = idx >> 6, c4 = (idx & 63) * 4;
    if (g0 + r < G) {
      float4 v = *(const float4*)(hp + (size_t)(g0 + r) * HID + c4);
      ushort4 o = {f2bf(v.x), f2bf(v.y), f2bf(v.z), f2bf(v.w)};
      *(ushort4*)&sCat[r][c4] = o;
    }
  }
  __syncthreads();
#pragma unroll
  for (int kc = 8; kc < 16; ++kc) {       // K 256..511: hp half
    short8 af[4], bf[4];
#pragma unroll
    for (int rt = 0; rt < 4; ++rt)
      af[rt] = *(const short8*)&sCat[rt * 16 + m][(kc - 8) * 32 + q * 8];
#pragma unroll
    for (int ct = 0; ct < 4; ++ct) {
      int col = w * 64 + ct * 16 + m;
      bf[ct] = *(const short8*)(W1b + (size_t)col * (2 * HID) + kc * 32 + q * 8);
    }
#pragma unroll
    for (int rt = 0; rt < 4; ++rt)
#pragma unroll
      for (int ct = 0; ct < 4; ++ct)
        acc2[rt][ct] = __builtin_amdgcn_mfma_f32_16x16x32_bf16(af[rt], bf[ct], acc2[rt][ct], 0, 0, 0);
  }
  __syncthreads();
  // h2 -> sCat (bf16)
#pragma unroll
  for (int ct = 0; ct < 4; ++ct) {
    int col = w * 64 + ct * 16 + m;
    float bias = b1[col];
#pragma unroll
    for (int rt = 0; rt < 4; ++rt)
#pragma unroll
      for (int i = 0; i < 4; ++i) {
        int row = rt * 16 + q * 4 + i;
        sCat[row][col] = f2bf(fmaxf(acc2[rt][ct][i] + bias, 0.f));
      }
  }
  __syncthreads();

  // ---- phase D: logits + log_softmax (fp32) ----
  {
    int row = t >> 2, qq = t & 3;
    float p0 = 0.f, p1 = 0.f;
    for (int c = qq * 64; c < qq * 64 + 64; ++c) {
      float hv = bf2f(sCat[row][c]);
      p0 += hv * W2[c];
      p1 += hv * W2[HID + c];
    }
    pp[t][0] = p0; pp[t][1] = p1;
  }
  __syncthreads();
  if (t < 64 && g0 + t < G) {
    float l0 = b2[0], l1 = b2[1];
#pragma unroll
    for (int k = 0; k < 4; ++k) { l0 += pp[t * 4 + k][0]; l1 += pp[t * 4 + k][1]; }
    float mx = fmaxf(l0, l1);
    float ls = logf(expf(l0 - mx) + expf(l1 - mx));
    out[(size_t)(g0 + t) * 2 + 0] = l0 - mx - ls;
    out[(size_t)(g0 + t) * 2 + 1] = l1 - mx - ls;
  }
}

// ---------------------------------------------------------------------------

extern "C" void kernel_launch(void* const* d_in, const int* in_sizes, int n_in,
                              void* d_out, int out_size, void* d_ws, size_t ws_size,
                              hipStream_t stream) {
  const float* x  = (const float*)d_in[0];
  const int* ei   = (const int*)d_in[1];
  const int* batch= (const int*)d_in[2];
  const float* Wl = (const float*)d_in[3];
  const float* bl = (const float*)d_in[4];
  const float* Wr = (const float*)d_in[5];
  const float* W0 = (const float*)d_in[6];
  const float* b0 = (const float*)d_in[7];
  const float* W1 = (const float*)d_in[8];
  const float* b1 = (const float*)d_in[9];
  const float* W2 = (const float*)d_in[10];
  const float* b2 = (const float*)d_in[11];
  float* out = (float*)d_out;

  const int N = in_sizes[0] / IN_C;
  const int E = in_sizes[1] / 2;
  const int G = out_size / OUT_C;
  const int* src = ei;
  const int* dst = ei + E;
  const int NB = (N + BNODES - 1) >> BSHIFT;

  char* w = (char*)d_ws;
  int* deg       = (int*)w; w += (size_t)N * 4;
  int* row_start = (int*)w; w += (size_t)N * 4;
  int* bcount    = (int*)w; w += 1024;
  int* bbase     = (int*)w; w += 1024;
  int* bcursor   = (int*)w; w += 1024;
  int* root      = (int*)w; w += (size_t)G * 4;
  w = (char*)(((uintptr_t)w + 255) & ~(uintptr_t)255);
  int* csr       = (int*)w; w += (size_t)E * 4;
  w = (char*)(((uintptr_t)w + 255) & ~(uintptr_t)255);
  ushort* xb     = (ushort*)w; w += (size_t)N * IN_C * 2;
  uint32_t* xf8  = (uint32_t*)w; w += (size_t)N * IN_C;
  ushort* aggrb  = (ushort*)w; w += (size_t)N * IN_C * 2;
  ushort* Wcat   = (ushort*)w; w += (size_t)HID * (2 * IN_C) * 2;
  ushort* W0b    = (ushort*)w; w += (size_t)HID * IN_C * 2;
  ushort* W1b    = (ushort*)w; w += (size_t)HID * 2 * HID * 2;
  float* hp      = (float*)w; w += (size_t)G * HID * 4;
  uint32_t* rec  = (uint32_t*)aggrb;   // dead before k_aggr writes aggrb

  hipMemsetAsync(bcount, 0, 1024, stream);
  hipMemsetAsync(hp, 0, (size_t)G * HID * 4, stream);

  k_cast<<<((N * IN_C / 4) + 255) / 256, 256, 0, stream>>>(x, xb, xf8, N * IN_C / 4);
  k_wcat<<<HID, 2 * IN_C, 0, stream>>>(Wl, Wr, Wcat);
  k_cast2<<<(HID * IN_C / 4 + HID * 2 * HID / 4 + 255) / 256, 256, 0, stream>>>(W0, W1, W0b, W1b);
  k_hist<<<1024, 256, 0, stream>>>(dst, bcount, E);
  k_bucket_scan<<<1, 256, 0, stream>>>(bcount, bbase, bcursor);
  k_scatter<<<(E + EPB - 1) / EPB, 256, 0, stream>>>(src, dst, bcursor, rec, E);
  k_csr<<<NB, 256, 0, stream>>>(rec, bbase, bcount, row_start, deg, csr, N);
  k_root<<<(N + 255) / 256, 256, 0, stream>>>(batch, root, N);
  k_aggr<<<(N + 3) / 4, 256, 0, stream>>>(xf8, csr, row_start, deg, aggrb, N);
  k_gemm_pool<<<(N + 63) / 64, 256, 0, stream>>>(aggrb, xb, Wcat, bl, batch, hp, N);
  k_tail<<<(G + 63) / 64, 256, 0, stream>>>(xb, hp, root, W0b, b0, W1b, b1, W2, b2, out, G);
}

// Round 8
// 299.875 us; speedup vs baseline: 3.9327x; 1.0079x over previous
//
#include <hip/hip_runtime.h>
#include <hip/hip_bf16.h>
#include <math.h>
#include <stdint.h>

#define IN_C 128
#define HID  256
#define OUT_C 2

// bucketing for CSR build: 512 nodes per bucket
#define BSHIFT 9
#define BNODES 512
#define EPB 4096   // edges per k_scatter block

typedef __attribute__((ext_vector_type(8))) short short8;
typedef __attribute__((ext_vector_type(4))) float f32x4;
typedef __attribute__((ext_vector_type(2))) float f32x2;

#if defined(__has_builtin)
#if __has_builtin(__builtin_amdgcn_cvt_pk_f32_fp8) && __has_builtin(__builtin_amdgcn_cvt_pk_fp8_f32)
#define HAVE_FP8_CVT 1
#endif
#if __has_builtin(__builtin_amdgcn_global_load_lds)
#define HAVE_GLL 1
#endif
#endif

__device__ __forceinline__ ushort f2bf(float f) {
  uint32_t u = __float_as_uint(f);
  uint32_t r = u + 0x7FFF + ((u >> 16) & 1);   // RNE
  return (ushort)(r >> 16);
}
__device__ __forceinline__ float bf2f(ushort b) {
  return __uint_as_float(((uint32_t)b) << 16);
}

#ifndef HAVE_FP8_CVT
__device__ __forceinline__ uint32_t f2fp8_1(float f) {
  uint32_t u = __float_as_uint(f);
  uint32_t s = (u >> 24) & 0x80;
  float a = fabsf(f);
  if (a >= 448.f) return s | 0x7E;
  if (a < 0.015625f) {
    uint32_t m = (uint32_t)(a * 512.f + 0.5f);
    return s | m;
  }
  uint32_t r = u & 0x7fffffff;
  r += 0x7FFFF + ((r >> 20) & 1);
  uint32_t e = (r >> 23) - 127;
  if ((int)e > 8) return s | 0x7E;
  return s | ((e + 7) << 3) | ((r >> 20) & 7);
}
__device__ __forceinline__ float fp8_2f(uint32_t b) {
  uint32_t s = (b & 0x80) << 24;
  uint32_t e = (b >> 3) & 0xF, m = b & 7;
  if (e == 0) { float f = (float)m * 0.001953125f; return s ? -f : f; }
  return __uint_as_float(s | ((e + 120) << 23) | (m << 20));
}
#endif

// accumulate 8 fp8 elements into 4 packed f32x2 (v_pk_add_f32 path)
__device__ __forceinline__ void acc8f8v(f32x2* s, uint2 v) {
#ifdef HAVE_FP8_CVT
  s[0] += __builtin_amdgcn_cvt_pk_f32_fp8(v.x, false);
  s[1] += __builtin_amdgcn_cvt_pk_f32_fp8(v.x, true);
  s[2] += __builtin_amdgcn_cvt_pk_f32_fp8(v.y, false);
  s[3] += __builtin_amdgcn_cvt_pk_f32_fp8(v.y, true);
#else
  s[0].x += fp8_2f(v.x & 0xff);         s[0].y += fp8_2f((v.x >> 8) & 0xff);
  s[1].x += fp8_2f((v.x >> 16) & 0xff); s[1].y += fp8_2f(v.x >> 24);
  s[2].x += fp8_2f(v.y & 0xff);         s[2].y += fp8_2f((v.y >> 8) & 0xff);
  s[3].x += fp8_2f((v.y >> 16) & 0xff); s[3].y += fp8_2f(v.y >> 24);
#endif
}

// ---------------------------------------------------------------------------
// CSR build
// ---------------------------------------------------------------------------

__global__ void k_hist(const int* __restrict__ dst, int* __restrict__ bcount, int E) {
  __shared__ int h[256];
  int t = threadIdx.x;
  h[t] = 0;
  __syncthreads();
  for (int e = blockIdx.x * 256 + t; e < E; e += gridDim.x * 256)
    atomicAdd(&h[dst[e] >> BSHIFT], 1);
  __syncthreads();
  if (h[t]) atomicAdd(&bcount[t], h[t]);
}

__global__ void k_bucket_scan(const int* __restrict__ bcount,
                              int* __restrict__ bbase, int* __restrict__ bcursor) {
  __shared__ int sd[256];
  int t = threadIdx.x;
  int cnt = bcount[t];
  sd[t] = cnt;
  __syncthreads();
  for (int off = 1; off < 256; off <<= 1) {
    int v = (t >= off) ? sd[t - off] : 0;
    __syncthreads();
    sd[t] += v;
    __syncthreads();
  }
  int base = sd[t] - cnt;
  bbase[t] = base;
  bcursor[t] = base;
}

__global__ __launch_bounds__(256) void k_scatter(
    const int* __restrict__ src, const int* __restrict__ dst,
    int* __restrict__ bcursor, uint32_t* __restrict__ rec, int E) {
  __shared__ int h[256];
  __shared__ int bbase[256];
  __shared__ int lcur[256];
  int t = threadIdx.x;
  int e0 = blockIdx.x * EPB;
  int e1 = e0 + EPB < E ? e0 + EPB : E;
  h[t] = 0; lcur[t] = 0;
  __syncthreads();
  for (int e = e0 + t; e < e1; e += 256)
    atomicAdd(&h[dst[e] >> BSHIFT], 1);
  __syncthreads();
  if (h[t]) bbase[t] = atomicAdd(&bcursor[t], h[t]);
  __syncthreads();
  for (int e = e0 + t; e < e1; e += 256) {
    int d = dst[e];
    int b = d >> BSHIFT;
    int r = atomicAdd(&lcur[b], 1);
    rec[bbase[b] + r] = ((uint32_t)src[e] << BSHIFT) | ((uint32_t)d & (BNODES - 1));
  }
}

__global__ __launch_bounds__(256) void k_csr(
    const uint32_t* __restrict__ rec, const int* __restrict__ bbase,
    const int* __restrict__ bcount,
    int* __restrict__ row_start, int* __restrict__ deg,
    int* __restrict__ csr, int n) {
  __shared__ int ldeg[BNODES];
  __shared__ int lexcl[BNODES];
  __shared__ int ssum[256];
  int t = threadIdx.x;
  int b = blockIdx.x;
  int node0 = b << BSHIFT;
  int ebase = bbase[b];
  int ecnt = bcount[b];

  ldeg[t] = 0; ldeg[t + 256] = 0;
  __syncthreads();
  for (int i = t; i < ecnt; i += 256)
    atomicAdd(&ldeg[rec[ebase + i] & (BNODES - 1)], 1);
  __syncthreads();

  int v0 = ldeg[2 * t], v1 = ldeg[2 * t + 1];
  ssum[t] = v0 + v1;
  __syncthreads();
  for (int off = 1; off < 256; off <<= 1) {
    int v = (t >= off) ? ssum[t - off] : 0;
    __syncthreads();
    ssum[t] += v;
    __syncthreads();
  }
  int excl = ssum[t] - (v0 + v1);
  lexcl[2 * t] = excl;
  lexcl[2 * t + 1] = excl + v0;
  int node = node0 + 2 * t;
  if (node < n) { row_start[node] = ebase + excl; deg[node] = v0; }
  if (node + 1 < n) { row_start[node + 1] = ebase + excl + v0; deg[node + 1] = v1; }
  ldeg[2 * t] = 0; ldeg[2 * t + 1] = 0;
  __syncthreads();
  for (int i = t; i < ecnt; i += 256) {
    uint32_t r = rec[ebase + i];
    int li = r & (BNODES - 1);
    int k = atomicAdd(&ldeg[li], 1);
    csr[ebase + lexcl[li] + k] = (int)(r >> BSHIFT);
  }
}

// ---------------------------------------------------------------------------
// Fused prep: x -> bf16+fp8, Wcat, W0b, W1b casts, root detection.
// Independent index ranges, one launch.
// ---------------------------------------------------------------------------

__global__ void k_prep(const float* __restrict__ x, ushort* __restrict__ xb,
                       uint32_t* __restrict__ xf8, int n4,
                       const float* __restrict__ Wl, const float* __restrict__ Wr,
                       ushort* __restrict__ Wcat,
                       const float* __restrict__ W0, ushort* __restrict__ W0b,
                       const float* __restrict__ W1, ushort* __restrict__ W1b,
                       const int* __restrict__ batch, int* __restrict__ root, int n) {
  int i = blockIdx.x * 256 + threadIdx.x;
  if (i < n4) {
    float4 v = ((const float4*)x)[i];
    ushort4 o = {f2bf(v.x), f2bf(v.y), f2bf(v.z), f2bf(v.w)};
    ((ushort4*)xb)[i] = o;
#ifdef HAVE_FP8_CVT
    int p = __builtin_amdgcn_cvt_pk_fp8_f32(v.x, v.y, 0, false);
    p = __builtin_amdgcn_cvt_pk_fp8_f32(v.z, v.w, p, true);
    xf8[i] = (uint32_t)p;
#else
    xf8[i] = f2fp8_1(v.x) | (f2fp8_1(v.y) << 8) | (f2fp8_1(v.z) << 16) |
             (f2fp8_1(v.w) << 24);
#endif
  }
  if (i < HID * (2 * IN_C) / 4) {         // Wcat: 16384
    int c = i >> 6, c4 = (i & 63) * 4;
    float4 v = (c4 < IN_C) ? *(const float4*)(Wl + (size_t)c * IN_C + c4)
                           : *(const float4*)(Wr + (size_t)c * IN_C + (c4 - IN_C));
    ushort4 o = {f2bf(v.x), f2bf(v.y), f2bf(v.z), f2bf(v.w)};
    *(ushort4*)(Wcat + (size_t)c * (2 * IN_C) + c4) = o;
  }
  if (i < HID * IN_C / 4) {               // W0b: 8192
    float4 v = ((const float4*)W0)[i];
    ushort4 o = {f2bf(v.x), f2bf(v.y), f2bf(v.z), f2bf(v.w)};
    ((ushort4*)W0b)[i] = o;
  }
  if (i < HID * 2 * HID / 4) {            // W1b: 32768
    float4 v = ((const float4*)W1)[i];
    ushort4 o = {f2bf(v.x), f2bf(v.y), f2bf(v.z), f2bf(v.w)};
    ((ushort4*)W1b)[i] = o;
  }
  if (i < n) {
    int g = batch[i];
    if (i == 0 || batch[i - 1] != g) root[g] = i;
  }
}

// ---------------------------------------------------------------------------
// Mean aggregation on fp8 rows: quarter-wave per row, packed f32x2 accum.
// ---------------------------------------------------------------------------

__global__ void k_aggr(const uint32_t* __restrict__ xf8, const int* __restrict__ csr,
                       const int* __restrict__ row_start, const int* __restrict__ deg,
                       ushort* __restrict__ aggr, int n) {
  int wid = threadIdx.x >> 6;
  int lane = threadIdx.x & 63;
  int node = blockIdx.x * 4 + wid;
  if (node >= n) return;
  int base = row_start[node];
  int d = deg[node];
  int q = lane >> 4, li = lane & 15;
  const uint2* xp = (const uint2*)xf8 + li;   // row stride = 16 uint2
  f32x2 s[4] = {};
  int i = q;
  for (; i + 12 < d; i += 16) {
    int n0 = csr[base + i];
    int n1 = csr[base + i + 4];
    int n2 = csr[base + i + 8];
    int n3 = csr[base + i + 12];
    uint2 a = xp[(size_t)n0 * 16];
    uint2 b = xp[(size_t)n1 * 16];
    uint2 c = xp[(size_t)n2 * 16];
    uint2 e = xp[(size_t)n3 * 16];
    acc8f8v(s, a); acc8f8v(s, b); acc8f8v(s, c); acc8f8v(s, e);
  }
  for (; i < d; i += 4) {
    int n0 = csr[base + i];
    uint2 a = xp[(size_t)n0 * 16];
    acc8f8v(s, a);
  }
#pragma unroll
  for (int j = 0; j < 4; ++j) {
    s[j].x += __shfl_xor(s[j].x, 16); s[j].y += __shfl_xor(s[j].y, 16);
    s[j].x += __shfl_xor(s[j].x, 32); s[j].y += __shfl_xor(s[j].y, 32);
  }
  if (q == 0) {
    float inv = 1.0f / (float)(d > 1 ? d : 1);
    uint4 o;
    o.x = (uint32_t)f2bf(s[0].x * inv) | ((uint32_t)f2bf(s[0].y * inv) << 16);
    o.y = (uint32_t)f2bf(s[1].x * inv) | ((uint32_t)f2bf(s[1].y * inv) << 16);
    o.z = (uint32_t)f2bf(s[2].x * inv) | ((uint32_t)f2bf(s[2].y * inv) << 16);
    o.w = (uint32_t)f2bf(s[3].x * inv) | ((uint32_t)f2bf(s[3].y * inv) << 16);
    ((uint4*)(aggr + (size_t)node * IN_C))[li] = o;
  }
}

// ---------------------------------------------------------------------------
// Fused SAGE GEMM (bf16 MFMA) + relu + per-graph max-pool.
// 64 nodes x 256 cols per block. A (= [aggr|x], 32 KB) staged ONCE into LDS
// via global_load_lds with 16-row XOR chunk swizzle -> ONE barrier total.
// B (Wcat, 128 KB, L2-broadcast across all blocks) read direct from global
// with register prefetch across the kc loop. No per-iteration barriers.
// ---------------------------------------------------------------------------

#ifdef HAVE_GLL
__device__ __forceinline__ void load16_lds(const ushort* g, ushort* l) {
  __builtin_amdgcn_global_load_lds(
      (const __attribute__((address_space(1))) uint32_t*)g,
      (__attribute__((address_space(3))) uint32_t*)l, 16, 0, 0);
}
#endif

__global__ __launch_bounds__(256) void k_gemm_pool(
    const ushort* __restrict__ aggrb, const ushort* __restrict__ xb,
    const ushort* __restrict__ Wcat, const float* __restrict__ bl,
    const int* __restrict__ batch, float* __restrict__ hp, int n) {
  __shared__ ushort sA[64 * 256];     // 32 KB; row r at r*256, chunk XOR-swizzled
  __shared__ float sbl[256];
  __shared__ int sBatch[64];

  int t = threadIdx.x;
  int n0 = blockIdx.x * 64;
  sbl[t] = bl[t];
  if (t < 64) sBatch[t] = (n0 + t < n) ? batch[n0 + t] : -1;

  int lane = t & 63, w = t >> 6;
  int q = lane >> 4, m = lane & 15;

  // stage A: 2048 16-B chunks; wave w, instr j covers slots (j*4+w)*64+lane.
  // slot s -> row r = s>>5, phys chunk p = s&31, logical chunk c = p^(r&15).
#pragma unroll
  for (int j = 0; j < 8; ++j) {
    int s = (j * 4 + w) * 64 + lane;
    int r = s >> 5, p = s & 31;
    int c = p ^ (r & 15);
    int gn = n0 + r; gn = gn < n ? gn : n - 1;
    const ushort* g = (c < 16) ? aggrb + (size_t)gn * IN_C + c * 8
                               : xb + (size_t)gn * IN_C + (c - 16) * 8;
#ifdef HAVE_GLL
    load16_lds(g, &sA[(size_t)s * 8]);
#else
    *(uint4*)&sA[(size_t)s * 8] = *(const uint4*)g;
#endif
  }

  // prefetch B chunk 0 (L2-resident, shared by all blocks)
  short8 bf_n[4];
#pragma unroll
  for (int ct = 0; ct < 4; ++ct)
    bf_n[ct] = *(const short8*)(Wcat + (size_t)(w * 64 + ct * 16 + m) * (2 * IN_C) + q * 8);

  __syncthreads();   // drains the A-staging DMA

  f32x4 acc[4][4] = {};
#pragma unroll
  for (int kc = 0; kc < 8; ++kc) {
    short8 bf[4];
#pragma unroll
    for (int ct = 0; ct < 4; ++ct) bf[ct] = bf_n[ct];
    if (kc < 7) {
#pragma unroll
      for (int ct = 0; ct < 4; ++ct)
        bf_n[ct] = *(const short8*)(Wcat + (size_t)(w * 64 + ct * 16 + m) * (2 * IN_C) +
                                    (kc + 1) * 32 + q * 8);
    }
    short8 af[4];
#pragma unroll
    for (int rt = 0; rt < 4; ++rt) {
      int r = rt * 16 + m;
      int p = (kc * 4 + q) ^ m;
      af[rt] = *(const short8*)&sA[r * 256 + p * 8];
    }
#pragma unroll
    for (int rt = 0; rt < 4; ++rt)
#pragma unroll
      for (int ct = 0; ct < 4; ++ct)
        acc[rt][ct] = __builtin_amdgcn_mfma_f32_16x16x32_bf16(af[rt], bf[ct], acc[rt][ct], 0, 0, 0);
  }

  // epilogue: bias + relu + per-graph max (registers -> <=2 atomics/col/wave)
  int last = n - 1 - n0; last = last < 63 ? last : 63;
  int gA = sBatch[0];
  int gB = sBatch[last];
#pragma unroll
  for (int ct = 0; ct < 4; ++ct) {
    int col = w * 64 + ct * 16 + m;
    float bias = sbl[col];
    float mA = 0.f, mB = 0.f;
#pragma unroll
    for (int rt = 0; rt < 4; ++rt) {
#pragma unroll
      for (int i = 0; i < 4; ++i) {
        int lr = rt * 16 + q * 4 + i;
        if (n0 + lr < n) {
          float v = fmaxf(acc[rt][ct][i] + bias, 0.f);
          if (sBatch[lr] == gA) mA = fmaxf(mA, v);
          else mB = fmaxf(mB, v);
        }
      }
    }
    mA = fmaxf(mA, __shfl_xor(mA, 16)); mA = fmaxf(mA, __shfl_xor(mA, 32));
    mB = fmaxf(mB, __shfl_xor(mB, 16)); mB = fmaxf(mB, __shfl_xor(mB, 32));
    if (q == 0) {
      atomicMax((int*)&hp[(size_t)gA * HID + col], __float_as_int(mA));
      if (gB != gA) atomicMax((int*)&hp[(size_t)gB * HID + col], __float_as_int(mB));
    }
  }
}

// ---------------------------------------------------------------------------
// Fused tail MLP (bf16 MFMA + fp32 softmax), one block per 64 graphs
// ---------------------------------------------------------------------------

__global__ __launch_bounds__(256) void k_tail(
    const ushort* __restrict__ xb, const float* __restrict__ hp,
    const int* __restrict__ root,
    const ushort* __restrict__ W0b, const float* __restrict__ b0,
    const ushort* __restrict__ W1b, const float* __restrict__ b1,
    const float* __restrict__ W2, const float* __restrict__ b2,
    float* __restrict__ out, int G) {
  __shared__ ushort sCat[64][264];
  __shared__ int sRoot[64];
  __shared__ float pp[256][2];

  int t = threadIdx.x;
  int g0 = blockIdx.x * 64;
  if (t < 64) sRoot[t] = (g0 + t < G) ? root[g0 + t] : 0;
  __syncthreads();

  int lane = t & 63, w = t >> 6;
  int q = lane >> 4, m = lane & 15;

  const ushort* xrow[4];
#pragma unroll
  for (int rt = 0; rt < 4; ++rt)
    xrow[rt] = xb + (size_t)sRoot[rt * 16 + m] * IN_C;

  {
    f32x4 acc[4][4] = {};
#pragma unroll
    for (int kc = 0; kc < 4; ++kc) {
      short8 af[4], bf[4];
#pragma unroll
      for (int rt = 0; rt < 4; ++rt)
        af[rt] = *(const short8*)(xrow[rt] + kc * 32 + q * 8);
#pragma unroll
      for (int ct = 0; ct < 4; ++ct) {
        int col = w * 64 + ct * 16 + m;
        bf[ct] = *(const short8*)(W0b + (size_t)col * IN_C + kc * 32 + q * 8);
      }
#pragma unroll
      for (int rt = 0; rt < 4; ++rt)
#pragma unroll
        for (int ct = 0; ct < 4; ++ct)
          acc[rt][ct] = __builtin_amdgcn_mfma_f32_16x16x32_bf16(af[rt], bf[ct], acc[rt][ct], 0, 0, 0);
    }
#pragma unroll
    for (int ct = 0; ct < 4; ++ct) {
      int col = w * 64 + ct * 16 + m;
      float bias = b0[col];
#pragma unroll
      for (int rt = 0; rt < 4; ++rt)
#pragma unroll
        for (int i = 0; i < 4; ++i) {
          int row = rt * 16 + q * 4 + i;
          sCat[row][col] = f2bf(fmaxf(acc[rt][ct][i] + bias, 0.f));
        }
    }
  }
  __syncthreads();

  f32x4 acc2[4][4] = {};
#pragma unroll
  for (int kc = 0; kc < 8; ++kc) {
    short8 af[4], bf[4];
#pragma unroll
    for (int rt = 0; rt < 4; ++rt)
      af[rt] = *(const short8*)&sCat[rt * 16 + m][kc * 32 + q * 8];
#pragma unroll
    for (int ct = 0; ct < 4; ++ct) {
      int col = w * 64 + ct * 16 + m;
      bf[ct] = *(const short8*)(W1b + (size_t)col * (2 * HID) + kc * 32 + q * 8);
    }
#pragma unroll
    for (int rt = 0; rt < 4; ++rt)
#pragma unroll
      for (int ct = 0; ct < 4; ++ct)
        acc2[rt][ct] = __builtin_amdgcn_mfma_f32_16x16x32_bf16(af[rt], bf[ct], acc2[rt][ct], 0, 0, 0);
  }
  __syncthreads();
#pragma unroll
  for (int it = 0; it < 16; ++it) {
    int idx = it * 256 + t;
    int r = idx >> 6, c4 = (idx & 63) * 4;
    if (g0 + r < G) {
      float4 v = *(const float4*)(hp + (size_t)(g0 + r) * HID + c4);
      ushort4 o = {f2bf(v.x), f2bf(v.y), f2bf(v.z), f2bf(v.w)};
      *(ushort4*)&sCat[r][c4] = o;
    }
  }
  __syncthreads();
#pragma unroll
  for (int kc = 8; kc < 16; ++kc) {
    short8 af[4], bf[4];
#pragma unroll
    for (int rt = 0; rt < 4; ++rt)
      af[rt] = *(const short8*)&sCat[rt * 16 + m][(kc - 8) * 32 + q * 8];
#pragma unroll
    for (int ct = 0; ct < 4; ++ct) {
      int col = w * 64 + ct * 16 + m;
      bf[ct] = *(const short8*)(W1b + (size_t)col * (2 * HID) + kc * 32 + q * 8);
    }
#pragma unroll
    for (int rt = 0; rt < 4; ++rt)
#pragma unroll
      for (int ct = 0; ct < 4; ++ct)
        acc2[rt][ct] = __builtin_amdgcn_mfma_f32_16x16x32_bf16(af[rt], bf[ct], acc2[rt][ct], 0, 0, 0);
  }
  __syncthreads();
#pragma unroll
  for (int ct = 0; ct < 4; ++ct) {
    int col = w * 64 + ct * 16 + m;
    float bias = b1[col];
#pragma unroll
    for (int rt = 0; rt < 4; ++rt)
#pragma unroll
      for (int i = 0; i < 4; ++i) {
        int row = rt * 16 + q * 4 + i;
        sCat[row][col] = f2bf(fmaxf(acc2[rt][ct][i] + bias, 0.f));
      }
  }
  __syncthreads();

  {
    int row = t >> 2, qq = t & 3;
    float p0 = 0.f, p1 = 0.f;
    for (int c = qq * 64; c < qq * 64 + 64; ++c) {
      float hv = bf2f(sCat[row][c]);
      p0 += hv * W2[c];
      p1 += hv * W2[HID + c];
    }
    pp[t][0] = p0; pp[t][1] = p1;
  }
  __syncthreads();
  if (t < 64 && g0 + t < G) {
    float l0 = b2[0], l1 = b2[1];
#pragma unroll
    for (int k = 0; k < 4; ++k) { l0 += pp[t * 4 + k][0]; l1 += pp[t * 4 + k][1]; }
    float mx = fmaxf(l0, l1);
    float ls = logf(expf(l0 - mx) + expf(l1 - mx));
    out[(size_t)(g0 + t) * 2 + 0] = l0 - mx - ls;
    out[(size_t)(g0 + t) * 2 + 1] = l1 - mx - ls;
  }
}

// ---------------------------------------------------------------------------

extern "C" void kernel_launch(void* const* d_in, const int* in_sizes, int n_in,
                              void* d_out, int out_size, void* d_ws, size_t ws_size,
                              hipStream_t stream) {
  const float* x  = (const float*)d_in[0];
  const int* ei   = (const int*)d_in[1];
  const int* batch= (const int*)d_in[2];
  const float* Wl = (const float*)d_in[3];
  const float* bl = (const float*)d_in[4];
  const float* Wr = (const float*)d_in[5];
  const float* W0 = (const float*)d_in[6];
  const float* b0 = (const float*)d_in[7];
  const float* W1 = (const float*)d_in[8];
  const float* b1 = (const float*)d_in[9];
  const float* W2 = (const float*)d_in[10];
  const float* b2 = (const float*)d_in[11];
  float* out = (float*)d_out;

  const int N = in_sizes[0] / IN_C;
  const int E = in_sizes[1] / 2;
  const int G = out_size / OUT_C;
  const int* src = ei;
  const int* dst = ei + E;
  const int NB = (N + BNODES - 1) >> BSHIFT;

  char* w = (char*)d_ws;
  int* deg       = (int*)w; w += (size_t)N * 4;
  int* row_start = (int*)w; w += (size_t)N * 4;
  int* bcount    = (int*)w; w += 1024;
  int* bbase     = (int*)w; w += 1024;
  int* bcursor   = (int*)w; w += 1024;
  int* root      = (int*)w; w += (size_t)G * 4;
  w = (char*)(((uintptr_t)w + 255) & ~(uintptr_t)255);
  int* csr       = (int*)w; w += (size_t)E * 4;
  w = (char*)(((uintptr_t)w + 255) & ~(uintptr_t)255);
  ushort* xb     = (ushort*)w; w += (size_t)N * IN_C * 2;
  uint32_t* xf8  = (uint32_t*)w; w += (size_t)N * IN_C;
  ushort* aggrb  = (ushort*)w; w += (size_t)N * IN_C * 2;
  ushort* Wcat   = (ushort*)w; w += (size_t)HID * (2 * IN_C) * 2;
  ushort* W0b    = (ushort*)w; w += (size_t)HID * IN_C * 2;
  ushort* W1b    = (ushort*)w; w += (size_t)HID * 2 * HID * 2;
  float* hp      = (float*)w; w += (size_t)G * HID * 4;
  uint32_t* rec  = (uint32_t*)aggrb;   // dead before k_aggr writes aggrb

  hipMemsetAsync(bcount, 0, 1024, stream);
  hipMemsetAsync(hp, 0, (size_t)G * HID * 4, stream);

  int n4 = N * IN_C / 4;
  k_prep<<<(n4 + 255) / 256, 256, 0, stream>>>(x, xb, xf8, n4, Wl, Wr, Wcat,
                                               W0, W0b, W1, W1b, batch, root, N);
  k_hist<<<1024, 256, 0, stream>>>(dst, bcount, E);
  k_bucket_scan<<<1, 256, 0, stream>>>(bcount, bbase, bcursor);
  k_scatter<<<(E + EPB - 1) / EPB, 256, 0, stream>>>(src, dst, bcursor, rec, E);
  k_csr<<<NB, 256, 0, stream>>>(rec, bbase, bcount, row_start, deg, csr, N);
  k_aggr<<<(N + 3) / 4, 256, 0, stream>>>(xf8, csr, row_start, deg, aggrb, N);
  k_gemm_pool<<<(N + 63) / 64, 256, 0, stream>>>(aggrb, xb, Wcat, bl, batch, hp, N);
  k_tail<<<(G + 63) / 64, 256, 0, stream>>>(xb, hp, root, W0b, b0, W1b, b1, W2, b2, out, G);
}

// Round 9
// 274.771 us; speedup vs baseline: 4.2920x; 1.0914x over previous
//
#include <hip/hip_runtime.h>
#include <hip/hip_bf16.h>
#include <math.h>
#include <stdint.h>

#define IN_C 128
#define HID  256
#define OUT_C 2

// bucketing for CSR build: 256 nodes per bucket
#define BSHIFT 8
#define BNODES 256
#define EPB 4096        // edges per k_scatter block
#define HISTB 784       // blocks of k_prep that do the histogram
#define PADB 3840       // max pad slack per bucket (15 * 256)

typedef __attribute__((ext_vector_type(8))) short short8;
typedef __attribute__((ext_vector_type(4))) float f32x4;
typedef __attribute__((ext_vector_type(2))) float f32x2;

#if defined(__has_builtin)
#if __has_builtin(__builtin_amdgcn_cvt_pk_f32_fp8) && __has_builtin(__builtin_amdgcn_cvt_pk_fp8_f32)
#define HAVE_FP8_CVT 1
#endif
#if __has_builtin(__builtin_amdgcn_global_load_lds)
#define HAVE_GLL 1
#endif
#endif

__device__ __forceinline__ ushort f2bf(float f) {
  uint32_t u = __float_as_uint(f);
  uint32_t r = u + 0x7FFF + ((u >> 16) & 1);   // RNE
  return (ushort)(r >> 16);
}
__device__ __forceinline__ float bf2f(ushort b) {
  return __uint_as_float(((uint32_t)b) << 16);
}

#ifndef HAVE_FP8_CVT
__device__ __forceinline__ uint32_t f2fp8_1(float f) {
  uint32_t u = __float_as_uint(f);
  uint32_t s = (u >> 24) & 0x80;
  float a = fabsf(f);
  if (a >= 448.f) return s | 0x7E;
  if (a < 0.015625f) {
    uint32_t m = (uint32_t)(a * 512.f + 0.5f);
    return s | m;
  }
  uint32_t r = u & 0x7fffffff;
  r += 0x7FFFF + ((r >> 20) & 1);
  uint32_t e = (r >> 23) - 127;
  if ((int)e > 8) return s | 0x7E;
  return s | ((e + 7) << 3) | ((r >> 20) & 7);
}
__device__ __forceinline__ float fp8_2f(uint32_t b) {
  uint32_t s = (b & 0x80) << 24;
  uint32_t e = (b >> 3) & 0xF, m = b & 7;
  if (e == 0) { float f = (float)m * 0.001953125f; return s ? -f : f; }
  return __uint_as_float(s | ((e + 120) << 23) | (m << 20));
}
#endif

__device__ __forceinline__ void acc8f8v(f32x2* s, uint2 v) {
#ifdef HAVE_FP8_CVT
  s[0] += __builtin_amdgcn_cvt_pk_f32_fp8(v.x, false);
  s[1] += __builtin_amdgcn_cvt_pk_f32_fp8(v.x, true);
  s[2] += __builtin_amdgcn_cvt_pk_f32_fp8(v.y, false);
  s[3] += __builtin_amdgcn_cvt_pk_f32_fp8(v.y, true);
#else
  s[0].x += fp8_2f(v.x & 0xff);         s[0].y += fp8_2f((v.x >> 8) & 0xff);
  s[1].x += fp8_2f((v.x >> 16) & 0xff); s[1].y += fp8_2f(v.x >> 24);
  s[2].x += fp8_2f(v.y & 0xff);         s[2].y += fp8_2f((v.y >> 8) & 0xff);
  s[3].x += fp8_2f((v.y >> 16) & 0xff); s[3].y += fp8_2f(v.y >> 24);
#endif
}

// ---------------------------------------------------------------------------
// Fused prep: x -> bf16+fp8, weight casts, root detection, hp zero,
// zero-row init, AND the bucket histogram (blocks < HISTB).
// ---------------------------------------------------------------------------

__global__ void k_prep(const float* __restrict__ x, ushort* __restrict__ xb,
                       uint32_t* __restrict__ xf8, int n4,
                       const float* __restrict__ Wl, const float* __restrict__ Wr,
                       ushort* __restrict__ Wcat,
                       const float* __restrict__ W0, ushort* __restrict__ W0b,
                       const float* __restrict__ W1, ushort* __restrict__ W1b,
                       const int* __restrict__ batch, int* __restrict__ root, int n,
                       const int* __restrict__ dst, int E, int* __restrict__ bcount,
                       float* __restrict__ hp, int hp4) {
  __shared__ int h[512];
  int t = threadIdx.x;
  int i = blockIdx.x * 256 + t;
  if (i < n4) {
    float4 v = ((const float4*)x)[i];
    ushort4 o = {f2bf(v.x), f2bf(v.y), f2bf(v.z), f2bf(v.w)};
    ((ushort4*)xb)[i] = o;
#ifdef HAVE_FP8_CVT
    int p = __builtin_amdgcn_cvt_pk_fp8_f32(v.x, v.y, 0, false);
    p = __builtin_amdgcn_cvt_pk_fp8_f32(v.z, v.w, p, true);
    xf8[i] = (uint32_t)p;
#else
    xf8[i] = f2fp8_1(v.x) | (f2fp8_1(v.y) << 8) | (f2fp8_1(v.z) << 16) |
             (f2fp8_1(v.w) << 24);
#endif
  }
  if (i < 32) xf8[(size_t)n * 32 + i] = 0;   // zero row (pad target)
  if (i < HID * (2 * IN_C) / 4) {
    int c = i >> 6, c4 = (i & 63) * 4;
    float4 v = (c4 < IN_C) ? *(const float4*)(Wl + (size_t)c * IN_C + c4)
                           : *(const float4*)(Wr + (size_t)c * IN_C + (c4 - IN_C));
    ushort4 o = {f2bf(v.x), f2bf(v.y), f2bf(v.z), f2bf(v.w)};
    *(ushort4*)(Wcat + (size_t)c * (2 * IN_C) + c4) = o;
  }
  if (i < HID * IN_C / 4) {
    float4 v = ((const float4*)W0)[i];
    ushort4 o = {f2bf(v.x), f2bf(v.y), f2bf(v.z), f2bf(v.w)};
    ((ushort4*)W0b)[i] = o;
  }
  if (i < HID * 2 * HID / 4) {
    float4 v = ((const float4*)W1)[i];
    ushort4 o = {f2bf(v.x), f2bf(v.y), f2bf(v.z), f2bf(v.w)};
    ((ushort4*)W1b)[i] = o;
  }
  if (i < hp4) ((float4*)hp)[i] = make_float4(0.f, 0.f, 0.f, 0.f);
  if (i < n) {
    int g = batch[i];
    if (i == 0 || batch[i - 1] != g) root[g] = i;
  }
  if (blockIdx.x < HISTB) {
    h[t] = 0; h[t + 256] = 0;
    __syncthreads();
    for (int e = blockIdx.x * 256 + t; e < E; e += HISTB * 256)
      atomicAdd(&h[dst[e] >> BSHIFT], 1);
    __syncthreads();
    if (h[t]) atomicAdd(&bcount[t], h[t]);
    if (h[t + 256]) atomicAdd(&bcount[t + 256], h[t + 256]);
  }
}

// ---------------------------------------------------------------------------
// Partition (src<<8 | dst&255) records into bucket regions. Bucket bases
// derived locally by scanning bcount in LDS; inter-block reservation via
// zero-initialized global cursor.
// ---------------------------------------------------------------------------

__global__ __launch_bounds__(256) void k_scatter(
    const int* __restrict__ src, const int* __restrict__ dst,
    const int* __restrict__ bcount, int* __restrict__ cursor0,
    uint32_t* __restrict__ rec, int E) {
  __shared__ int sBB[512];
  __shared__ int stmp[256];
  __shared__ int h[512];
  __shared__ int hb[512];
  __shared__ int lcur[512];
  int t = threadIdx.x;
  // exclusive scan of bcount -> sBB
  int c0 = bcount[2 * t], c1 = bcount[2 * t + 1];
  stmp[t] = c0 + c1;
  h[2 * t] = 0; h[2 * t + 1] = 0;
  lcur[2 * t] = 0; lcur[2 * t + 1] = 0;
  __syncthreads();
  for (int off = 1; off < 256; off <<= 1) {
    int v = (t >= off) ? stmp[t - off] : 0;
    __syncthreads();
    stmp[t] += v;
    __syncthreads();
  }
  int ex = stmp[t] - (c0 + c1);
  sBB[2 * t] = ex;
  sBB[2 * t + 1] = ex + c0;
  __syncthreads();

  int e0 = blockIdx.x * EPB;
  int e1 = e0 + EPB < E ? e0 + EPB : E;
  for (int e = e0 + t; e < e1; e += 256)
    atomicAdd(&h[dst[e] >> BSHIFT], 1);
  __syncthreads();
  for (int j = t; j < 512; j += 256)
    if (h[j]) hb[j] = sBB[j] + atomicAdd(&cursor0[j], h[j]);
  __syncthreads();
  for (int e = e0 + t; e < e1; e += 256) {
    int d = dst[e];
    int b = d >> BSHIFT;
    int r = atomicAdd(&lcur[b], 1);
    rec[hb[b] + r] = ((uint32_t)src[e] << BSHIFT) | ((uint32_t)d & (BNODES - 1));
  }
}

// ---------------------------------------------------------------------------
// Per-bucket CSR with 16-padding: each node's list padded to a multiple of
// 16 (pads -> zero row), padded starts 16-aligned. One block per bucket.
// ---------------------------------------------------------------------------

__global__ __launch_bounds__(256) void k_csr(
    const uint32_t* __restrict__ rec, const int* __restrict__ bcount,
    int* __restrict__ row_start, int* __restrict__ deg,
    int* __restrict__ csr, int n, int zrow) {
  __shared__ int stmp[256];
  __shared__ int lexcl[256];
  __shared__ int ldeg[256];
  __shared__ int lcur[256];
  int t = threadIdx.x, b = blockIdx.x;
  // ebase = prefix sum of bcount below b
  int i2 = 2 * t;
  int v = ((i2 < b) ? bcount[i2] : 0) + ((i2 + 1 < b) ? bcount[i2 + 1] : 0);
  stmp[t] = v;
  ldeg[t] = 0;
  __syncthreads();
  for (int off = 128; off > 0; off >>= 1) {
    if (t < off) stmp[t] += stmp[t + off];
    __syncthreads();
  }
  int ebase = stmp[0];
  int ecnt = bcount[b];
  int padbase = ((ebase + 15) & ~15) + PADB * b;
  int node0 = b << BSHIFT;
  __syncthreads();

  for (int i = t; i < ecnt; i += 256)
    atomicAdd(&ldeg[rec[ebase + i] & (BNODES - 1)], 1);
  __syncthreads();
  int d = ldeg[t];
  int P = (d + 15) & ~15;
  stmp[t] = P;
  __syncthreads();
  for (int off = 1; off < 256; off <<= 1) {
    int vv = (t >= off) ? stmp[t - off] : 0;
    __syncthreads();
    stmp[t] += vv;
    __syncthreads();
  }
  int excl = stmp[t] - P;
  lexcl[t] = excl;
  int rs = padbase + excl;
  int node = node0 + t;
  if (node < n) { row_start[node] = rs; deg[node] = d; }
  lcur[t] = 0;
  __syncthreads();
  for (int i = t; i < ecnt; i += 256) {
    uint32_t r = rec[ebase + i];
    int li = r & (BNODES - 1);
    int k = atomicAdd(&lcur[li], 1);
    csr[padbase + lexcl[li] + k] = (int)(r >> BSHIFT);
  }
  for (int k = d; k < P; ++k) csr[rs + k] = zrow;
}

// ---------------------------------------------------------------------------
// Mean aggregation on fp8 rows: quarter-wave per 4-neighbor chunk, padded
// lists -> fixed trip count, int4 neighbor-id loads, 4 gathers in flight.
// ---------------------------------------------------------------------------

__global__ void k_aggr(const uint32_t* __restrict__ xf8, const int* __restrict__ csr,
                       const int* __restrict__ row_start, const int* __restrict__ deg,
                       ushort* __restrict__ aggr, int n) {
  int wid = threadIdx.x >> 6;
  int lane = threadIdx.x & 63;
  int node = blockIdx.x * 4 + wid;
  if (node >= n) return;
  int base = row_start[node];
  int d = deg[node];
  int P = (d + 15) & ~15;
  int q = lane >> 4, li = lane & 15;
  const uint2* xp = (const uint2*)xf8 + li;   // row stride = 16 uint2
  f32x2 s[4] = {};
  for (int i = 4 * q; i < P; i += 16) {
    int4 ns = *(const int4*)(csr + base + i);
    uint2 a = xp[(size_t)ns.x * 16];
    uint2 b = xp[(size_t)ns.y * 16];
    uint2 c = xp[(size_t)ns.z * 16];
    uint2 e = xp[(size_t)ns.w * 16];
    acc8f8v(s, a); acc8f8v(s, b); acc8f8v(s, c); acc8f8v(s, e);
  }
#pragma unroll
  for (int j = 0; j < 4; ++j) {
    s[j].x += __shfl_xor(s[j].x, 16); s[j].y += __shfl_xor(s[j].y, 16);
    s[j].x += __shfl_xor(s[j].x, 32); s[j].y += __shfl_xor(s[j].y, 32);
  }
  if (q == 0) {
    float inv = 1.0f / (float)(d > 1 ? d : 1);
    uint4 o;
    o.x = (uint32_t)f2bf(s[0].x * inv) | ((uint32_t)f2bf(s[0].y * inv) << 16);
    o.y = (uint32_t)f2bf(s[1].x * inv) | ((uint32_t)f2bf(s[1].y * inv) << 16);
    o.z = (uint32_t)f2bf(s[2].x * inv) | ((uint32_t)f2bf(s[2].y * inv) << 16);
    o.w = (uint32_t)f2bf(s[3].x * inv) | ((uint32_t)f2bf(s[3].y * inv) << 16);
    ((uint4*)(aggr + (size_t)node * IN_C))[li] = o;
  }
}

// ---------------------------------------------------------------------------
// Fused SAGE GEMM (bf16 MFMA) + relu + per-graph max-pool.
// A staged once into LDS via DMA (one barrier); B direct-global w/ prefetch.
// ---------------------------------------------------------------------------

#ifdef HAVE_GLL
__device__ __forceinline__ void load16_lds(const ushort* g, ushort* l) {
  __builtin_amdgcn_global_load_lds(
      (const __attribute__((address_space(1))) uint32_t*)g,
      (__attribute__((address_space(3))) uint32_t*)l, 16, 0, 0);
}
#endif

__global__ __launch_bounds__(256) void k_gemm_pool(
    const ushort* __restrict__ aggrb, const ushort* __restrict__ xb,
    const ushort* __restrict__ Wcat, const float* __restrict__ bl,
    const int* __restrict__ batch, float* __restrict__ hp, int n) {
  __shared__ ushort sA[64 * 256];
  __shared__ float sbl[256];
  __shared__ int sBatch[64];

  int t = threadIdx.x;
  int n0 = blockIdx.x * 64;
  sbl[t] = bl[t];
  if (t < 64) sBatch[t] = (n0 + t < n) ? batch[n0 + t] : -1;

  int lane = t & 63, w = t >> 6;
  int q = lane >> 4, m = lane & 15;

#pragma unroll
  for (int j = 0; j < 8; ++j) {
    int s = (j * 4 + w) * 64 + lane;
    int r = s >> 5, p = s & 31;
    int c = p ^ (r & 15);
    int gn = n0 + r; gn = gn < n ? gn : n - 1;
    const ushort* g = (c < 16) ? aggrb + (size_t)gn * IN_C + c * 8
                               : xb + (size_t)gn * IN_C + (c - 16) * 8;
#ifdef HAVE_GLL
    load16_lds(g, &sA[(size_t)s * 8]);
#else
    *(uint4*)&sA[(size_t)s * 8] = *(const uint4*)g;
#endif
  }

  short8 bf_n[4];
#pragma unroll
  for (int ct = 0; ct < 4; ++ct)
    bf_n[ct] = *(const short8*)(Wcat + (size_t)(w * 64 + ct * 16 + m) * (2 * IN_C) + q * 8);

  __syncthreads();

  f32x4 acc[4][4] = {};
#pragma unroll
  for (int kc = 0; kc < 8; ++kc) {
    short8 bf[4];
#pragma unroll
    for (int ct = 0; ct < 4; ++ct) bf[ct] = bf_n[ct];
    if (kc < 7) {
#pragma unroll
      for (int ct = 0; ct < 4; ++ct)
        bf_n[ct] = *(const short8*)(Wcat + (size_t)(w * 64 + ct * 16 + m) * (2 * IN_C) +
                                    (kc + 1) * 32 + q * 8);
    }
    short8 af[4];
#pragma unroll
    for (int rt = 0; rt < 4; ++rt) {
      int r = rt * 16 + m;
      int p = (kc * 4 + q) ^ m;
      af[rt] = *(const short8*)&sA[r * 256 + p * 8];
    }
#pragma unroll
    for (int rt = 0; rt < 4; ++rt)
#pragma unroll
      for (int ct = 0; ct < 4; ++ct)
        acc[rt][ct] = __builtin_amdgcn_mfma_f32_16x16x32_bf16(af[rt], bf[ct], acc[rt][ct], 0, 0, 0);
  }

  int last = n - 1 - n0; last = last < 63 ? last : 63;
  int gA = sBatch[0];
  int gB = sBatch[last];
#pragma unroll
  for (int ct = 0; ct < 4; ++ct) {
    int col = w * 64 + ct * 16 + m;
    float bias = sbl[col];
    float mA = 0.f, mB = 0.f;
#pragma unroll
    for (int rt = 0; rt < 4; ++rt) {
#pragma unroll
      for (int i = 0; i < 4; ++i) {
        int lr = rt * 16 + q * 4 + i;
        if (n0 + lr < n) {
          float v = fmaxf(acc[rt][ct][i] + bias, 0.f);
          if (sBatch[lr] == gA) mA = fmaxf(mA, v);
          else mB = fmaxf(mB, v);
        }
      }
    }
    mA = fmaxf(mA, __shfl_xor(mA, 16)); mA = fmaxf(mA, __shfl_xor(mA, 32));
    mB = fmaxf(mB, __shfl_xor(mB, 16)); mB = fmaxf(mB, __shfl_xor(mB, 32));
    if (q == 0) {
      atomicMax((int*)&hp[(size_t)gA * HID + col], __float_as_int(mA));
      if (gB != gA) atomicMax((int*)&hp[(size_t)gB * HID + col], __float_as_int(mB));
    }
  }
}

// ---------------------------------------------------------------------------
// Fused tail MLP: 32 graphs per block (16 blocks), bf16 MFMA, W prefetch.
// ---------------------------------------------------------------------------

__global__ __launch_bounds__(256) void k_tail(
    const ushort* __restrict__ xb, const float* __restrict__ hp,
    const int* __restrict__ root,
    const ushort* __restrict__ W0b, const float* __restrict__ b0,
    const ushort* __restrict__ W1b, const float* __restrict__ b1,
    const float* __restrict__ W2, const float* __restrict__ b2,
    float* __restrict__ out, int G) {
  __shared__ ushort sCat[32][264];
  __shared__ int sRoot[32];
  __shared__ float pp[256][2];

  int t = threadIdx.x;
  int g0 = blockIdx.x * 32;
  if (t < 32) sRoot[t] = (g0 + t < G) ? root[g0 + t] : 0;
  __syncthreads();

  int lane = t & 63, w = t >> 6;
  int q = lane >> 4, m = lane & 15;

  const ushort* xrow[2];
#pragma unroll
  for (int rt = 0; rt < 2; ++rt)
    xrow[rt] = xb + (size_t)sRoot[rt * 16 + m] * IN_C;

  // phase A: news = relu(x[root] @ W0b^T + b0)
  {
    f32x4 acc[2][4] = {};
#pragma unroll
    for (int kc = 0; kc < 4; ++kc) {
      short8 af[2], bf[4];
#pragma unroll
      for (int rt = 0; rt < 2; ++rt)
        af[rt] = *(const short8*)(xrow[rt] + kc * 32 + q * 8);
#pragma unroll
      for (int ct = 0; ct < 4; ++ct) {
        int col = w * 64 + ct * 16 + m;
        bf[ct] = *(const short8*)(W0b + (size_t)col * IN_C + kc * 32 + q * 8);
      }
#pragma unroll
      for (int rt = 0; rt < 2; ++rt)
#pragma unroll
        for (int ct = 0; ct < 4; ++ct)
          acc[rt][ct] = __builtin_amdgcn_mfma_f32_16x16x32_bf16(af[rt], bf[ct], acc[rt][ct], 0, 0, 0);
    }
#pragma unroll
    for (int ct = 0; ct < 4; ++ct) {
      int col = w * 64 + ct * 16 + m;
      float bias = b0[col];
#pragma unroll
      for (int rt = 0; rt < 2; ++rt)
#pragma unroll
        for (int i = 0; i < 4; ++i) {
          int row = rt * 16 + q * 4 + i;
          sCat[row][col] = f2bf(fmaxf(acc[rt][ct][i] + bias, 0.f));
        }
    }
  }
  __syncthreads();

  // phase C: h2 = relu(cat @ W1b^T + b1), K=512 in two halves, W prefetch
  f32x4 acc2[2][4] = {};
  short8 bfn[4];
#pragma unroll
  for (int ct = 0; ct < 4; ++ct)
    bfn[ct] = *(const short8*)(W1b + (size_t)(w * 64 + ct * 16 + m) * (2 * HID) + q * 8);
#pragma unroll
  for (int kc = 0; kc < 8; ++kc) {
    short8 af[2], bf[4];
#pragma unroll
    for (int ct = 0; ct < 4; ++ct) bf[ct] = bfn[ct];
    if (kc < 7) {
#pragma unroll
      for (int ct = 0; ct < 4; ++ct)
        bfn[ct] = *(const short8*)(W1b + (size_t)(w * 64 + ct * 16 + m) * (2 * HID) +
                                   (kc + 1) * 32 + q * 8);
    }
#pragma unroll
    for (int rt = 0; rt < 2; ++rt)
      af[rt] = *(const short8*)&sCat[rt * 16 + m][kc * 32 + q * 8];
#pragma unroll
    for (int rt = 0; rt < 2; ++rt)
#pragma unroll
      for (int ct = 0; ct < 4; ++ct)
        acc2[rt][ct] = __builtin_amdgcn_mfma_f32_16x16x32_bf16(af[rt], bf[ct], acc2[rt][ct], 0, 0, 0);
  }
  __syncthreads();
#pragma unroll
  for (int it = 0; it < 8; ++it) {
    int idx = it * 256 + t;          // 2048 float4 = 32 rows x 64/row
    int r = idx >> 6, c4 = (idx & 63) * 4;
    if (g0 + r < G) {
      float4 v = *(const float4*)(hp + (size_t)(g0 + r) * HID + c4);
      ushort4 o = {f2bf(v.x), f2bf(v.y), f2bf(v.z), f2bf(v.w)};
      *(ushort4*)&sCat[r][c4] = o;
    }
  }
  __syncthreads();
#pragma unroll
  for (int ct = 0; ct < 4; ++ct)
    bfn[ct] = *(const short8*)(W1b + (size_t)(w * 64 + ct * 16 + m) * (2 * HID) + 8 * 32 + q * 8);
#pragma unroll
  for (int kc = 8; kc < 16; ++kc) {
    short8 af[2], bf[4];
#pragma unroll
    for (int ct = 0; ct < 4; ++ct) bf[ct] = bfn[ct];
    if (kc < 15) {
#pragma unroll
      for (int ct = 0; ct < 4; ++ct)
        bfn[ct] = *(const short8*)(W1b + (size_t)(w * 64 + ct * 16 + m) * (2 * HID) +
                                   (kc + 1) * 32 + q * 8);
    }
#pragma unroll
    for (int rt = 0; rt < 2; ++rt)
      af[rt] = *(const short8*)&sCat[rt * 16 + m][(kc - 8) * 32 + q * 8];
#pragma unroll
    for (int rt = 0; rt < 2; ++rt)
#pragma unroll
      for (int ct = 0; ct < 4; ++ct)
        acc2[rt][ct] = __builtin_amdgcn_mfma_f32_16x16x32_bf16(af[rt], bf[ct], acc2[rt][ct], 0, 0, 0);
  }
  __syncthreads();
#pragma unroll
  for (int ct = 0; ct < 4; ++ct) {
    int col = w * 64 + ct * 16 + m;
    float bias = b1[col];
#pragma unroll
    for (int rt = 0; rt < 2; ++rt)
#pragma unroll
      for (int i = 0; i < 4; ++i) {
        int row = rt * 16 + q * 4 + i;
        sCat[row][col] = f2bf(fmaxf(acc2[rt][ct][i] + bias, 0.f));
      }
  }
  __syncthreads();

  // phase D: logits + log_softmax (fp32)
  {
    int row = t >> 3, qq = t & 7;
    float p0 = 0.f, p1 = 0.f;
    for (int c = qq * 32; c < qq * 32 + 32; ++c) {
      float hv = bf2f(sCat[row][c]);
      p0 += hv * W2[c];
      p1 += hv * W2[HID + c];
    }
    pp[t][0] = p0; pp[t][1] = p1;
  }
  __syncthreads();
  if (t < 32 && g0 + t < G) {
    float l0 = b2[0], l1 = b2[1];
#pragma unroll
    for (int k = 0; k < 8; ++k) { l0 += pp[t * 8 + k][0]; l1 += pp[t * 8 + k][1]; }
    float mx = fmaxf(l0, l1);
    float ls = logf(expf(l0 - mx) + expf(l1 - mx));
    out[(size_t)(g0 + t) * 2 + 0] = l0 - mx - ls;
    out[(size_t)(g0 + t) * 2 + 1] = l1 - mx - ls;
  }
}

// ---------------------------------------------------------------------------

extern "C" void kernel_launch(void* const* d_in, const int* in_sizes, int n_in,
                              void* d_out, int out_size, void* d_ws, size_t ws_size,
                              hipStream_t stream) {
  const float* x  = (const float*)d_in[0];
  const int* ei   = (const int*)d_in[1];
  const int* batch= (const int*)d_in[2];
  const float* Wl = (const float*)d_in[3];
  const float* bl = (const float*)d_in[4];
  const float* Wr = (const float*)d_in[5];
  const float* W0 = (const float*)d_in[6];
  const float* b0 = (const float*)d_in[7];
  const float* W1 = (const float*)d_in[8];
  const float* b1 = (const float*)d_in[9];
  const float* W2 = (const float*)d_in[10];
  const float* b2 = (const float*)d_in[11];
  float* out = (float*)d_out;

  const int N = in_sizes[0] / IN_C;
  const int E = in_sizes[1] / 2;
  const int G = out_size / OUT_C;
  const int* src = ei;
  const int* dst = ei + E;
  const int NB = (N + BNODES - 1) >> BSHIFT;   // 391

  char* w = (char*)d_ws;
  int* deg       = (int*)w; w += (size_t)N * 4;
  int* row_start = (int*)w; w += (size_t)N * 4;
  int* bcount    = (int*)w; w += 2048;
  int* cursor0   = (int*)w; w += 2048;
  int* root      = (int*)w; w += (size_t)G * 4;
  w = (char*)(((uintptr_t)w + 255) & ~(uintptr_t)255);
  int* csr       = (int*)w; w += (size_t)(E + PADB * NB + 8192) * 4;
  w = (char*)(((uintptr_t)w + 255) & ~(uintptr_t)255);
  ushort* xb     = (ushort*)w; w += (size_t)N * IN_C * 2;
  uint32_t* xf8  = (uint32_t*)w; w += (size_t)(N + 1) * IN_C;   // +1 zero row
  ushort* aggrb  = (ushort*)w; w += (size_t)N * IN_C * 2;
  ushort* Wcat   = (ushort*)w; w += (size_t)HID * (2 * IN_C) * 2;
  ushort* W0b    = (ushort*)w; w += (size_t)HID * IN_C * 2;
  ushort* W1b    = (ushort*)w; w += (size_t)HID * 2 * HID * 2;
  float* hp      = (float*)w; w += (size_t)G * HID * 4;
  uint32_t* rec  = (uint32_t*)aggrb;   // dead before k_aggr writes aggrb

  hipMemsetAsync(bcount, 0, 4096, stream);   // bcount + cursor0

  int n4 = N * IN_C / 4;
  k_prep<<<(n4 + 255) / 256, 256, 0, stream>>>(
      x, xb, xf8, n4, Wl, Wr, Wcat, W0, W0b, W1, W1b, batch, root, N,
      dst, E, bcount, hp, G * HID / 4);
  k_scatter<<<(E + EPB - 1) / EPB, 256, 0, stream>>>(src, dst, bcount, cursor0, rec, E);
  k_csr<<<NB, 256, 0, stream>>>(rec, bcount, row_start, deg, csr, N, N);
  k_aggr<<<(N + 3) / 4, 256, 0, stream>>>(xf8, csr, row_start, deg, aggrb, N);
  k_gemm_pool<<<(N + 63) / 64, 256, 0, stream>>>(aggrb, xb, Wcat, bl, batch, hp, N);
  k_tail<<<(G + 31) / 32, 256, 0, stream>>>(xb, hp, root, W0b, b0, W1b, b1, W2, b2, out, G);
}